// Round 8
// baseline (3982.211 us; speedup 1.0000x reference)
//
#include <hip/hip_runtime.h>
#include <hip/hip_bf16.h>
#include <math.h>

// Problem constants (fixed by setup_inputs)
#define BB 128
#define DD 512
#define HH 1024
#define NB 32     // num_coeff_per_dim
#define MM 63     // 2N-1 simpson points
#define TT 16
#define ITERS 10

// ws layout (float units)
#define OFF_U       0        // 32 fp32
#define OFF_TTRUE   64       // 64 fp32 (tt[63]=0)
#define OFF_PHIOUT  128      // 512 fp32
#define OFF_PHIF_BF 1024     // bf16 [64 m][32 n]  (row 63 = 0)   = 1024 floats
#define OFF_QT_BF   2048     // bf16 [32 j][64 m]  (col 63 = 0)   = 1024 floats
#define OFF_K1F     4096     // u32 k1flag[128], stride 32 u32 (128B) = 4096 f
#define OFF_K2F     8192     // u32 k2flag[128], stride 32 u32        = 4096 f
#define HDRF        12288
#define OFF_BN      HDRF                     // fp32 [B][512][32]  = 2097152
#define OFF_BCT     (OFF_BN + 2097152)       // bf16 [B][32][512]  = 1048576 f
#define OFF_PT      (OFF_BCT + 1048576)      // bf16 [B][32][1024] = 2097152 f
#define OFF_W1T     (OFF_PT + 2097152)       // bf16 [1024][512]   = 262144 f
#define OFF_W2T     (OFF_W1T + 262144)       // bf16 [512][1024]   = 262144 f
// end = 5779456 floats = 23.1 MB

typedef __attribute__((ext_vector_type(8))) short bf16x8;
typedef __attribute__((ext_vector_type(4))) float f32x4;

static __device__ __forceinline__ unsigned short f2bf(float f) {
    unsigned int x = __builtin_bit_cast(unsigned int, f);
    unsigned int r = x + 0x7FFFu + ((x >> 16) & 1u);   // RNE
    return (unsigned short)(r >> 16);
}

static __device__ __forceinline__ void store4bf(unsigned short* p,
                                                float v0, float v1, float v2, float v3) {
    unsigned int lo = (unsigned int)f2bf(v0) | ((unsigned int)f2bf(v1) << 16);
    unsigned int hi = (unsigned int)f2bf(v2) | ((unsigned int)f2bf(v3) << 16);
    uint2 u; u.x = lo; u.y = hi;
    *(uint2*)p = u;   // 8B-aligned by construction
}

static __device__ __forceinline__ float tanh_fast(float x) {
    float e = exp2f(x * 2.88539008177793f);   // 2*log2(e)
    return 1.0f - 2.0f / (e + 1.0f);
}

// XOR-swizzled LDS A-tile addressing: tile [32 r][512 c] bf16, linear 32KB,
// byte = (r*1024 + c*2) ^ ((r&7)<<4). Bijective per row, 16B-aligned b128.
static __device__ __forceinline__ unsigned short* aS(unsigned short* smA, int r, int c16) {
    return (unsigned short*)((char*)smA + (((r << 10) + (c16 << 4)) ^ ((r & 7) << 4)));
}

// Per-b producer/consumer flags (R4-validated release/acquire pattern).
// NOT a global barrier: each flag sees 8 (or 4) adds, waiters spin on own-b flag.
static __device__ __forceinline__ void wait_flag(unsigned* f, unsigned target) {
    __syncthreads();
    if (threadIdx.x == 0) {
        while (__hip_atomic_load(f, __ATOMIC_ACQUIRE, __HIP_MEMORY_SCOPE_AGENT) < target)
            __builtin_amdgcn_s_sleep(1);
    }
    __syncthreads();
}
static __device__ __forceinline__ void signal_flag(unsigned* f) {
    __syncthreads();   // all block's stores issued
    if (threadIdx.x == 0) {
        __threadfence();   // agent-scope release of this block's writes
        __hip_atomic_fetch_add(f, 1u, __ATOMIC_RELEASE, __HIP_MEMORY_SCOPE_AGENT);
    }
}

// ---------------------------------------------------------------------------
// Setup: t grids, Phi_f, Phi_inv (double GJ, wave-parallel), Q = R@Phi_inv,
// u, Phi_out, bf16 tables. Also zeroes the per-b flags each replay.
// ---------------------------------------------------------------------------
__global__ __launch_bounds__(256) void setup_kernel(const float* __restrict__ t_span,
                                                    float* __restrict__ ws) {
    __shared__ double tsim[MM];
    __shared__ double ttrue_d[MM];
    __shared__ double wid[31];
    __shared__ double phid[NB * MM];   // [n][m]
    __shared__ double aug[NB * 64];    // [Phi | I]
    __shared__ double mlt[NB];
    __shared__ double Rl[MM * NB];
    __shared__ double Qd[MM * NB];     // [m][j]
    __shared__ int    piv_s;

    const int t    = threadIdx.x;  // 256 threads
    const int lane = t & 63;
    const int rgrp = t >> 6;
    const double PI = 3.14159265358979323846;
    const double t0 = (double)t_span[0];
    const double t1 = (double)t_span[TT - 1];

    // zero flags (graph replay safe)
    for (int f = OFF_K1F + t; f < HDRF; f += 256) ws[f] = 0.0f;

    if (t < MM) {
        double v;
        if ((t & 1) == 0) {
            int j = t >> 1;
            v = -cos(PI * (double)j / (double)(NB - 1));
        } else {
            int i = t >> 1;
            double a = -cos(PI * (double)i / (double)(NB - 1));
            double b = -cos(PI * (double)(i + 1) / (double)(NB - 1));
            v = 0.5 * (a + b);
        }
        tsim[t] = v;
        ttrue_d[t] = t0 + 0.5 * (t1 - t0) * (v + 1.0);
    }
    __syncthreads();
    if (t < 31) wid[t] = (ttrue_d[2 * t + 2] - ttrue_d[2 * t]) / 6.0;
    if (t < MM) ws[OFF_TTRUE + t] = (float)ttrue_d[t];
    if (t == 63) ws[OFF_TTRUE + 63] = 0.0f;

    if (t < MM) {
        double x = tsim[t];
        double r0 = 1.0, r1 = x;
        phid[0 * MM + t] = r0;
        phid[1 * MM + t] = r1;
        for (int n = 2; n < NB; n++) {
            double r2 = 2.0 * x * r1 - r0;
            phid[n * MM + t] = r2;
            r0 = r1; r1 = r2;
        }
    }
    __syncthreads();

    {   // phif_bf [m 64][n 32], row 63 = 0
        unsigned short* pf = (unsigned short*)(ws + OFF_PHIF_BF);
        for (int f = t; f < 64 * 32; f += 256) {
            int m = f >> 5, n = f & 31;
            pf[f] = f2bf(m < MM ? (float)phid[n * MM + m] : 0.0f);
        }
    }

    for (int f = t; f < NB * 64; f += 256) {
        int r = f >> 6, c = f & 63;
        double v;
        if (c < NB) v = phid[r * MM + 2 * c];
        else        v = ((c - NB) == r) ? 1.0 : 0.0;
        aug[f] = v;
    }
    __syncthreads();

    for (int k = 0; k < NB; k++) {
        if (t < 32) {
            double v = (t >= k) ? fabs(aug[t * 64 + k]) : -1.0;
            int idx = t;
            #pragma unroll
            for (int off = 16; off >= 1; off >>= 1) {
                double ov = __shfl_xor(v, off);
                int    oi = __shfl_xor(idx, off);
                if (ov > v) { v = ov; idx = oi; }
            }
            if (t == 0) piv_s = idx;
        }
        __syncthreads();
        const int p = piv_s;
        if (t < 64) {
            double pv   = aug[p * 64 + k];
            double rowp = aug[p * 64 + t];
            double rowk = aug[k * 64 + t];
            aug[k * 64 + t] = rowp / pv;
            if (p != k) aug[p * 64 + t] = rowk;
        }
        __syncthreads();
        if (t < 32) mlt[t] = (t == k) ? 0.0 : aug[t * 64 + k];
        __syncthreads();
        {
            double pk = aug[k * 64 + lane];
            #pragma unroll
            for (int i = 0; i < 8; i++) {
                int r = rgrp * 8 + i;
                aug[r * 64 + lane] -= mlt[r] * pk;
            }
        }
        __syncthreads();
    }

    if (t < MM) {
        double acc = 0.0;
        Rl[t * NB + 0] = 0.0;
        for (int i = 1; i < NB; i++) {
            int ip = i - 1;
            double w = 0.0;
            if (t == 2 * ip)     w += wid[ip];
            if (t == 2 * ip + 1) w += 4.0 * wid[ip];
            if (t == 2 * ip + 2) w += wid[ip];
            acc += w;
            Rl[t * NB + i] = acc;
        }
    }
    __syncthreads();

    for (int f = t; f < MM * NB; f += 256) {
        int m = f >> 5, j = f & 31;
        double s = 0.0;
        for (int i = 0; i < NB; i++) s += Rl[m * NB + i] * aug[i * 64 + 32 + j];
        Qd[f] = s;
    }
    __syncthreads();

    {   // qt_bf [j 32][m 64], col 63 = 0
        unsigned short* qt = (unsigned short*)(ws + OFF_QT_BF);
        for (int f = t; f < 32 * 64; f += 256) {
            int j = f >> 6, m = f & 63;
            qt[f] = f2bf(m < MM ? (float)Qd[m * NB + j] : 0.0f);
        }
    }
    if (t < NB) {
        double s = 0.0;
        for (int i = 0; i < NB; i++) s += aug[i * 64 + 32 + t];
        ws[OFF_U + t] = (float)s;
    }
    if (t < TT) {
        double x = -1.0 + 2.0 * ((double)t_span[t] - t0) / (t1 - t0);
        double r0 = 1.0, r1 = x;
        ws[OFF_PHIOUT + 0 * TT + t] = 1.0f;
        ws[OFF_PHIOUT + 1 * TT + t] = (float)x;
        for (int n = 2; n < NB; n++) {
            double r2 = 2.0 * x * r1 - r0;
            ws[OFF_PHIOUT + n * TT + t] = (float)r2;
            r0 = r1; r1 = r2;
        }
    }
}

// ---------------------------------------------------------------------------
// Transpose fp32 (R x C) -> bf16 (C x R)
// ---------------------------------------------------------------------------
__global__ __launch_bounds__(256) void transpose_f32_bf16(
        const float* __restrict__ in, unsigned short* __restrict__ out,
        int R, int C) {
    __shared__ float tile[32][33];
    const int t = threadIdx.x;
    const int tc = blockIdx.x, tr = blockIdx.y;
    const int c = tc * 32 + (t & 31);
    #pragma unroll
    for (int i = 0; i < 4; i++) {
        int rl = (t >> 5) + i * 8;
        tile[rl][t & 31] = in[(size_t)(tr * 32 + rl) * C + c];
    }
    __syncthreads();
    #pragma unroll
    for (int i = 0; i < 4; i++) {
        int orl = (t >> 5) + i * 8;            // local col of input
        int orow = tc * 32 + orl;
        int ocol = tr * 32 + (t & 31);
        out[(size_t)orow * R + ocol] = f2bf(tile[t & 31][orl]);
    }
}

// B_init [b][d][n] fp32 -> Bct [b][n][d] bf16
__global__ __launch_bounds__(256) void binit_kernel(
        const float* __restrict__ Bi, unsigned short* __restrict__ Bct) {
    __shared__ float tile[32][33];
    const int t = threadIdx.x;
    const int b = blockIdx.y, d0 = blockIdx.x * 32;
    #pragma unroll
    for (int i = 0; i < 4; i++) {
        int f = i * 256 + t;
        int dd = f >> 5, n = f & 31;
        tile[dd][n] = Bi[((size_t)b * DD + d0 + dd) * NB + n];
    }
    __syncthreads();
    #pragma unroll
    for (int i = 0; i < 4; i++) {
        int f = i * 256 + t;
        int n = f >> 5, dd = f & 31;
        Bct[((size_t)b * NB + n) * DD + d0 + dd] = f2bf(tile[dd][n]);
    }
}

// ---------------------------------------------------------------------------
// k1 phase (verbatim R6 k1_kernel body): block (b, hblk). A-tile staged in
// LDS (swz), shared by 4 waves; G = A W1^T; Z = Phi_f^T G; tanh; P = Q^T T.
// smem layout: [0,32768) A | t_sb overlay; [32768,40960) g_sb.
// ---------------------------------------------------------------------------
static __device__ void k1_phase(
        int b, int hblk,
        const unsigned short* Bct, const unsigned short* W1t,
        const float* b1, const float* ws, unsigned short* Pt,
        char* smem) {
    unsigned short* smA  = (unsigned short*)smem;
    unsigned short* t_sb = (unsigned short*)smem;
    unsigned short* g_sb = (unsigned short*)(smem + 32768);

    const int t    = threadIdx.x;
    const int lane = t & 63;
    const int w    = t >> 6;
    const int q    = lane >> 4;
    const int l15  = lane & 15;
    const int h0   = hblk * 128;
    const int hw   = h0 + w * 32;

    {   // stage A = Bct[b] (32x512 bf16 = 32KB)
        const unsigned short* A0 = Bct + (size_t)b * NB * DD;
        #pragma unroll
        for (int i = 0; i < 8; i++) {
            int c = i * 256 + t;
            int r = c >> 6, c16 = c & 63;
            bf16x8 v = *(const bf16x8*)(A0 + (size_t)r * DD + c16 * 8);
            *(bf16x8*)aS(smA, r, c16) = v;
        }
    }
    __syncthreads();

    // Phase A: G = A W1^T, M=32(n) x N=32(h/wave) x K=512
    f32x4 acc[2][2] = {};
    #pragma unroll 4
    for (int d0 = 0; d0 < DD; d0 += 32) {
        int c16 = (d0 >> 3) + q;
        bf16x8 a0 = *(const bf16x8*)aS(smA, l15, c16);
        bf16x8 a1 = *(const bf16x8*)aS(smA, 16 + l15, c16);
        bf16x8 bb0 = *(const bf16x8*)(W1t + (size_t)(hw + l15) * DD + d0 + q * 8);
        bf16x8 bb1 = *(const bf16x8*)(W1t + (size_t)(hw + 16 + l15) * DD + d0 + q * 8);
        acc[0][0] = __builtin_amdgcn_mfma_f32_16x16x32_bf16(a0, bb0, acc[0][0], 0, 0, 0);
        acc[0][1] = __builtin_amdgcn_mfma_f32_16x16x32_bf16(a0, bb1, acc[0][1], 0, 0, 0);
        acc[1][0] = __builtin_amdgcn_mfma_f32_16x16x32_bf16(a1, bb0, acc[1][0], 0, 0, 0);
        acc[1][1] = __builtin_amdgcn_mfma_f32_16x16x32_bf16(a1, bb1, acc[1][1], 0, 0, 0);
    }
    #pragma unroll
    for (int mt = 0; mt < 2; mt++)
        #pragma unroll
        for (int nt = 0; nt < 2; nt++) {
            int hl = w * 32 + nt * 16 + l15;
            store4bf(&g_sb[hl * 32 + mt * 16 + q * 4],
                     acc[mt][nt][0], acc[mt][nt][1], acc[mt][nt][2], acc[mt][nt][3]);
        }
    __syncthreads();   // all A_s reads complete -> t_sb may overlay

    // Z = Phi_f^T G : M=64(m) x N=32(h/wave) x K=32(n)
    f32x4 zacc[4][2] = {};
    const unsigned short* PF = (const unsigned short*)(ws + OFF_PHIF_BF);
    bf16x8 gb[2];
    #pragma unroll
    for (int nt = 0; nt < 2; nt++)
        gb[nt] = *(const bf16x8*)(&g_sb[(w * 32 + nt * 16 + l15) * 32 + q * 8]);
    #pragma unroll
    for (int mt = 0; mt < 4; mt++) {
        bf16x8 af = *(const bf16x8*)(PF + (mt * 16 + l15) * 32 + q * 8);
        zacc[mt][0] = __builtin_amdgcn_mfma_f32_16x16x32_bf16(af, gb[0], zacc[mt][0], 0, 0, 0);
        zacc[mt][1] = __builtin_amdgcn_mfma_f32_16x16x32_bf16(af, gb[1], zacc[mt][1], 0, 0, 0);
    }

    const float* TTp = ws + OFF_TTRUE;
    float b1v[2] = { b1[hw + l15], b1[hw + 16 + l15] };
    #pragma unroll
    for (int mt = 0; mt < 4; mt++) {
        float4 ttv = *(const float4*)(TTp + mt * 16 + q * 4);
        #pragma unroll
        for (int nt = 0; nt < 2; nt++) {
            int hl = w * 32 + nt * 16 + l15;
            float v0 = tanh_fast(zacc[mt][nt][0] + ttv.x * b1v[nt]);
            float v1 = tanh_fast(zacc[mt][nt][1] + ttv.y * b1v[nt]);
            float v2 = tanh_fast(zacc[mt][nt][2] + ttv.z * b1v[nt]);
            float v3 = tanh_fast(zacc[mt][nt][3] + ttv.w * b1v[nt]);
            store4bf(&t_sb[hl * 72 + mt * 16 + q * 4], v0, v1, v2, v3);
        }
    }
    __syncthreads();

    // P = Q^T T : M=32(j) x N=32(h/wave) x K=64(m)
    f32x4 pacc[2][2] = {};
    const unsigned short* QT = (const unsigned short*)(ws + OFF_QT_BF);
    #pragma unroll
    for (int ks = 0; ks < 2; ks++) {
        bf16x8 bt[2];
        #pragma unroll
        for (int nt = 0; nt < 2; nt++)
            bt[nt] = *(const bf16x8*)(&t_sb[(w * 32 + nt * 16 + l15) * 72 + ks * 32 + q * 8]);
        #pragma unroll
        for (int jt = 0; jt < 2; jt++) {
            bf16x8 aq = *(const bf16x8*)(QT + (jt * 16 + l15) * 64 + ks * 32 + q * 8);
            pacc[jt][0] = __builtin_amdgcn_mfma_f32_16x16x32_bf16(aq, bt[0], pacc[jt][0], 0, 0, 0);
            pacc[jt][1] = __builtin_amdgcn_mfma_f32_16x16x32_bf16(aq, bt[1], pacc[jt][1], 0, 0, 0);
        }
    }

    #pragma unroll
    for (int jt = 0; jt < 2; jt++)
        #pragma unroll
        for (int nt = 0; nt < 2; nt++) {
            int hg = hw + nt * 16 + l15;
            #pragma unroll
            for (int r = 0; r < 4; r++) {
                int j = jt * 16 + q * 4 + r;
                Pt[((size_t)b * NB + j) * HH + hg] = f2bf(pacc[jt][nt][r]);
            }
        }
}

// ---------------------------------------------------------------------------
// k2 phase (verbatim R6 k2_kernel body): block (b, dblk). A = Pt[b] staged in
// two 32x512 LDS chunks (swz); Bn only on last iter, Bct otherwise.
// smem layout: [0,32768) A chunk | ls overlay.
// ---------------------------------------------------------------------------
static __device__ void k2_phase(
        int b, int dblk, bool last,
        const unsigned short* Pt, const unsigned short* W2t,
        const float* y_init, const float* ws,
        float* Bn, unsigned short* Bct,
        char* smem) {
    unsigned short* smA = (unsigned short*)smem;
    float*          ls  = (float*)smem;

    const int t    = threadIdx.x;
    const int lane = t & 63;
    const int w    = t >> 6;
    const int q    = lane >> 4;
    const int l15  = lane & 15;
    const int d0   = dblk * 128;
    const int dw   = d0 + w * 32;

    f32x4 acc[2][2] = {};
    #pragma unroll 1
    for (int chunk = 0; chunk < 2; chunk++) {
        {
            const unsigned short* A0 = Pt + (size_t)b * NB * HH + chunk * 512;
            #pragma unroll
            for (int i = 0; i < 8; i++) {
                int c = i * 256 + t;
                int r = c >> 6, c16 = c & 63;
                bf16x8 v = *(const bf16x8*)(A0 + (size_t)r * HH + c16 * 8);
                *(bf16x8*)aS(smA, r, c16) = v;
            }
        }
        __syncthreads();
        #pragma unroll 4
        for (int hc = 0; hc < 512; hc += 32) {
            int c16 = (hc >> 3) + q;
            bf16x8 a0 = *(const bf16x8*)aS(smA, l15, c16);
            bf16x8 a1 = *(const bf16x8*)aS(smA, 16 + l15, c16);
            bf16x8 bb0 = *(const bf16x8*)(W2t + (size_t)(dw + l15) * HH + chunk * 512 + hc + q * 8);
            bf16x8 bb1 = *(const bf16x8*)(W2t + (size_t)(dw + 16 + l15) * HH + chunk * 512 + hc + q * 8);
            acc[0][0] = __builtin_amdgcn_mfma_f32_16x16x32_bf16(a0, bb0, acc[0][0], 0, 0, 0);
            acc[0][1] = __builtin_amdgcn_mfma_f32_16x16x32_bf16(a0, bb1, acc[0][1], 0, 0, 0);
            acc[1][0] = __builtin_amdgcn_mfma_f32_16x16x32_bf16(a1, bb0, acc[1][0], 0, 0, 0);
            acc[1][1] = __builtin_amdgcn_mfma_f32_16x16x32_bf16(a1, bb1, acc[1][1], 0, 0, 0);
        }
        __syncthreads();
    }

    const float* U = ws + OFF_U;
    float yv[2] = { y_init[(size_t)b * DD + dw + l15],
                    y_init[(size_t)b * DD + dw + 16 + l15] };
    #pragma unroll
    for (int mt = 0; mt < 2; mt++) {
        float4 uv = *(const float4*)(U + mt * 16 + q * 4);
        #pragma unroll
        for (int nt = 0; nt < 2; nt++) {
            int dl = nt * 16 + l15;
            #pragma unroll
            for (int r = 0; r < 4; r++) {
                int j = mt * 16 + q * 4 + r;
                float uvr = (r == 0) ? uv.x : (r == 1) ? uv.y : (r == 2) ? uv.z : uv.w;
                float val = acc[mt][nt][r] + yv[nt] * uvr;
                if (!last) Bct[((size_t)b * NB + j) * DD + dw + dl] = f2bf(val);
                else       ls[w * 1056 + j * 33 + dl] = val;
            }
        }
    }
    if (last) {
        __syncthreads();
        #pragma unroll
        for (int it = 0; it < 16; it++) {
            int f = it * 64 + lane;
            int d_l = f >> 5, j2 = f & 31;
            Bn[((size_t)b * DD + dw + d_l) * NB + j2] = ls[w * 1056 + j2 * 33 + d_l];
        }
    }
}

// ---------------------------------------------------------------------------
// loop_kernel: ONE launch for all 10 iterations. 1024 blocks (bid = s*128+b),
// all co-resident (LDS 40960 -> exactly 4 blocks/CU; VGPR<=128 via
// launch_bounds). Per-b flags replace the 20 launch boundaries: k2(b) starts
// as soon as ITS 8 k1 producers finish; b's pipeline independently (no global
// drain, no 1024-way atomic contention -- the R4 failure modes).
// Same-b blocks share bid%8 -> same XCD under round-robin (perf only).
// ---------------------------------------------------------------------------
__global__ __launch_bounds__(256, 4) void loop_kernel(
        const unsigned short* W1t, const unsigned short* W2t,
        const float* b1, const float* y_init,
        float* ws, float* Bn, unsigned short* Bct, unsigned short* Pt) {
    __shared__ __align__(16) char smem[40960];

    const int bid = blockIdx.x;
    const int b   = bid & 127;
    const int s   = bid >> 7;      // 0..7: k1 hblk; s<4 also k2 dblk
    unsigned* k1f = (unsigned*)ws + OFF_K1F + b * 32;
    unsigned* k2f = (unsigned*)ws + OFF_K2F + b * 32;

    #pragma unroll 1
    for (int it = 0; it < ITERS; ++it) {
        if (it > 0) wait_flag(k2f, 4u * (unsigned)it);       // Bct[b] v(it) ready
        k1_phase(b, s, Bct, W1t, b1, ws, Pt, smem);
        signal_flag(k1f);
        if (s < 4) {
            wait_flag(k1f, 8u * (unsigned)(it + 1));         // Pt[b] v(it) ready
            k2_phase(b, s, it == ITERS - 1, Pt, W2t, y_init, ws, Bn, Bct, smem);
            if (it < ITERS - 1) signal_flag(k2f);
        }
    }
}

// ---------------------------------------------------------------------------
// K3: out0[t,b,d] = sum_n Bn[b,d,n]*Phi_out[n,t] ; out1 = Bn
// ---------------------------------------------------------------------------
__global__ __launch_bounds__(256) void k3_kernel(
        const float* __restrict__ ws_c, float* __restrict__ out) {
    __shared__ float rows_s[64 * 33];
    __shared__ float phiout_s[NB * TT];

    const int t = threadIdx.x;
    const int r0 = blockIdx.x * 64;
    const float* Bf = ws_c + OFF_BN;

    for (int f = t; f < NB * TT; f += 256) phiout_s[f] = ws_c[OFF_PHIOUT + f];

    float vals[8];
    {
        int f = t;
        #pragma unroll
        for (int i = 0; i < 8; i++, f += 256) {
            float v = Bf[(size_t)r0 * NB + f];
            rows_s[(f >> 5) * 33 + (f & 31)] = v;
            vals[i] = v;
        }
    }
    float* out1 = out + (size_t)TT * BB * DD;
    {
        int f = t;
        #pragma unroll
        for (int i = 0; i < 8; i++, f += 256) out1[(size_t)r0 * NB + f] = vals[i];
    }
    __syncthreads();

    #pragma unroll
    for (int i = 0; i < 4; i++) {
        int idx = i * 256 + t;
        int tt = idx >> 6, rl = idx & 63;
        float s = 0.f;
        #pragma unroll
        for (int n = 0; n < NB; n++)
            s += rows_s[rl * 33 + n] * phiout_s[n * TT + tt];
        out[(size_t)tt * (BB * DD) + r0 + rl] = s;
    }
}

// ---------------------------------------------------------------------------
extern "C" void kernel_launch(void* const* d_in, const int* in_sizes, int n_in,
                              void* d_out, int out_size, void* d_ws, size_t ws_size,
                              hipStream_t stream) {
    const float* t_span = (const float*)d_in[0];
    const float* y_init = (const float*)d_in[1];
    const float* B_init = (const float*)d_in[2];
    const float* W1     = (const float*)d_in[3];
    const float* b1     = (const float*)d_in[4];
    const float* W2     = (const float*)d_in[5];
    float* ws  = (float*)d_ws;
    float* out = (float*)d_out;

    unsigned short* W1t = (unsigned short*)(ws + OFF_W1T);
    unsigned short* W2t = (unsigned short*)(ws + OFF_W2T);
    unsigned short* Bct = (unsigned short*)(ws + OFF_BCT);
    unsigned short* Pt  = (unsigned short*)(ws + OFF_PT);
    float*          Bn  = ws + OFF_BN;

    setup_kernel<<<1, 256, 0, stream>>>(t_span, ws);
    transpose_f32_bf16<<<dim3(HH / 32, DD / 32), 256, 0, stream>>>(W1, W1t, DD, HH);
    transpose_f32_bf16<<<dim3(DD / 32, HH / 32), 256, 0, stream>>>(W2, W2t, HH, DD);
    binit_kernel<<<dim3(DD / 32, BB), 256, 0, stream>>>(B_init, Bct);

    loop_kernel<<<dim3(1024), dim3(256), 0, stream>>>(
        W1t, W2t, b1, y_init, ws, Bn, Bct, Pt);

    k3_kernel<<<dim3((BB * DD) / 64), 256, 0, stream>>>(ws, out);
}

// Round 9
// 468.243 us; speedup vs baseline: 8.5046x; 8.5046x over previous
//
#include <hip/hip_runtime.h>
#include <hip/hip_bf16.h>
#include <math.h>

// Problem constants (fixed by setup_inputs)
#define BB 128
#define DD 512
#define HH 1024
#define NB 32     // num_coeff_per_dim
#define MM 63     // 2N-1 simpson points
#define TT 16
#define ITERS 10

// ws layout (float units)
#define OFF_U       0        // 32 fp32
#define OFF_TTRUE   64       // 64 fp32 (tt[63]=0)
#define OFF_PHIOUT  128      // 512 fp32
#define OFF_PHIF_BF 1024     // bf16 [64 m][32 n]  (row 63 = 0)   = 1024 floats
#define OFF_QT_BF   2048     // bf16 [32 j][64 m]  (col 63 = 0)   = 1024 floats
#define HDRF        4096
#define OFF_BN      HDRF                     // fp32 [B][512][32]  = 2097152
#define OFF_BCT     (OFF_BN + 2097152)       // bf16 [B][32][512]  = 1048576 f
#define OFF_PT      (OFF_BCT + 1048576)      // bf16 [B][32][1024] = 2097152 f
#define OFF_W1P     (OFF_PT + 2097152)       // bf16 frag-packed [64 hb][16 ds][64][8] = 262144 f
#define OFF_W2P     (OFF_W1P + 262144)       // bf16 frag-packed [32 db][32 hs][64][8] = 262144 f
// end = 5771264 floats = 23.1 MB

typedef __attribute__((ext_vector_type(8))) short bf16x8;
typedef __attribute__((ext_vector_type(4))) float f32x4;

static __device__ __forceinline__ unsigned short f2bf(float f) {
    unsigned int x = __builtin_bit_cast(unsigned int, f);
    unsigned int r = x + 0x7FFFu + ((x >> 16) & 1u);   // RNE
    return (unsigned short)(r >> 16);
}

static __device__ __forceinline__ void store4bf(unsigned short* p,
                                                float v0, float v1, float v2, float v3) {
    unsigned int lo = (unsigned int)f2bf(v0) | ((unsigned int)f2bf(v1) << 16);
    unsigned int hi = (unsigned int)f2bf(v2) | ((unsigned int)f2bf(v3) << 16);
    uint2 u; u.x = lo; u.y = hi;
    *(uint2*)p = u;   // 8B-aligned by construction
}

static __device__ __forceinline__ float tanh_fast(float x) {
    float e = exp2f(x * 2.88539008177793f);   // 2*log2(e)
    return 1.0f - 2.0f / (e + 1.0f);
}

// XOR-swizzled LDS A-tile addressing: tile [32 r][512 c] bf16, linear 32KB,
// byte = (r*1024 + c*2) ^ ((r&7)<<4). Bijective per row, 16B-aligned b128.
static __device__ __forceinline__ unsigned short* aS(unsigned short* smA, int r, int c16) {
    return (unsigned short*)((char*)smA + (((r << 10) + (c16 << 4)) ^ ((r & 7) << 4)));
}

// ---------------------------------------------------------------------------
// Setup: t grids, Phi_f, Phi_inv (double GJ, wave-parallel), Q = R@Phi_inv,
// u, Phi_out, bf16 tables.
// ---------------------------------------------------------------------------
__global__ __launch_bounds__(256) void setup_kernel(const float* __restrict__ t_span,
                                                    float* __restrict__ ws) {
    __shared__ double tsim[MM];
    __shared__ double ttrue_d[MM];
    __shared__ double wid[31];
    __shared__ double phid[NB * MM];   // [n][m]
    __shared__ double aug[NB * 64];    // [Phi | I]
    __shared__ double mlt[NB];
    __shared__ double Rl[MM * NB];
    __shared__ double Qd[MM * NB];     // [m][j]
    __shared__ int    piv_s;

    const int t    = threadIdx.x;  // 256 threads
    const int lane = t & 63;
    const int rgrp = t >> 6;
    const double PI = 3.14159265358979323846;
    const double t0 = (double)t_span[0];
    const double t1 = (double)t_span[TT - 1];

    if (t < MM) {
        double v;
        if ((t & 1) == 0) {
            int j = t >> 1;
            v = -cos(PI * (double)j / (double)(NB - 1));
        } else {
            int i = t >> 1;
            double a = -cos(PI * (double)i / (double)(NB - 1));
            double b = -cos(PI * (double)(i + 1) / (double)(NB - 1));
            v = 0.5 * (a + b);
        }
        tsim[t] = v;
        ttrue_d[t] = t0 + 0.5 * (t1 - t0) * (v + 1.0);
    }
    __syncthreads();
    if (t < 31) wid[t] = (ttrue_d[2 * t + 2] - ttrue_d[2 * t]) / 6.0;
    if (t < MM) ws[OFF_TTRUE + t] = (float)ttrue_d[t];
    if (t == 63) ws[OFF_TTRUE + 63] = 0.0f;

    if (t < MM) {
        double x = tsim[t];
        double r0 = 1.0, r1 = x;
        phid[0 * MM + t] = r0;
        phid[1 * MM + t] = r1;
        for (int n = 2; n < NB; n++) {
            double r2 = 2.0 * x * r1 - r0;
            phid[n * MM + t] = r2;
            r0 = r1; r1 = r2;
        }
    }
    __syncthreads();

    {   // phif_bf [m 64][n 32], row 63 = 0
        unsigned short* pf = (unsigned short*)(ws + OFF_PHIF_BF);
        for (int f = t; f < 64 * 32; f += 256) {
            int m = f >> 5, n = f & 31;
            pf[f] = f2bf(m < MM ? (float)phid[n * MM + m] : 0.0f);
        }
    }

    for (int f = t; f < NB * 64; f += 256) {
        int r = f >> 6, c = f & 63;
        double v;
        if (c < NB) v = phid[r * MM + 2 * c];
        else        v = ((c - NB) == r) ? 1.0 : 0.0;
        aug[f] = v;
    }
    __syncthreads();

    for (int k = 0; k < NB; k++) {
        if (t < 32) {
            double v = (t >= k) ? fabs(aug[t * 64 + k]) : -1.0;
            int idx = t;
            #pragma unroll
            for (int off = 16; off >= 1; off >>= 1) {
                double ov = __shfl_xor(v, off);
                int    oi = __shfl_xor(idx, off);
                if (ov > v) { v = ov; idx = oi; }
            }
            if (t == 0) piv_s = idx;
        }
        __syncthreads();
        const int p = piv_s;
        if (t < 64) {
            double pv   = aug[p * 64 + k];
            double rowp = aug[p * 64 + t];
            double rowk = aug[k * 64 + t];
            aug[k * 64 + t] = rowp / pv;
            if (p != k) aug[p * 64 + t] = rowk;
        }
        __syncthreads();
        if (t < 32) mlt[t] = (t == k) ? 0.0 : aug[t * 64 + k];
        __syncthreads();
        {
            double pk = aug[k * 64 + lane];
            #pragma unroll
            for (int i = 0; i < 8; i++) {
                int r = rgrp * 8 + i;
                aug[r * 64 + lane] -= mlt[r] * pk;
            }
        }
        __syncthreads();
    }

    if (t < MM) {
        double acc = 0.0;
        Rl[t * NB + 0] = 0.0;
        for (int i = 1; i < NB; i++) {
            int ip = i - 1;
            double w = 0.0;
            if (t == 2 * ip)     w += wid[ip];
            if (t == 2 * ip + 1) w += 4.0 * wid[ip];
            if (t == 2 * ip + 2) w += wid[ip];
            acc += w;
            Rl[t * NB + i] = acc;
        }
    }
    __syncthreads();

    for (int f = t; f < MM * NB; f += 256) {
        int m = f >> 5, j = f & 31;
        double s = 0.0;
        for (int i = 0; i < NB; i++) s += Rl[m * NB + i] * aug[i * 64 + 32 + j];
        Qd[f] = s;
    }
    __syncthreads();

    {   // qt_bf [j 32][m 64], col 63 = 0
        unsigned short* qt = (unsigned short*)(ws + OFF_QT_BF);
        for (int f = t; f < 32 * 64; f += 256) {
            int j = f >> 6, m = f & 63;
            qt[f] = f2bf(m < MM ? (float)Qd[m * NB + j] : 0.0f);
        }
    }
    if (t < NB) {
        double s = 0.0;
        for (int i = 0; i < NB; i++) s += aug[i * 64 + 32 + t];
        ws[OFF_U + t] = (float)s;
    }
    if (t < TT) {
        double x = -1.0 + 2.0 * ((double)t_span[t] - t0) / (t1 - t0);
        double r0 = 1.0, r1 = x;
        ws[OFF_PHIOUT + 0 * TT + t] = 1.0f;
        ws[OFF_PHIOUT + 1 * TT + t] = (float)x;
        for (int n = 2; n < NB; n++) {
            double r2 = 2.0 * x * r1 - r0;
            ws[OFF_PHIOUT + n * TT + t] = (float)r2;
            r0 = r1; r1 = r2;
        }
    }
}

// ---------------------------------------------------------------------------
// pack_w1: W1 fp32 [512 d][1024 h] -> W1p bf16 [64 hb][16 ds][64 lane][8 e]
// fragment-packed so a wave's B-operand load is ONE contiguous 1KB read:
// W1p[hb][ds][q*16+l15][e] = bf16(W1[(ds*32+q*8+e)][hb*16+l15])
// ---------------------------------------------------------------------------
__global__ __launch_bounds__(256) void pack_w1(
        const float* __restrict__ W1, unsigned short* __restrict__ W1p) {
    const int hb = blockIdx.x;    // 0..63
    const int t  = threadIdx.x;
    #pragma unroll
    for (int i = 0; i < 4; i++) {
        int f = i * 256 + t;               // fragment 0..1023
        int ds = f >> 6, lane = f & 63;
        int q = lane >> 4, l15 = lane & 15;
        unsigned short tmp[8];
        #pragma unroll
        for (int e = 0; e < 8; e++)
            tmp[e] = f2bf(W1[(size_t)(ds * 32 + q * 8 + e) * HH + hb * 16 + l15]);
        *(uint4*)(W1p + ((size_t)(hb * 16 + ds) * 64 + lane) * 8) = *(uint4*)tmp;
    }
}

// pack_w2: W2 fp32 [1024 h][512 d] -> W2p bf16 [32 db][32 hs][64 lane][8 e]
// W2p[db][hs][q*16+l15][e] = bf16(W2[(hs*32+q*8+e)][db*16+l15])
__global__ __launch_bounds__(256) void pack_w2(
        const float* __restrict__ W2, unsigned short* __restrict__ W2p) {
    const int db = blockIdx.x;    // 0..31
    const int t  = threadIdx.x;
    #pragma unroll
    for (int i = 0; i < 8; i++) {
        int f = i * 256 + t;               // fragment 0..2047
        int hs = f >> 6, lane = f & 63;
        int q = lane >> 4, l15 = lane & 15;
        unsigned short tmp[8];
        #pragma unroll
        for (int e = 0; e < 8; e++)
            tmp[e] = f2bf(W2[(size_t)(hs * 32 + q * 8 + e) * DD + db * 16 + l15]);
        *(uint4*)(W2p + ((size_t)(db * 32 + hs) * 64 + lane) * 8) = *(uint4*)tmp;
    }
}

// B_init [b][d][n] fp32 -> Bct [b][n][d] bf16
__global__ __launch_bounds__(256) void binit_kernel(
        const float* __restrict__ Bi, unsigned short* __restrict__ Bct) {
    __shared__ float tile[32][33];
    const int t = threadIdx.x;
    const int b = blockIdx.y, d0 = blockIdx.x * 32;
    #pragma unroll
    for (int i = 0; i < 4; i++) {
        int f = i * 256 + t;
        int dd = f >> 5, n = f & 31;
        tile[dd][n] = Bi[((size_t)b * DD + d0 + dd) * NB + n];
    }
    __syncthreads();
    #pragma unroll
    for (int i = 0; i < 4; i++) {
        int f = i * 256 + t;
        int n = f >> 5, dd = f & 31;
        Bct[((size_t)b * NB + n) * DD + d0 + dd] = f2bf(tile[dd][n]);
    }
}

// ---------------------------------------------------------------------------
// K1: per block (b, 128 h). A-tile (Bct b-slice 32x512) staged once in LDS
// (XOR-swizzled), shared by all 4 waves. B-operand from frag-packed W1p:
// each load = one contiguous 1KB wave-read (was 16-line gather).
// LDS: 32768 (A_s | t_sb) + 8192 (g_sb) = 40960 B -> 4 blocks/CU.
// ---------------------------------------------------------------------------
__global__ __launch_bounds__(256) void k1_kernel(
        const unsigned short* __restrict__ Bct,  // [B][32 n][512 d] bf16
        const unsigned short* __restrict__ W1p,  // frag-packed
        const float* __restrict__ b1,            // [1024]
        const float* __restrict__ ws,
        unsigned short* __restrict__ Pt)         // [B][32 j][1024 h] bf16
{
    __shared__ __align__(16) char smem[40960];
    unsigned short* smA  = (unsigned short*)smem;           // A [32][512] swz (phase A)
    unsigned short* t_sb = (unsigned short*)smem;           // [128][72] (phase B, overlays A)
    unsigned short* g_sb = (unsigned short*)(smem + 32768); // [128][32]

    const int t    = threadIdx.x;
    const int lane = t & 63;
    const int w    = t >> 6;       // wave 0..3
    const int q    = lane >> 4;    // quad 0..3
    const int l15  = lane & 15;
    const int b    = blockIdx.y;
    const int h0   = blockIdx.x * 128;
    const int hw   = h0 + w * 32;  // wave's global h base

    // ---- stage A = Bct[b] (32x512 bf16 = 32KB; 8x 16B per thread) ----
    {
        const unsigned short* A0 = Bct + (size_t)b * NB * DD;
        #pragma unroll
        for (int i = 0; i < 8; i++) {
            int c = i * 256 + t;           // 0..2047 16B-chunks
            int r = c >> 6, c16 = c & 63;
            bf16x8 v = *(const bf16x8*)(A0 + (size_t)r * DD + c16 * 8);
            *(bf16x8*)aS(smA, r, c16) = v;
        }
    }
    __syncthreads();

    // ---- Phase A: G = A W1^T, M=32(n) x N=32(h/wave) x K=512 ----
    f32x4 acc[2][2] = {};
    const unsigned short* W1b = W1p + (size_t)(hw >> 4) * 8192;   // hb0 tile base
    #pragma unroll 4
    for (int d0 = 0; d0 < DD; d0 += 32) {
        int c16 = (d0 >> 3) + q;
        int ds  = d0 >> 5;
        bf16x8 a0 = *(const bf16x8*)aS(smA, l15, c16);
        bf16x8 a1 = *(const bf16x8*)aS(smA, 16 + l15, c16);
        bf16x8 bb0 = *(const bf16x8*)(W1b + ds * 512 + lane * 8);
        bf16x8 bb1 = *(const bf16x8*)(W1b + 8192 + ds * 512 + lane * 8);
        acc[0][0] = __builtin_amdgcn_mfma_f32_16x16x32_bf16(a0, bb0, acc[0][0], 0, 0, 0);
        acc[0][1] = __builtin_amdgcn_mfma_f32_16x16x32_bf16(a0, bb1, acc[0][1], 0, 0, 0);
        acc[1][0] = __builtin_amdgcn_mfma_f32_16x16x32_bf16(a1, bb0, acc[1][0], 0, 0, 0);
        acc[1][1] = __builtin_amdgcn_mfma_f32_16x16x32_bf16(a1, bb1, acc[1][1], 0, 0, 0);
    }
    // write G to g_sb[h_loc][n] bf16
    #pragma unroll
    for (int mt = 0; mt < 2; mt++)
        #pragma unroll
        for (int nt = 0; nt < 2; nt++) {
            int hl = w * 32 + nt * 16 + l15;
            store4bf(&g_sb[hl * 32 + mt * 16 + q * 4],
                     acc[mt][nt][0], acc[mt][nt][1], acc[mt][nt][2], acc[mt][nt][3]);
        }
    __syncthreads();   // also: all A_s reads complete -> t_sb may overlay

    // ---- Z = Phi_f^T G : M=64(m) x N=32(h/wave) x K=32(n) ----
    f32x4 zacc[4][2] = {};
    const unsigned short* PF = (const unsigned short*)(ws + OFF_PHIF_BF);
    bf16x8 gb[2];
    #pragma unroll
    for (int nt = 0; nt < 2; nt++)
        gb[nt] = *(const bf16x8*)(&g_sb[(w * 32 + nt * 16 + l15) * 32 + q * 8]);
    #pragma unroll
    for (int mt = 0; mt < 4; mt++) {
        bf16x8 af = *(const bf16x8*)(PF + (mt * 16 + l15) * 32 + q * 8);
        zacc[mt][0] = __builtin_amdgcn_mfma_f32_16x16x32_bf16(af, gb[0], zacc[mt][0], 0, 0, 0);
        zacc[mt][1] = __builtin_amdgcn_mfma_f32_16x16x32_bf16(af, gb[1], zacc[mt][1], 0, 0, 0);
    }

    // bias + tanh + write t_sb[h_loc][m] bf16
    const float* TTp = ws + OFF_TTRUE;
    float b1v[2] = { b1[hw + l15], b1[hw + 16 + l15] };
    #pragma unroll
    for (int mt = 0; mt < 4; mt++) {
        float4 ttv = *(const float4*)(TTp + mt * 16 + q * 4);
        #pragma unroll
        for (int nt = 0; nt < 2; nt++) {
            int hl = w * 32 + nt * 16 + l15;
            float v0 = tanh_fast(zacc[mt][nt][0] + ttv.x * b1v[nt]);
            float v1 = tanh_fast(zacc[mt][nt][1] + ttv.y * b1v[nt]);
            float v2 = tanh_fast(zacc[mt][nt][2] + ttv.z * b1v[nt]);
            float v3 = tanh_fast(zacc[mt][nt][3] + ttv.w * b1v[nt]);
            store4bf(&t_sb[hl * 72 + mt * 16 + q * 4], v0, v1, v2, v3);
        }
    }
    __syncthreads();

    // ---- P = Q^T T : M=32(j) x N=32(h/wave) x K=64(m) ----
    f32x4 pacc[2][2] = {};
    const unsigned short* QT = (const unsigned short*)(ws + OFF_QT_BF);
    #pragma unroll
    for (int ks = 0; ks < 2; ks++) {
        bf16x8 bt[2];
        #pragma unroll
        for (int nt = 0; nt < 2; nt++)
            bt[nt] = *(const bf16x8*)(&t_sb[(w * 32 + nt * 16 + l15) * 72 + ks * 32 + q * 8]);
        #pragma unroll
        for (int jt = 0; jt < 2; jt++) {
            bf16x8 aq = *(const bf16x8*)(QT + (jt * 16 + l15) * 64 + ks * 32 + q * 8);
            pacc[jt][0] = __builtin_amdgcn_mfma_f32_16x16x32_bf16(aq, bt[0], pacc[jt][0], 0, 0, 0);
            pacc[jt][1] = __builtin_amdgcn_mfma_f32_16x16x32_bf16(aq, bt[1], pacc[jt][1], 0, 0, 0);
        }
    }

    // store P_t[b][j][h] bf16
    #pragma unroll
    for (int jt = 0; jt < 2; jt++)
        #pragma unroll
        for (int nt = 0; nt < 2; nt++) {
            int hg = hw + nt * 16 + l15;
            #pragma unroll
            for (int r = 0; r < 4; r++) {
                int j = jt * 16 + q * 4 + r;
                Pt[((size_t)b * NB + j) * HH + hg] = f2bf(pacc[jt][nt][r]);
            }
        }
}

// ---------------------------------------------------------------------------
// K2: Bn[b,d,j] = sum_h P[b,h,j] W2[h,d] + y u[j]  via MFMA.
// Grid 1024 blocks (8 dblk x 128 b) = 4 blocks/CU (was 512 = 2/CU, half-idle).
// Each wave: one 16-d tile; A = Pt[b] staged in two 32x512 LDS chunks (swz);
// B from frag-packed W2p (contiguous 1KB wave-reads). Bn only on last iter.
// Per-output K-accumulation order identical to R6 -> bitwise-same results.
// ---------------------------------------------------------------------------
__global__ __launch_bounds__(256) void k2_kernel(
        const unsigned short* __restrict__ Pt,   // [B][32 j][1024 h] bf16
        const unsigned short* __restrict__ W2p,  // frag-packed
        const float* __restrict__ y_init,        // [B][512]
        const float* __restrict__ ws,
        float* __restrict__ Bn,                  // [B][512][32] fp32 (last iter)
        unsigned short* __restrict__ Bct,        // [B][32][512] bf16 (next iter)
        int last)
{
    __shared__ __align__(16) char smem[32768];
    unsigned short* smA = (unsigned short*)smem;   // A chunk [32][512] swz
    float*          ls  = (float*)smem;            // 4x[32*17] f32 (epilogue overlay)

    const int t    = threadIdx.x;
    const int lane = t & 63;
    const int w    = t >> 6;
    const int q    = lane >> 4;
    const int l15  = lane & 15;
    const int b    = blockIdx.y;
    const int dblk = blockIdx.x;        // 0..7
    const int dw   = dblk * 64 + w * 16;

    f32x4 acc[2] = {};                  // [j-tile]; wave owns one 16-d tile
    const unsigned short* W2b = W2p + (size_t)(dblk * 4 + w) * 16384;  // db tile base
    #pragma unroll 1
    for (int chunk = 0; chunk < 2; chunk++) {
        // stage A chunk: Pt[b][j][chunk*512 .. +512)
        {
            const unsigned short* A0 = Pt + (size_t)b * NB * HH + chunk * 512;
            #pragma unroll
            for (int i = 0; i < 8; i++) {
                int c = i * 256 + t;
                int r = c >> 6, c16 = c & 63;
                bf16x8 v = *(const bf16x8*)(A0 + (size_t)r * HH + c16 * 8);
                *(bf16x8*)aS(smA, r, c16) = v;
            }
        }
        __syncthreads();
        #pragma unroll 4
        for (int hc = 0; hc < 512; hc += 32) {
            int c16 = (hc >> 3) + q;
            bf16x8 a0 = *(const bf16x8*)aS(smA, l15, c16);
            bf16x8 a1 = *(const bf16x8*)aS(smA, 16 + l15, c16);
            bf16x8 bb = *(const bf16x8*)(W2b + (chunk * 16 + (hc >> 5)) * 512 + lane * 8);
            acc[0] = __builtin_amdgcn_mfma_f32_16x16x32_bf16(a0, bb, acc[0], 0, 0, 0);
            acc[1] = __builtin_amdgcn_mfma_f32_16x16x32_bf16(a1, bb, acc[1], 0, 0, 0);
        }
        __syncthreads();   // A_s safe to restage / overlay
    }

    // epilogue: add y*u; non-last -> Bct bf16; last -> stage + fp32 Bn
    const float* U = ws + OFF_U;
    float yv = y_init[(size_t)b * DD + dw + l15];
    #pragma unroll
    for (int mt = 0; mt < 2; mt++) {
        float4 uv = *(const float4*)(U + mt * 16 + q * 4);
        #pragma unroll
        for (int r = 0; r < 4; r++) {
            int j = mt * 16 + q * 4 + r;
            float uvr = (r == 0) ? uv.x : (r == 1) ? uv.y : (r == 2) ? uv.z : uv.w;
            float val = acc[mt][r] + yv * uvr;
            if (!last) Bct[((size_t)b * NB + j) * DD + dw + l15] = f2bf(val);
            else       ls[w * 544 + j * 17 + l15] = val;
        }
    }
    if (last) {
        __syncthreads();
        // coalesced fp32 Bn write: [b][d][j], wave covers its 16 d x 32 j
        #pragma unroll
        for (int it = 0; it < 8; it++) {
            int f = it * 64 + lane;
            int d_l = f >> 5, j2 = f & 31;    // d_l 0..15
            Bn[((size_t)b * DD + dw + d_l) * NB + j2] = ls[w * 544 + j2 * 17 + d_l];
        }
    }
}

// ---------------------------------------------------------------------------
// K3: out0[t,b,d] = sum_n Bn[b,d,n]*Phi_out[n,t] ; out1 = Bn
// ---------------------------------------------------------------------------
__global__ __launch_bounds__(256) void k3_kernel(
        const float* __restrict__ ws_c, float* __restrict__ out) {
    __shared__ float rows_s[64 * 33];
    __shared__ float phiout_s[NB * TT];

    const int t = threadIdx.x;
    const int r0 = blockIdx.x * 64;
    const float* Bf = ws_c + OFF_BN;

    for (int f = t; f < NB * TT; f += 256) phiout_s[f] = ws_c[OFF_PHIOUT + f];

    float vals[8];
    {
        int f = t;
        #pragma unroll
        for (int i = 0; i < 8; i++, f += 256) {
            float v = Bf[(size_t)r0 * NB + f];
            rows_s[(f >> 5) * 33 + (f & 31)] = v;
            vals[i] = v;
        }
    }
    float* out1 = out + (size_t)TT * BB * DD;
    {
        int f = t;
        #pragma unroll
        for (int i = 0; i < 8; i++, f += 256) out1[(size_t)r0 * NB + f] = vals[i];
    }
    __syncthreads();

    #pragma unroll
    for (int i = 0; i < 4; i++) {
        int idx = i * 256 + t;
        int tt = idx >> 6, rl = idx & 63;
        float s = 0.f;
        #pragma unroll
        for (int n = 0; n < NB; n++)
            s += rows_s[rl * 33 + n] * phiout_s[n * TT + tt];
        out[(size_t)tt * (BB * DD) + r0 + rl] = s;
    }
}

// ---------------------------------------------------------------------------
extern "C" void kernel_launch(void* const* d_in, const int* in_sizes, int n_in,
                              void* d_out, int out_size, void* d_ws, size_t ws_size,
                              hipStream_t stream) {
    const float* t_span = (const float*)d_in[0];
    const float* y_init = (const float*)d_in[1];
    const float* B_init = (const float*)d_in[2];
    const float* W1     = (const float*)d_in[3];
    const float* b1     = (const float*)d_in[4];
    const float* W2     = (const float*)d_in[5];
    float* ws  = (float*)d_ws;
    float* out = (float*)d_out;

    unsigned short* W1p = (unsigned short*)(ws + OFF_W1P);
    unsigned short* W2p = (unsigned short*)(ws + OFF_W2P);
    unsigned short* Bct = (unsigned short*)(ws + OFF_BCT);
    unsigned short* Pt  = (unsigned short*)(ws + OFF_PT);
    float*          Bn  = ws + OFF_BN;

    setup_kernel<<<1, 256, 0, stream>>>(t_span, ws);
    pack_w1<<<dim3(64), 256, 0, stream>>>(W1, W1p);
    pack_w2<<<dim3(32), 256, 0, stream>>>(W2, W2p);
    binit_kernel<<<dim3(DD / 32, BB), 256, 0, stream>>>(B_init, Bct);

    for (int it = 0; it < ITERS; it++) {
        k1_kernel<<<dim3(HH / 128, BB), 256, 0, stream>>>(Bct, W1p, b1, ws, Pt);
        k2_kernel<<<dim3(8, BB), 256, 0, stream>>>(Pt, W2p, y_init, ws, Bn, Bct,
                                                   it == ITERS - 1 ? 1 : 0);
    }
    k3_kernel<<<dim3((BB * DD) / 64), 256, 0, stream>>>(ws, out);
}

// Round 10
// 461.377 us; speedup vs baseline: 8.6311x; 1.0149x over previous
//
#include <hip/hip_runtime.h>
#include <hip/hip_bf16.h>
#include <math.h>

// Problem constants (fixed by setup_inputs)
#define BB 128
#define DD 512
#define HH 1024
#define NB 32     // num_coeff_per_dim
#define MM 63     // 2N-1 simpson points
#define TT 16
#define ITERS 10

// ws layout (float units)
#define OFF_U       0        // 32 fp32
#define OFF_TTRUE   64       // 64 fp32 (tt[63]=0)
#define OFF_PHIOUT  128      // 512 fp32
#define OFF_PHIF_BF 1024     // bf16 [64 m][32 n]  (row 63 = 0)   = 1024 floats
#define OFF_QT_BF   2048     // bf16 [32 j][64 m]  (col 63 = 0)   = 1024 floats
#define HDRF        4096
#define OFF_BN      HDRF                     // fp32 [B][512][32]  = 2097152
#define OFF_BCP     (OFF_BN + 2097152)       // bf16 frag-packed [B][16 ds][2 mt][64][8] = 1048576 f
#define OFF_PTP     (OFF_BCP + 1048576)      // bf16 frag-packed [B][32 hs][2 mt][64][8] = 2097152 f
#define OFF_W1P     (OFF_PTP + 2097152)      // bf16 frag-packed [64 hb][16 ds][64][8] = 262144 f
#define OFF_W2P     (OFF_W1P + 262144)       // bf16 frag-packed [32 db][32 hs][64][8] = 262144 f
// end = 5771264 floats = 23.1 MB

typedef __attribute__((ext_vector_type(8))) short bf16x8;
typedef __attribute__((ext_vector_type(4))) float f32x4;

static __device__ __forceinline__ unsigned short f2bf(float f) {
    unsigned int x = __builtin_bit_cast(unsigned int, f);
    unsigned int r = x + 0x7FFFu + ((x >> 16) & 1u);   // RNE
    return (unsigned short)(r >> 16);
}

static __device__ __forceinline__ void store4bf(unsigned short* p,
                                                float v0, float v1, float v2, float v3) {
    unsigned int lo = (unsigned int)f2bf(v0) | ((unsigned int)f2bf(v1) << 16);
    unsigned int hi = (unsigned int)f2bf(v2) | ((unsigned int)f2bf(v3) << 16);
    uint2 u; u.x = lo; u.y = hi;
    *(uint2*)p = u;   // 8B-aligned by construction
}

static __device__ __forceinline__ float tanh_fast(float x) {
    float e = exp2f(x * 2.88539008177793f);   // 2*log2(e)
    return 1.0f - 2.0f / (e + 1.0f);
}

// ---------------------------------------------------------------------------
// Setup: t grids, Phi_f, Phi_inv (double GJ, wave-parallel), Q = R@Phi_inv,
// u, Phi_out, bf16 tables.
// ---------------------------------------------------------------------------
__global__ __launch_bounds__(256) void setup_kernel(const float* __restrict__ t_span,
                                                    float* __restrict__ ws) {
    __shared__ double tsim[MM];
    __shared__ double ttrue_d[MM];
    __shared__ double wid[31];
    __shared__ double phid[NB * MM];   // [n][m]
    __shared__ double aug[NB * 64];    // [Phi | I]
    __shared__ double mlt[NB];
    __shared__ double Rl[MM * NB];
    __shared__ double Qd[MM * NB];     // [m][j]
    __shared__ int    piv_s;

    const int t    = threadIdx.x;  // 256 threads
    const int lane = t & 63;
    const int rgrp = t >> 6;
    const double PI = 3.14159265358979323846;
    const double t0 = (double)t_span[0];
    const double t1 = (double)t_span[TT - 1];

    if (t < MM) {
        double v;
        if ((t & 1) == 0) {
            int j = t >> 1;
            v = -cos(PI * (double)j / (double)(NB - 1));
        } else {
            int i = t >> 1;
            double a = -cos(PI * (double)i / (double)(NB - 1));
            double b = -cos(PI * (double)(i + 1) / (double)(NB - 1));
            v = 0.5 * (a + b);
        }
        tsim[t] = v;
        ttrue_d[t] = t0 + 0.5 * (t1 - t0) * (v + 1.0);
    }
    __syncthreads();
    if (t < 31) wid[t] = (ttrue_d[2 * t + 2] - ttrue_d[2 * t]) / 6.0;
    if (t < MM) ws[OFF_TTRUE + t] = (float)ttrue_d[t];
    if (t == 63) ws[OFF_TTRUE + 63] = 0.0f;

    if (t < MM) {
        double x = tsim[t];
        double r0 = 1.0, r1 = x;
        phid[0 * MM + t] = r0;
        phid[1 * MM + t] = r1;
        for (int n = 2; n < NB; n++) {
            double r2 = 2.0 * x * r1 - r0;
            phid[n * MM + t] = r2;
            r0 = r1; r1 = r2;
        }
    }
    __syncthreads();

    {   // phif_bf [m 64][n 32], row 63 = 0
        unsigned short* pf = (unsigned short*)(ws + OFF_PHIF_BF);
        for (int f = t; f < 64 * 32; f += 256) {
            int m = f >> 5, n = f & 31;
            pf[f] = f2bf(m < MM ? (float)phid[n * MM + m] : 0.0f);
        }
    }

    for (int f = t; f < NB * 64; f += 256) {
        int r = f >> 6, c = f & 63;
        double v;
        if (c < NB) v = phid[r * MM + 2 * c];
        else        v = ((c - NB) == r) ? 1.0 : 0.0;
        aug[f] = v;
    }
    __syncthreads();

    for (int k = 0; k < NB; k++) {
        if (t < 32) {
            double v = (t >= k) ? fabs(aug[t * 64 + k]) : -1.0;
            int idx = t;
            #pragma unroll
            for (int off = 16; off >= 1; off >>= 1) {
                double ov = __shfl_xor(v, off);
                int    oi = __shfl_xor(idx, off);
                if (ov > v) { v = ov; idx = oi; }
            }
            if (t == 0) piv_s = idx;
        }
        __syncthreads();
        const int p = piv_s;
        if (t < 64) {
            double pv   = aug[p * 64 + k];
            double rowp = aug[p * 64 + t];
            double rowk = aug[k * 64 + t];
            aug[k * 64 + t] = rowp / pv;
            if (p != k) aug[p * 64 + t] = rowk;
        }
        __syncthreads();
        if (t < 32) mlt[t] = (t == k) ? 0.0 : aug[t * 64 + k];
        __syncthreads();
        {
            double pk = aug[k * 64 + lane];
            #pragma unroll
            for (int i = 0; i < 8; i++) {
                int r = rgrp * 8 + i;
                aug[r * 64 + lane] -= mlt[r] * pk;
            }
        }
        __syncthreads();
    }

    if (t < MM) {
        double acc = 0.0;
        Rl[t * NB + 0] = 0.0;
        for (int i = 1; i < NB; i++) {
            int ip = i - 1;
            double w = 0.0;
            if (t == 2 * ip)     w += wid[ip];
            if (t == 2 * ip + 1) w += 4.0 * wid[ip];
            if (t == 2 * ip + 2) w += wid[ip];
            acc += w;
            Rl[t * NB + i] = acc;
        }
    }
    __syncthreads();

    for (int f = t; f < MM * NB; f += 256) {
        int m = f >> 5, j = f & 31;
        double s = 0.0;
        for (int i = 0; i < NB; i++) s += Rl[m * NB + i] * aug[i * 64 + 32 + j];
        Qd[f] = s;
    }
    __syncthreads();

    {   // qt_bf [j 32][m 64], col 63 = 0
        unsigned short* qt = (unsigned short*)(ws + OFF_QT_BF);
        for (int f = t; f < 32 * 64; f += 256) {
            int j = f >> 6, m = f & 63;
            qt[f] = f2bf(m < MM ? (float)Qd[m * NB + j] : 0.0f);
        }
    }
    if (t < NB) {
        double s = 0.0;
        for (int i = 0; i < NB; i++) s += aug[i * 64 + 32 + t];
        ws[OFF_U + t] = (float)s;
    }
    if (t < TT) {
        double x = -1.0 + 2.0 * ((double)t_span[t] - t0) / (t1 - t0);
        double r0 = 1.0, r1 = x;
        ws[OFF_PHIOUT + 0 * TT + t] = 1.0f;
        ws[OFF_PHIOUT + 1 * TT + t] = (float)x;
        for (int n = 2; n < NB; n++) {
            double r2 = 2.0 * x * r1 - r0;
            ws[OFF_PHIOUT + n * TT + t] = (float)r2;
            r0 = r1; r1 = r2;
        }
    }
}

// ---------------------------------------------------------------------------
// pack_w1: W1 fp32 [512 d][1024 h] -> W1p bf16 [64 hb][16 ds][64 lane][8 e]
// W1p[hb][ds][q*16+l15][e] = bf16(W1[(ds*32+q*8+e)][hb*16+l15])
// ---------------------------------------------------------------------------
__global__ __launch_bounds__(256) void pack_w1(
        const float* __restrict__ W1, unsigned short* __restrict__ W1p) {
    const int hb = blockIdx.x;    // 0..63
    const int t  = threadIdx.x;
    #pragma unroll
    for (int i = 0; i < 4; i++) {
        int f = i * 256 + t;               // fragment 0..1023
        int ds = f >> 6, lane = f & 63;
        int q = lane >> 4, l15 = lane & 15;
        unsigned short tmp[8];
        #pragma unroll
        for (int e = 0; e < 8; e++)
            tmp[e] = f2bf(W1[(size_t)(ds * 32 + q * 8 + e) * HH + hb * 16 + l15]);
        *(uint4*)(W1p + ((size_t)(hb * 16 + ds) * 64 + lane) * 8) = *(uint4*)tmp;
    }
}

// pack_w2: W2 fp32 [1024 h][512 d] -> W2p bf16 [32 db][32 hs][64 lane][8 e]
// W2p[db][hs][q*16+l15][e] = bf16(W2[(hs*32+q*8+e)][db*16+l15])
__global__ __launch_bounds__(256) void pack_w2(
        const float* __restrict__ W2, unsigned short* __restrict__ W2p) {
    const int db = blockIdx.x;    // 0..31
    const int t  = threadIdx.x;
    #pragma unroll
    for (int i = 0; i < 8; i++) {
        int f = i * 256 + t;               // fragment 0..2047
        int hs = f >> 6, lane = f & 63;
        int q = lane >> 4, l15 = lane & 15;
        unsigned short tmp[8];
        #pragma unroll
        for (int e = 0; e < 8; e++)
            tmp[e] = f2bf(W2[(size_t)(hs * 32 + q * 8 + e) * DD + db * 16 + l15]);
        *(uint4*)(W2p + ((size_t)(db * 32 + hs) * 64 + lane) * 8) = *(uint4*)tmp;
    }
}

// ---------------------------------------------------------------------------
// binit_pack: B_init [b][d][n] fp32 -> Bcp frag-packed
// Bcp[b][ds][mt][q*16+l15][e] = bf16(Bc[n = mt*16+l15][d = ds*32+q*8+e])
// ---------------------------------------------------------------------------
__global__ __launch_bounds__(256) void binit_pack(
        const float* __restrict__ Bi, unsigned short* __restrict__ Bcp) {
    __shared__ float tile[32 * 33];
    const int t  = threadIdx.x;
    const int b  = blockIdx.y, ds = blockIdx.x;   // ds 0..15
    #pragma unroll
    for (int i = 0; i < 4; i++) {
        int f = i * 256 + t;
        int dd = f >> 5, n = f & 31;
        tile[dd * 33 + n] = Bi[((size_t)b * DD + ds * 32 + dd) * NB + n];
    }
    __syncthreads();
    if (t < 128) {
        int mt = t >> 6, lane = t & 63;
        int q = lane >> 4, l15 = lane & 15;
        unsigned short tmp[8];
        #pragma unroll
        for (int e = 0; e < 8; e++)
            tmp[e] = f2bf(tile[(q * 8 + e) * 33 + mt * 16 + l15]);
        *(uint4*)(Bcp + (size_t)b * 16384 + ((size_t)(ds * 2 + mt) * 64 + lane) * 8)
            = *(uint4*)tmp;
    }
}

// ---------------------------------------------------------------------------
// K1: per block (b, 128 h). A from frag-packed Bcp (contiguous 1KB wave
// reads, no LDS staging). g_sb/t_sb are wave-private -> ZERO __syncthreads.
// Epilogue packs P into k2's A-fragment layout via wave-private LDS bounce
// (g_sb region, dead after Z), then 2x16B coalesced global store.
// LDS: t_sb 18432 + g_sb 8192 = 26624 B.
// ---------------------------------------------------------------------------
__global__ __launch_bounds__(256) void k1_kernel(
        const unsigned short* __restrict__ Bcp,  // [B][16 ds][2 mt][64][8] bf16
        const unsigned short* __restrict__ W1p,  // frag-packed
        const float* __restrict__ b1,            // [1024]
        const float* __restrict__ ws,
        unsigned short* __restrict__ Ptp)        // [B][32 hs][2 mt][64][8] bf16
{
    __shared__ __align__(16) unsigned short t_sb[128 * 72];  // wave-private rows
    __shared__ __align__(16) unsigned short g_sb[128 * 32];  // wave-private; P-bounce later

    const int t    = threadIdx.x;
    const int lane = t & 63;
    const int w    = t >> 6;       // wave 0..3
    const int q    = lane >> 4;    // quad 0..3
    const int l15  = lane & 15;
    const int b    = blockIdx.y;
    const int hblk = blockIdx.x;
    const int hw   = hblk * 128 + w * 32;   // wave's global h base

    // ---- Phase A: G = A W1^T, M=32(n) x N=32(h/wave) x K=512 ----
    f32x4 acc[2][2] = {};
    const unsigned short* Ab  = Bcp + (size_t)b * 16384;
    const unsigned short* W1b = W1p + (size_t)(hw >> 4) * 8192;   // hb0 tile base
    #pragma unroll 4
    for (int ds = 0; ds < 16; ds++) {
        bf16x8 a0  = *(const bf16x8*)(Ab + (ds * 2 + 0) * 512 + lane * 8);
        bf16x8 a1  = *(const bf16x8*)(Ab + (ds * 2 + 1) * 512 + lane * 8);
        bf16x8 bb0 = *(const bf16x8*)(W1b + ds * 512 + lane * 8);
        bf16x8 bb1 = *(const bf16x8*)(W1b + 8192 + ds * 512 + lane * 8);
        acc[0][0] = __builtin_amdgcn_mfma_f32_16x16x32_bf16(a0, bb0, acc[0][0], 0, 0, 0);
        acc[0][1] = __builtin_amdgcn_mfma_f32_16x16x32_bf16(a0, bb1, acc[0][1], 0, 0, 0);
        acc[1][0] = __builtin_amdgcn_mfma_f32_16x16x32_bf16(a1, bb0, acc[1][0], 0, 0, 0);
        acc[1][1] = __builtin_amdgcn_mfma_f32_16x16x32_bf16(a1, bb1, acc[1][1], 0, 0, 0);
    }
    // write G to g_sb[h_loc][n] bf16 (wave-private rows)
    #pragma unroll
    for (int mt = 0; mt < 2; mt++)
        #pragma unroll
        for (int nt = 0; nt < 2; nt++) {
            int hl = w * 32 + nt * 16 + l15;
            store4bf(&g_sb[hl * 32 + mt * 16 + q * 4],
                     acc[mt][nt][0], acc[mt][nt][1], acc[mt][nt][2], acc[mt][nt][3]);
        }

    // ---- Z = Phi_f^T G : M=64(m) x N=32(h/wave) x K=32(n) ----
    f32x4 zacc[4][2] = {};
    const unsigned short* PF = (const unsigned short*)(ws + OFF_PHIF_BF);
    bf16x8 gb[2];
    #pragma unroll
    for (int nt = 0; nt < 2; nt++)
        gb[nt] = *(const bf16x8*)(&g_sb[(w * 32 + nt * 16 + l15) * 32 + q * 8]);
    #pragma unroll
    for (int mt = 0; mt < 4; mt++) {
        bf16x8 af = *(const bf16x8*)(PF + (mt * 16 + l15) * 32 + q * 8);
        zacc[mt][0] = __builtin_amdgcn_mfma_f32_16x16x32_bf16(af, gb[0], zacc[mt][0], 0, 0, 0);
        zacc[mt][1] = __builtin_amdgcn_mfma_f32_16x16x32_bf16(af, gb[1], zacc[mt][1], 0, 0, 0);
    }

    // bias + tanh + write t_sb[h_loc][m] bf16 (wave-private rows)
    const float* TTp = ws + OFF_TTRUE;
    float b1v[2] = { b1[hw + l15], b1[hw + 16 + l15] };
    #pragma unroll
    for (int mt = 0; mt < 4; mt++) {
        float4 ttv = *(const float4*)(TTp + mt * 16 + q * 4);
        #pragma unroll
        for (int nt = 0; nt < 2; nt++) {
            int hl = w * 32 + nt * 16 + l15;
            float v0 = tanh_fast(zacc[mt][nt][0] + ttv.x * b1v[nt]);
            float v1 = tanh_fast(zacc[mt][nt][1] + ttv.y * b1v[nt]);
            float v2 = tanh_fast(zacc[mt][nt][2] + ttv.z * b1v[nt]);
            float v3 = tanh_fast(zacc[mt][nt][3] + ttv.w * b1v[nt]);
            store4bf(&t_sb[hl * 72 + mt * 16 + q * 4], v0, v1, v2, v3);
        }
    }

    // ---- P = Q^T T : M=32(j) x N=32(h/wave) x K=64(m) ----
    f32x4 pacc[2][2] = {};
    const unsigned short* QT = (const unsigned short*)(ws + OFF_QT_BF);
    #pragma unroll
    for (int ks = 0; ks < 2; ks++) {
        bf16x8 bt[2];
        #pragma unroll
        for (int nt = 0; nt < 2; nt++)
            bt[nt] = *(const bf16x8*)(&t_sb[(w * 32 + nt * 16 + l15) * 72 + ks * 32 + q * 8]);
        #pragma unroll
        for (int jt = 0; jt < 2; jt++) {
            bf16x8 aq = *(const bf16x8*)(QT + (jt * 16 + l15) * 64 + ks * 32 + q * 8);
            pacc[jt][0] = __builtin_amdgcn_mfma_f32_16x16x32_bf16(aq, bt[0], pacc[jt][0], 0, 0, 0);
            pacc[jt][1] = __builtin_amdgcn_mfma_f32_16x16x32_bf16(aq, bt[1], pacc[jt][1], 0, 0, 0);
        }
    }

    // ---- pack P -> Ptp[b][hs][mt][lane][e] via wave-private bounce ----
    // element (j = jt*16+q*4+r, h = hw + nt*16 + l15):
    //   lane8 = ((nt*2 + (l15>>3)) & 3)*16 + q*4 + r ; e = l15 & 7
    {
        unsigned short* pb = g_sb + w * 1024;   // wave's 2KB region (dead after Z)
        #pragma unroll
        for (int jt = 0; jt < 2; jt++)
            #pragma unroll
            for (int nt = 0; nt < 2; nt++) {
                int grp = (nt * 2 + (l15 >> 3)) & 3;
                #pragma unroll
                for (int r = 0; r < 4; r++) {
                    int lane8 = grp * 16 + q * 4 + r;
                    pb[(jt * 64 + lane8) * 8 + (l15 & 7)] = f2bf(pacc[jt][nt][r]);
                }
            }
        // same-wave LDS RAW: compiler orders via lgkmcnt (no cross-wave sharing)
        int hs = hblk * 4 + w;
        uint4 f0 = *(uint4*)(pb + (0 * 64 + lane) * 8);
        uint4 f1 = *(uint4*)(pb + (1 * 64 + lane) * 8);
        *(uint4*)(Ptp + (((size_t)(b * 32 + hs) * 2 + 0) * 64 + lane) * 8) = f0;
        *(uint4*)(Ptp + (((size_t)(b * 32 + hs) * 2 + 1) * 64 + lane) * 8) = f1;
    }
}

// ---------------------------------------------------------------------------
// K2: Bn[b,d,j] = sum_h P[b,h,j] W2[h,d] + y u[j]. Pure streaming GEMM:
// A from frag-packed Ptp, B from frag-packed W2p -- all contiguous 1KB wave
// reads, ZERO LDS / syncs in the K-loop. Grid (8 dblk,128 b) = 4 blocks/CU.
// Epilogue: non-last -> pack into Bcp (k1's A-frag layout) via 4KB LDS
// bounce + coalesced 16B stores; last -> fp32 Bn via ls staging.
// ---------------------------------------------------------------------------
__global__ __launch_bounds__(256) void k2_kernel(
        const unsigned short* __restrict__ Ptp,  // [B][32 hs][2 mt][64][8] bf16
        const unsigned short* __restrict__ W2p,  // frag-packed
        const float* __restrict__ y_init,        // [B][512]
        const float* __restrict__ ws,
        float* __restrict__ Bn,                  // [B][512][32] fp32 (last iter)
        unsigned short* __restrict__ Bcp,        // frag-packed (next iter)
        int last)
{
    __shared__ __align__(16) float ls[4 * 544];  // 8704B; bounce overlay (4KB) on non-last

    const int t    = threadIdx.x;
    const int lane = t & 63;
    const int w    = t >> 6;
    const int q    = lane >> 4;
    const int l15  = lane & 15;
    const int b    = blockIdx.y;
    const int dblk = blockIdx.x;        // 0..7
    const int dw   = dblk * 64 + w * 16;

    f32x4 acc[2] = {};                  // [j-tile]; wave owns one 16-d tile
    const unsigned short* Ab  = Ptp + (size_t)b * 32768;
    const unsigned short* W2b = W2p + (size_t)(dblk * 4 + w) * 16384;
    #pragma unroll 4
    for (int s = 0; s < 32; s++) {
        bf16x8 a0 = *(const bf16x8*)(Ab + (s * 2 + 0) * 512 + lane * 8);
        bf16x8 a1 = *(const bf16x8*)(Ab + (s * 2 + 1) * 512 + lane * 8);
        bf16x8 bb = *(const bf16x8*)(W2b + s * 512 + lane * 8);
        acc[0] = __builtin_amdgcn_mfma_f32_16x16x32_bf16(a0, bb, acc[0], 0, 0, 0);
        acc[1] = __builtin_amdgcn_mfma_f32_16x16x32_bf16(a1, bb, acc[1], 0, 0, 0);
    }

    // epilogue: val = acc + y*u
    const float* U = ws + OFF_U;
    float yv = y_init[(size_t)b * DD + dw + l15];
    if (!last) {
        // pack into Bcp[b][ds][mtA][lane8][e]:
        // d = dw + l15 -> ds = dblk*2 + (w>>1); lane8 = ((w*2 + (l15>>3))&3)*16 + q*4+r; e = l15&7
        unsigned short* bl = (unsigned short*)ls;   // 4KB bounce: [2 ds_loc][2 mt][64][8]
        const int ds_loc = w >> 1;
        const int grp    = (w * 2 + (l15 >> 3)) & 3;
        #pragma unroll
        for (int mt = 0; mt < 2; mt++) {
            float4 uv = *(const float4*)(U + mt * 16 + q * 4);
            #pragma unroll
            for (int r = 0; r < 4; r++) {
                float uvr = (r == 0) ? uv.x : (r == 1) ? uv.y : (r == 2) ? uv.z : uv.w;
                float val = acc[mt][r] + yv * uvr;
                int lane8 = grp * 16 + q * 4 + r;
                bl[((ds_loc * 2 + mt) * 64 + lane8) * 8 + (l15 & 7)] = f2bf(val);
            }
        }
        __syncthreads();
        // readback: thread t -> fragment (ds_loc', mtA, lane') = decomposition of t
        uint4 v = *(uint4*)(bl + t * 8);
        int dsl = t >> 7, mtA = (t >> 6) & 1, ln = t & 63;
        *(uint4*)(Bcp + (size_t)b * 16384
                  + ((size_t)((dblk * 2 + dsl) * 2 + mtA) * 64 + ln) * 8) = v;
    } else {
        #pragma unroll
        for (int mt = 0; mt < 2; mt++) {
            float4 uv = *(const float4*)(U + mt * 16 + q * 4);
            #pragma unroll
            for (int r = 0; r < 4; r++) {
                int j = mt * 16 + q * 4 + r;
                float uvr = (r == 0) ? uv.x : (r == 1) ? uv.y : (r == 2) ? uv.z : uv.w;
                float val = acc[mt][r] + yv * uvr;
                ls[w * 544 + j * 17 + l15] = val;
            }
        }
        __syncthreads();
        // coalesced fp32 Bn write: [b][d][j], wave covers its 16 d x 32 j
        #pragma unroll
        for (int it = 0; it < 8; it++) {
            int f = it * 64 + lane;
            int d_l = f >> 5, j2 = f & 31;    // d_l 0..15
            Bn[((size_t)b * DD + dw + d_l) * NB + j2] = ls[w * 544 + j2 * 17 + d_l];
        }
    }
}

// ---------------------------------------------------------------------------
// K3: out0[t,b,d] = sum_n Bn[b,d,n]*Phi_out[n,t] ; out1 = Bn
// ---------------------------------------------------------------------------
__global__ __launch_bounds__(256) void k3_kernel(
        const float* __restrict__ ws_c, float* __restrict__ out) {
    __shared__ float rows_s[64 * 33];
    __shared__ float phiout_s[NB * TT];

    const int t = threadIdx.x;
    const int r0 = blockIdx.x * 64;
    const float* Bf = ws_c + OFF_BN;

    for (int f = t; f < NB * TT; f += 256) phiout_s[f] = ws_c[OFF_PHIOUT + f];

    float vals[8];
    {
        int f = t;
        #pragma unroll
        for (int i = 0; i < 8; i++, f += 256) {
            float v = Bf[(size_t)r0 * NB + f];
            rows_s[(f >> 5) * 33 + (f & 31)] = v;
            vals[i] = v;
        }
    }
    float* out1 = out + (size_t)TT * BB * DD;
    {
        int f = t;
        #pragma unroll
        for (int i = 0; i < 8; i++, f += 256) out1[(size_t)r0 * NB + f] = vals[i];
    }
    __syncthreads();

    #pragma unroll
    for (int i = 0; i < 4; i++) {
        int idx = i * 256 + t;
        int tt = idx >> 6, rl = idx & 63;
        float s = 0.f;
        #pragma unroll
        for (int n = 0; n < NB; n++)
            s += rows_s[rl * 33 + n] * phiout_s[n * TT + tt];
        out[(size_t)tt * (BB * DD) + r0 + rl] = s;
    }
}

// ---------------------------------------------------------------------------
extern "C" void kernel_launch(void* const* d_in, const int* in_sizes, int n_in,
                              void* d_out, int out_size, void* d_ws, size_t ws_size,
                              hipStream_t stream) {
    const float* t_span = (const float*)d_in[0];
    const float* y_init = (const float*)d_in[1];
    const float* B_init = (const float*)d_in[2];
    const float* W1     = (const float*)d_in[3];
    const float* b1     = (const float*)d_in[4];
    const float* W2     = (const float*)d_in[5];
    float* ws  = (float*)d_ws;
    float* out = (float*)d_out;

    unsigned short* W1p = (unsigned short*)(ws + OFF_W1P);
    unsigned short* W2p = (unsigned short*)(ws + OFF_W2P);
    unsigned short* Bcp = (unsigned short*)(ws + OFF_BCP);
    unsigned short* Ptp = (unsigned short*)(ws + OFF_PTP);
    float*          Bn  = ws + OFF_BN;

    setup_kernel<<<1, 256, 0, stream>>>(t_span, ws);
    pack_w1<<<dim3(64), 256, 0, stream>>>(W1, W1p);
    pack_w2<<<dim3(32), 256, 0, stream>>>(W2, W2p);
    binit_pack<<<dim3(16, BB), 256, 0, stream>>>(B_init, Bcp);

    for (int it = 0; it < ITERS; it++) {
        k1_kernel<<<dim3(HH / 128, BB), 256, 0, stream>>>(Bcp, W1p, b1, ws, Ptp);
        k2_kernel<<<dim3(8, BB), 256, 0, stream>>>(Ptp, W2p, y_init, ws, Bn, Bcp,
                                                   it == ITERS - 1 ? 1 : 0);
    }
    k3_kernel<<<dim3((BB * DD) / 64), 256, 0, stream>>>(ws, out);
}

// Round 11
// 417.398 us; speedup vs baseline: 9.5406x; 1.1054x over previous
//
#include <hip/hip_runtime.h>
#include <hip/hip_bf16.h>
#include <math.h>

// Problem constants (fixed by setup_inputs)
#define BB 128
#define DD 512
#define HH 1024
#define NB 32     // num_coeff_per_dim
#define MM 63     // 2N-1 simpson points
#define TT 16
#define ITERS 10

// ws layout (float units)
#define OFF_U       0        // 32 fp32
#define OFF_TTRUE   64       // 64 fp32 (tt[63]=0)
#define OFF_PHIOUT  128      // 512 fp32
#define OFF_PHIF_BF 1024     // bf16 [64 m][32 n]  (row 63 = 0)   = 1024 floats
#define OFF_QT_BF   2048     // bf16 [32 j][64 m]  (col 63 = 0)   = 1024 floats
#define HDRF        4096
#define OFF_BN      HDRF                     // fp32 [B][512][32] = 2097152 f; doubles as Ptp_A
#define OFF_PTP0    (OFF_BN + 2097152)       // bf16 frag-packed [B][32 hs][2 mt][64][8] = 2097152 f
#define OFF_W1P     (OFF_PTP0 + 2097152)     // bf16 frag-packed [64 hb][16 ds][64][8] = 262144 f
#define OFF_W2P     (OFF_W1P + 262144)       // bf16 frag-packed [32 db][32 hs][64][8] = 262144 f
#define OFF_WWP     (OFF_W2P + 262144)       // bf16 frag-packed [64 h2b][32 hs][64][8] = 524288 f
#define OFF_YW1     (OFF_WWP + 524288)       // fp32 [128 b][1024 h2] = 131072 f
// end = 5378048 floats = 21.5 MB (< previous 23.1 MB layout)

typedef __attribute__((ext_vector_type(8))) short bf16x8;
typedef __attribute__((ext_vector_type(4))) float f32x4;

static __device__ __forceinline__ unsigned short f2bf(float f) {
    unsigned int x = __builtin_bit_cast(unsigned int, f);
    unsigned int r = x + 0x7FFFu + ((x >> 16) & 1u);   // RNE
    return (unsigned short)(r >> 16);
}

static __device__ __forceinline__ float bfr(float f) {   // round to bf16, back to f32
    unsigned int u = ((unsigned int)f2bf(f)) << 16;
    return __builtin_bit_cast(float, u);
}

static __device__ __forceinline__ void store4bf(unsigned short* p,
                                                float v0, float v1, float v2, float v3) {
    unsigned int lo = (unsigned int)f2bf(v0) | ((unsigned int)f2bf(v1) << 16);
    unsigned int hi = (unsigned int)f2bf(v2) | ((unsigned int)f2bf(v3) << 16);
    uint2 u; u.x = lo; u.y = hi;
    *(uint2*)p = u;   // 8B-aligned by construction
}

static __device__ __forceinline__ float tanh_fast(float x) {
    float e = exp2f(x * 2.88539008177793f);   // 2*log2(e)
    return 1.0f - 2.0f / (e + 1.0f);
}

// XOR-swizzled LDS A-tile addressing: tile [32 r][512 c] bf16, linear 32KB,
// byte = (r*1024 + c*2) ^ ((r&7)<<4). Bijective per row, 16B-aligned b128.
static __device__ __forceinline__ unsigned short* aS(unsigned short* smA, int r, int c16) {
    return (unsigned short*)((char*)smA + (((r << 10) + (c16 << 4)) ^ ((r & 7) << 4)));
}

// ---------------------------------------------------------------------------
// Setup: t grids, Phi_f, Phi_inv (double GJ, wave-parallel), Q = R@Phi_inv,
// u, Phi_out, bf16 tables.
// ---------------------------------------------------------------------------
__global__ __launch_bounds__(256) void setup_kernel(const float* __restrict__ t_span,
                                                    float* __restrict__ ws) {
    __shared__ double tsim[MM];
    __shared__ double ttrue_d[MM];
    __shared__ double wid[31];
    __shared__ double phid[NB * MM];   // [n][m]
    __shared__ double aug[NB * 64];    // [Phi | I]
    __shared__ double mlt[NB];
    __shared__ double Rl[MM * NB];
    __shared__ double Qd[MM * NB];     // [m][j]
    __shared__ int    piv_s;

    const int t    = threadIdx.x;  // 256 threads
    const int lane = t & 63;
    const int rgrp = t >> 6;
    const double PI = 3.14159265358979323846;
    const double t0 = (double)t_span[0];
    const double t1 = (double)t_span[TT - 1];

    if (t < MM) {
        double v;
        if ((t & 1) == 0) {
            int j = t >> 1;
            v = -cos(PI * (double)j / (double)(NB - 1));
        } else {
            int i = t >> 1;
            double a = -cos(PI * (double)i / (double)(NB - 1));
            double b = -cos(PI * (double)(i + 1) / (double)(NB - 1));
            v = 0.5 * (a + b);
        }
        tsim[t] = v;
        ttrue_d[t] = t0 + 0.5 * (t1 - t0) * (v + 1.0);
    }
    __syncthreads();
    if (t < 31) wid[t] = (ttrue_d[2 * t + 2] - ttrue_d[2 * t]) / 6.0;
    if (t < MM) ws[OFF_TTRUE + t] = (float)ttrue_d[t];
    if (t == 63) ws[OFF_TTRUE + 63] = 0.0f;

    if (t < MM) {
        double x = tsim[t];
        double r0 = 1.0, r1 = x;
        phid[0 * MM + t] = r0;
        phid[1 * MM + t] = r1;
        for (int n = 2; n < NB; n++) {
            double r2 = 2.0 * x * r1 - r0;
            phid[n * MM + t] = r2;
            r0 = r1; r1 = r2;
        }
    }
    __syncthreads();

    {   // phif_bf [m 64][n 32], row 63 = 0
        unsigned short* pf = (unsigned short*)(ws + OFF_PHIF_BF);
        for (int f = t; f < 64 * 32; f += 256) {
            int m = f >> 5, n = f & 31;
            pf[f] = f2bf(m < MM ? (float)phid[n * MM + m] : 0.0f);
        }
    }

    for (int f = t; f < NB * 64; f += 256) {
        int r = f >> 6, c = f & 63;
        double v;
        if (c < NB) v = phid[r * MM + 2 * c];
        else        v = ((c - NB) == r) ? 1.0 : 0.0;
        aug[f] = v;
    }
    __syncthreads();

    for (int k = 0; k < NB; k++) {
        if (t < 32) {
            double v = (t >= k) ? fabs(aug[t * 64 + k]) : -1.0;
            int idx = t;
            #pragma unroll
            for (int off = 16; off >= 1; off >>= 1) {
                double ov = __shfl_xor(v, off);
                int    oi = __shfl_xor(idx, off);
                if (ov > v) { v = ov; idx = oi; }
            }
            if (t == 0) piv_s = idx;
        }
        __syncthreads();
        const int p = piv_s;
        if (t < 64) {
            double pv   = aug[p * 64 + k];
            double rowp = aug[p * 64 + t];
            double rowk = aug[k * 64 + t];
            aug[k * 64 + t] = rowp / pv;
            if (p != k) aug[p * 64 + t] = rowk;
        }
        __syncthreads();
        if (t < 32) mlt[t] = (t == k) ? 0.0 : aug[t * 64 + k];
        __syncthreads();
        {
            double pk = aug[k * 64 + lane];
            #pragma unroll
            for (int i = 0; i < 8; i++) {
                int r = rgrp * 8 + i;
                aug[r * 64 + lane] -= mlt[r] * pk;
            }
        }
        __syncthreads();
    }

    if (t < MM) {
        double acc = 0.0;
        Rl[t * NB + 0] = 0.0;
        for (int i = 1; i < NB; i++) {
            int ip = i - 1;
            double w = 0.0;
            if (t == 2 * ip)     w += wid[ip];
            if (t == 2 * ip + 1) w += 4.0 * wid[ip];
            if (t == 2 * ip + 2) w += wid[ip];
            acc += w;
            Rl[t * NB + i] = acc;
        }
    }
    __syncthreads();

    for (int f = t; f < MM * NB; f += 256) {
        int m = f >> 5, j = f & 31;
        double s = 0.0;
        for (int i = 0; i < NB; i++) s += Rl[m * NB + i] * aug[i * 64 + 32 + j];
        Qd[f] = s;
    }
    __syncthreads();

    {   // qt_bf [j 32][m 64], col 63 = 0
        unsigned short* qt = (unsigned short*)(ws + OFF_QT_BF);
        for (int f = t; f < 32 * 64; f += 256) {
            int j = f >> 6, m = f & 63;
            qt[f] = f2bf(m < MM ? (float)Qd[m * NB + j] : 0.0f);
        }
    }
    if (t < NB) {
        double s = 0.0;
        for (int i = 0; i < NB; i++) s += aug[i * 64 + 32 + t];
        ws[OFF_U + t] = (float)s;
    }
    if (t < TT) {
        double x = -1.0 + 2.0 * ((double)t_span[t] - t0) / (t1 - t0);
        double r0 = 1.0, r1 = x;
        ws[OFF_PHIOUT + 0 * TT + t] = 1.0f;
        ws[OFF_PHIOUT + 1 * TT + t] = (float)x;
        for (int n = 2; n < NB; n++) {
            double r2 = 2.0 * x * r1 - r0;
            ws[OFF_PHIOUT + n * TT + t] = (float)r2;
            r0 = r1; r1 = r2;
        }
    }
}

// ---------------------------------------------------------------------------
// pack_w1: W1 fp32 [512 d][1024 h] -> W1p bf16 [64 hb][16 ds][64 lane][8 e]
// W1p[hb][ds][q*16+l15][e] = bf16(W1[(ds*32+q*8+e)][hb*16+l15])
// ---------------------------------------------------------------------------
__global__ __launch_bounds__(256) void pack_w1(
        const float* __restrict__ W1, unsigned short* __restrict__ W1p) {
    const int hb = blockIdx.x;    // 0..63
    const int t  = threadIdx.x;
    #pragma unroll
    for (int i = 0; i < 4; i++) {
        int f = i * 256 + t;               // fragment 0..1023
        int ds = f >> 6, lane = f & 63;
        int q = lane >> 4, l15 = lane & 15;
        unsigned short tmp[8];
        #pragma unroll
        for (int e = 0; e < 8; e++)
            tmp[e] = f2bf(W1[(size_t)(ds * 32 + q * 8 + e) * HH + hb * 16 + l15]);
        *(uint4*)(W1p + ((size_t)(hb * 16 + ds) * 64 + lane) * 8) = *(uint4*)tmp;
    }
}

// pack_w2: W2 fp32 [1024 h][512 d] -> W2p bf16 [32 db][32 hs][64 lane][8 e]
// W2p[db][hs][q*16+l15][e] = bf16(W2[(hs*32+q*8+e)][db*16+l15])
__global__ __launch_bounds__(256) void pack_w2(
        const float* __restrict__ W2, unsigned short* __restrict__ W2p) {
    const int db = blockIdx.x;    // 0..31
    const int t  = threadIdx.x;
    #pragma unroll
    for (int i = 0; i < 8; i++) {
        int f = i * 256 + t;               // fragment 0..2047
        int hs = f >> 6, lane = f & 63;
        int q = lane >> 4, l15 = lane & 15;
        unsigned short tmp[8];
        #pragma unroll
        for (int e = 0; e < 8; e++)
            tmp[e] = f2bf(W2[(size_t)(hs * 32 + q * 8 + e) * DD + db * 16 + l15]);
        *(uint4*)(W2p + ((size_t)(db * 32 + hs) * 64 + lane) * 8) = *(uint4*)tmp;
    }
}

// ---------------------------------------------------------------------------
// pack_ww: WW = bf16(W2bf . W1bf)  [1024 h'][1024 h2], frag-packed as B-op
// over k=h':  WWp[h2b][hs][qq*16+ll][e] = WW[(hs*32+qq*8+e)][h2b*16+ll].
// Grid (8 h2blk, 32 h'blk); A = W2 rows (fp32 gather + round), B = W1p frags.
// ---------------------------------------------------------------------------
__global__ __launch_bounds__(256) void pack_ww(
        const float* __restrict__ W2, const unsigned short* __restrict__ W1p,
        unsigned short* __restrict__ WWp) {
    __shared__ __align__(16) unsigned short pbounce[4 * 1024];
    const int t    = threadIdx.x;
    const int lane = t & 63;
    const int w    = t >> 6;
    const int q    = lane >> 4;
    const int l15  = lane & 15;
    const int h2blk = blockIdx.x;    // 0..7
    const int hpb   = blockIdx.y;    // 0..31 (h' block of 32 == hs index)
    const int h2w   = h2blk * 128 + w * 32;

    f32x4 acc[2][2] = {};
    #pragma unroll 4
    for (int ds = 0; ds < 16; ds++) {
        bf16x8 a[2];
        #pragma unroll
        for (int mt = 0; mt < 2; mt++) {
            const float* w2r = W2 + (size_t)(hpb * 32 + mt * 16 + l15) * DD + ds * 32 + q * 8;
            float4 va = *(const float4*)w2r;
            float4 vb = *(const float4*)(w2r + 4);
            unsigned short tmp[8] = { f2bf(va.x), f2bf(va.y), f2bf(va.z), f2bf(va.w),
                                      f2bf(vb.x), f2bf(vb.y), f2bf(vb.z), f2bf(vb.w) };
            a[mt] = *(bf16x8*)tmp;
        }
        bf16x8 bb0 = *(const bf16x8*)(W1p + (size_t)(h2w >> 4) * 8192 + ds * 512 + lane * 8);
        bf16x8 bb1 = *(const bf16x8*)(W1p + (size_t)((h2w >> 4) + 1) * 8192 + ds * 512 + lane * 8);
        acc[0][0] = __builtin_amdgcn_mfma_f32_16x16x32_bf16(a[0], bb0, acc[0][0], 0, 0, 0);
        acc[0][1] = __builtin_amdgcn_mfma_f32_16x16x32_bf16(a[0], bb1, acc[0][1], 0, 0, 0);
        acc[1][0] = __builtin_amdgcn_mfma_f32_16x16x32_bf16(a[1], bb0, acc[1][0], 0, 0, 0);
        acc[1][1] = __builtin_amdgcn_mfma_f32_16x16x32_bf16(a[1], bb1, acc[1][1], 0, 0, 0);
    }
    // element (h'loc = mt*16+q*4+r, h2loc = nt*16+l15) -> frag (nt; lane8; e)
    unsigned short* pb = pbounce + w * 1024;
    #pragma unroll
    for (int mt = 0; mt < 2; mt++)
        #pragma unroll
        for (int nt = 0; nt < 2; nt++) {
            int lane8 = (mt * 2 + (q >> 1)) * 16 + l15;
            #pragma unroll
            for (int r = 0; r < 4; r++)
                pb[(nt * 64 + lane8) * 8 + (q & 1) * 4 + r] = f2bf(acc[mt][nt][r]);
        }
    // same-wave LDS RAW; readback + contiguous store
    uint4 f0 = *(uint4*)(pb + (0 * 64 + lane) * 8);
    uint4 f1 = *(uint4*)(pb + (1 * 64 + lane) * 8);
    int h2b0 = h2w >> 4;
    *(uint4*)(WWp + ((size_t)(h2b0 + 0) * 32 + hpb) * 512 + lane * 8) = f0;
    *(uint4*)(WWp + ((size_t)(h2b0 + 1) * 32 + hpb) * 512 + lane * 8) = f1;
}

// ---------------------------------------------------------------------------
// yw1_kernel: yW1[b][h2] = sum_d bf16(y[b][d]) * W1bf[d][h2]  (fp32 out)
// MFMA GEMM M=128 b x N=1024 h2 x K=512. Grid (8 h2blk, 4 bblk).
// ---------------------------------------------------------------------------
__global__ __launch_bounds__(256) void yw1_kernel(
        const float* __restrict__ y_init, const unsigned short* __restrict__ W1p,
        float* __restrict__ yW1) {
    const int t    = threadIdx.x;
    const int lane = t & 63;
    const int w    = t >> 6;
    const int q    = lane >> 4;
    const int l15  = lane & 15;
    const int h2blk = blockIdx.x;    // 0..7
    const int bblk  = blockIdx.y;    // 0..3
    const int h2w   = h2blk * 128 + w * 32;

    f32x4 acc[2][2] = {};
    #pragma unroll 4
    for (int ds = 0; ds < 16; ds++) {
        bf16x8 a[2];
        #pragma unroll
        for (int mt = 0; mt < 2; mt++) {
            const float* yr = y_init + (size_t)(bblk * 32 + mt * 16 + l15) * DD + ds * 32 + q * 8;
            float4 va = *(const float4*)yr;
            float4 vb = *(const float4*)(yr + 4);
            unsigned short tmp[8] = { f2bf(va.x), f2bf(va.y), f2bf(va.z), f2bf(va.w),
                                      f2bf(vb.x), f2bf(vb.y), f2bf(vb.z), f2bf(vb.w) };
            a[mt] = *(bf16x8*)tmp;
        }
        bf16x8 bb0 = *(const bf16x8*)(W1p + (size_t)(h2w >> 4) * 8192 + ds * 512 + lane * 8);
        bf16x8 bb1 = *(const bf16x8*)(W1p + (size_t)((h2w >> 4) + 1) * 8192 + ds * 512 + lane * 8);
        acc[0][0] = __builtin_amdgcn_mfma_f32_16x16x32_bf16(a[0], bb0, acc[0][0], 0, 0, 0);
        acc[0][1] = __builtin_amdgcn_mfma_f32_16x16x32_bf16(a[0], bb1, acc[0][1], 0, 0, 0);
        acc[1][0] = __builtin_amdgcn_mfma_f32_16x16x32_bf16(a[1], bb0, acc[1][0], 0, 0, 0);
        acc[1][1] = __builtin_amdgcn_mfma_f32_16x16x32_bf16(a[1], bb1, acc[1][1], 0, 0, 0);
    }
    #pragma unroll
    for (int mt = 0; mt < 2; mt++)
        #pragma unroll
        for (int nt = 0; nt < 2; nt++)
            #pragma unroll
            for (int r = 0; r < 4; r++) {
                int b  = bblk * 32 + mt * 16 + q * 4 + r;
                int h2 = h2w + nt * 16 + l15;
                yW1[(size_t)b * HH + h2] = acc[mt][nt][r];
            }
}

// ---------------------------------------------------------------------------
// K1_0 (first iteration only): stages B_init[b] fp32 -> LDS bf16 [n][d] (swz),
// G = A W1^T (B from W1p frags), Z = Phi_f^T G, tanh, P = Q^T T, pack -> Ptp.
// LDS: smA 32768 (t_sb overlays) + g_sb 8192 = 40960 B.
// ---------------------------------------------------------------------------
__global__ __launch_bounds__(256) void k1_kernel(
        const float* __restrict__ B_init,        // [B][512 d][32 n] fp32
        const unsigned short* __restrict__ W1p,  // frag-packed
        const float* __restrict__ b1,            // [1024]
        const float* __restrict__ ws,
        unsigned short* __restrict__ Ptp)        // [B][32 hs][2 mt][64][8] bf16
{
    __shared__ __align__(16) char smem[40960];
    unsigned short* smA  = (unsigned short*)smem;           // A [32 n][512 d] swz
    unsigned short* t_sb = (unsigned short*)smem;           // [128][72] (overlays A)
    unsigned short* g_sb = (unsigned short*)(smem + 32768); // [128][32]

    const int t    = threadIdx.x;
    const int lane = t & 63;
    const int w    = t >> 6;
    const int q    = lane >> 4;
    const int l15  = lane & 15;
    const int b    = blockIdx.y;
    const int hblk = blockIdx.x;
    const int hw   = hblk * 128 + w * 32;

    // stage: B_init[b] [512 d][32 n] fp32 -> smA bf16 [n][d] swizzled
    {
        const float* Bi = B_init + (size_t)b * DD * NB;
        #pragma unroll 8
        for (int i = 0; i < 64; i++) {
            int f = i * 256 + t;       // 0..16383
            int d = f >> 5, n = f & 31;
            *(unsigned short*)(smem + (((n << 10) + (d << 1)) ^ ((n & 7) << 4)))
                = f2bf(Bi[f]);
        }
    }
    __syncthreads();

    // Phase A: G = A W1^T, M=32(n) x N=32(h/wave) x K=512
    f32x4 acc[2][2] = {};
    const unsigned short* W1b = W1p + (size_t)(hw >> 4) * 8192;
    #pragma unroll 4
    for (int d0 = 0; d0 < DD; d0 += 32) {
        int c16 = (d0 >> 3) + q;
        int ds  = d0 >> 5;
        bf16x8 a0  = *(const bf16x8*)aS(smA, l15, c16);
        bf16x8 a1  = *(const bf16x8*)aS(smA, 16 + l15, c16);
        bf16x8 bb0 = *(const bf16x8*)(W1b + ds * 512 + lane * 8);
        bf16x8 bb1 = *(const bf16x8*)(W1b + 8192 + ds * 512 + lane * 8);
        acc[0][0] = __builtin_amdgcn_mfma_f32_16x16x32_bf16(a0, bb0, acc[0][0], 0, 0, 0);
        acc[0][1] = __builtin_amdgcn_mfma_f32_16x16x32_bf16(a0, bb1, acc[0][1], 0, 0, 0);
        acc[1][0] = __builtin_amdgcn_mfma_f32_16x16x32_bf16(a1, bb0, acc[1][0], 0, 0, 0);
        acc[1][1] = __builtin_amdgcn_mfma_f32_16x16x32_bf16(a1, bb1, acc[1][1], 0, 0, 0);
    }
    #pragma unroll
    for (int mt = 0; mt < 2; mt++)
        #pragma unroll
        for (int nt = 0; nt < 2; nt++) {
            int hl = w * 32 + nt * 16 + l15;
            store4bf(&g_sb[hl * 32 + mt * 16 + q * 4],
                     acc[mt][nt][0], acc[mt][nt][1], acc[mt][nt][2], acc[mt][nt][3]);
        }
    __syncthreads();   // all smA reads complete -> t_sb may overlay

    // Z = Phi_f^T G
    f32x4 zacc[4][2] = {};
    const unsigned short* PF = (const unsigned short*)(ws + OFF_PHIF_BF);
    bf16x8 gb[2];
    #pragma unroll
    for (int nt = 0; nt < 2; nt++)
        gb[nt] = *(const bf16x8*)(&g_sb[(w * 32 + nt * 16 + l15) * 32 + q * 8]);
    #pragma unroll
    for (int mt = 0; mt < 4; mt++) {
        bf16x8 af = *(const bf16x8*)(PF + (mt * 16 + l15) * 32 + q * 8);
        zacc[mt][0] = __builtin_amdgcn_mfma_f32_16x16x32_bf16(af, gb[0], zacc[mt][0], 0, 0, 0);
        zacc[mt][1] = __builtin_amdgcn_mfma_f32_16x16x32_bf16(af, gb[1], zacc[mt][1], 0, 0, 0);
    }

    const float* TTp = ws + OFF_TTRUE;
    float b1v[2] = { b1[hw + l15], b1[hw + 16 + l15] };
    #pragma unroll
    for (int mt = 0; mt < 4; mt++) {
        float4 ttv = *(const float4*)(TTp + mt * 16 + q * 4);
        #pragma unroll
        for (int nt = 0; nt < 2; nt++) {
            int hl = w * 32 + nt * 16 + l15;
            float v0 = tanh_fast(zacc[mt][nt][0] + ttv.x * b1v[nt]);
            float v1 = tanh_fast(zacc[mt][nt][1] + ttv.y * b1v[nt]);
            float v2 = tanh_fast(zacc[mt][nt][2] + ttv.z * b1v[nt]);
            float v3 = tanh_fast(zacc[mt][nt][3] + ttv.w * b1v[nt]);
            store4bf(&t_sb[hl * 72 + mt * 16 + q * 4], v0, v1, v2, v3);
        }
    }
    __syncthreads();

    // P = Q^T T
    f32x4 pacc[2][2] = {};
    const unsigned short* QT = (const unsigned short*)(ws + OFF_QT_BF);
    #pragma unroll
    for (int ks = 0; ks < 2; ks++) {
        bf16x8 bt[2];
        #pragma unroll
        for (int nt = 0; nt < 2; nt++)
            bt[nt] = *(const bf16x8*)(&t_sb[(w * 32 + nt * 16 + l15) * 72 + ks * 32 + q * 8]);
        #pragma unroll
        for (int jt = 0; jt < 2; jt++) {
            bf16x8 aq = *(const bf16x8*)(QT + (jt * 16 + l15) * 64 + ks * 32 + q * 8);
            pacc[jt][0] = __builtin_amdgcn_mfma_f32_16x16x32_bf16(aq, bt[0], pacc[jt][0], 0, 0, 0);
            pacc[jt][1] = __builtin_amdgcn_mfma_f32_16x16x32_bf16(aq, bt[1], pacc[jt][1], 0, 0, 0);
        }
    }

    // pack P -> Ptp via wave-private bounce (g_sb region dead after Z)
    {
        unsigned short* pb = g_sb + w * 1024;
        #pragma unroll
        for (int jt = 0; jt < 2; jt++)
            #pragma unroll
            for (int nt = 0; nt < 2; nt++) {
                int grp = (nt * 2 + (l15 >> 3)) & 3;
                #pragma unroll
                for (int r = 0; r < 4; r++) {
                    int lane8 = grp * 16 + q * 4 + r;
                    pb[(jt * 64 + lane8) * 8 + (l15 & 7)] = f2bf(pacc[jt][nt][r]);
                }
            }
        int hs = hblk * 4 + w;
        uint4 f0 = *(uint4*)(pb + (0 * 64 + lane) * 8);
        uint4 f1 = *(uint4*)(pb + (1 * 64 + lane) * 8);
        *(uint4*)(Ptp + (((size_t)(b * 32 + hs) * 2 + 0) * 64 + lane) * 8) = f0;
        *(uint4*)(Ptp + (((size_t)(b * 32 + hs) * 2 + 1) * 64 + lane) * 8) = f1;
    }
}

// ---------------------------------------------------------------------------
// KF (iterations 1..9 fused): G' = P.WW + u (x) yW1, then Z/tanh/P as k1.
// Pure streaming K-loop (K=1024, frag-packed A and B), no __syncthreads.
// ---------------------------------------------------------------------------
__global__ __launch_bounds__(256) void kf_kernel(
        const unsigned short* __restrict__ Ptin,  // [B][32 hs][2 mt][64][8]
        const unsigned short* __restrict__ WWp,   // [64 h2b][32 hs][64][8]
        const float* __restrict__ yW1,            // [B][1024] fp32
        const float* __restrict__ b1,
        const float* __restrict__ ws,
        unsigned short* __restrict__ Ptout)
{
    __shared__ __align__(16) unsigned short t_sb[128 * 72];
    __shared__ __align__(16) unsigned short g_sb[128 * 32];

    const int t    = threadIdx.x;
    const int lane = t & 63;
    const int w    = t >> 6;
    const int q    = lane >> 4;
    const int l15  = lane & 15;
    const int b    = blockIdx.y;
    const int hblk = blockIdx.x;
    const int hw   = hblk * 128 + w * 32;

    // G' = P.WW : M=32(j) x N=32(h2/wave) x K=1024
    f32x4 acc[2][2] = {};
    const unsigned short* Ab  = Ptin + (size_t)b * 32768;
    const unsigned short* WWb = WWp + (size_t)(hw >> 4) * 16384;
    #pragma unroll 4
    for (int s = 0; s < 32; s++) {
        bf16x8 a0  = *(const bf16x8*)(Ab + (s * 2 + 0) * 512 + lane * 8);
        bf16x8 a1  = *(const bf16x8*)(Ab + (s * 2 + 1) * 512 + lane * 8);
        bf16x8 bb0 = *(const bf16x8*)(WWb + s * 512 + lane * 8);
        bf16x8 bb1 = *(const bf16x8*)(WWb + 16384 + s * 512 + lane * 8);
        acc[0][0] = __builtin_amdgcn_mfma_f32_16x16x32_bf16(a0, bb0, acc[0][0], 0, 0, 0);
        acc[0][1] = __builtin_amdgcn_mfma_f32_16x16x32_bf16(a0, bb1, acc[0][1], 0, 0, 0);
        acc[1][0] = __builtin_amdgcn_mfma_f32_16x16x32_bf16(a1, bb0, acc[1][0], 0, 0, 0);
        acc[1][1] = __builtin_amdgcn_mfma_f32_16x16x32_bf16(a1, bb1, acc[1][1], 0, 0, 0);
    }

    // bias u[j]*yW1[b][h2], write g_sb[h_loc][j]
    const float* U = ws + OFF_U;
    float yw[2] = { yW1[(size_t)b * HH + hw + l15],
                    yW1[(size_t)b * HH + hw + 16 + l15] };
    #pragma unroll
    for (int mt = 0; mt < 2; mt++) {
        float4 uv = *(const float4*)(U + mt * 16 + q * 4);
        #pragma unroll
        for (int nt = 0; nt < 2; nt++) {
            int hl = w * 32 + nt * 16 + l15;
            store4bf(&g_sb[hl * 32 + mt * 16 + q * 4],
                     acc[mt][nt][0] + uv.x * yw[nt],
                     acc[mt][nt][1] + uv.y * yw[nt],
                     acc[mt][nt][2] + uv.z * yw[nt],
                     acc[mt][nt][3] + uv.w * yw[nt]);
        }
    }

    // Z = Phi_f^T G'
    f32x4 zacc[4][2] = {};
    const unsigned short* PF = (const unsigned short*)(ws + OFF_PHIF_BF);
    bf16x8 gb[2];
    #pragma unroll
    for (int nt = 0; nt < 2; nt++)
        gb[nt] = *(const bf16x8*)(&g_sb[(w * 32 + nt * 16 + l15) * 32 + q * 8]);
    #pragma unroll
    for (int mt = 0; mt < 4; mt++) {
        bf16x8 af = *(const bf16x8*)(PF + (mt * 16 + l15) * 32 + q * 8);
        zacc[mt][0] = __builtin_amdgcn_mfma_f32_16x16x32_bf16(af, gb[0], zacc[mt][0], 0, 0, 0);
        zacc[mt][1] = __builtin_amdgcn_mfma_f32_16x16x32_bf16(af, gb[1], zacc[mt][1], 0, 0, 0);
    }

    const float* TTp = ws + OFF_TTRUE;
    float b1v[2] = { b1[hw + l15], b1[hw + 16 + l15] };
    #pragma unroll
    for (int mt = 0; mt < 4; mt++) {
        float4 ttv = *(const float4*)(TTp + mt * 16 + q * 4);
        #pragma unroll
        for (int nt = 0; nt < 2; nt++) {
            int hl = w * 32 + nt * 16 + l15;
            float v0 = tanh_fast(zacc[mt][nt][0] + ttv.x * b1v[nt]);
            float v1 = tanh_fast(zacc[mt][nt][1] + ttv.y * b1v[nt]);
            float v2 = tanh_fast(zacc[mt][nt][2] + ttv.z * b1v[nt]);
            float v3 = tanh_fast(zacc[mt][nt][3] + ttv.w * b1v[nt]);
            store4bf(&t_sb[hl * 72 + mt * 16 + q * 4], v0, v1, v2, v3);
        }
    }

    // P = Q^T T
    f32x4 pacc[2][2] = {};
    const unsigned short* QT = (const unsigned short*)(ws + OFF_QT_BF);
    #pragma unroll
    for (int ks = 0; ks < 2; ks++) {
        bf16x8 bt[2];
        #pragma unroll
        for (int nt = 0; nt < 2; nt++)
            bt[nt] = *(const bf16x8*)(&t_sb[(w * 32 + nt * 16 + l15) * 72 + ks * 32 + q * 8]);
        #pragma unroll
        for (int jt = 0; jt < 2; jt++) {
            bf16x8 aq = *(const bf16x8*)(QT + (jt * 16 + l15) * 64 + ks * 32 + q * 8);
            pacc[jt][0] = __builtin_amdgcn_mfma_f32_16x16x32_bf16(aq, bt[0], pacc[jt][0], 0, 0, 0);
            pacc[jt][1] = __builtin_amdgcn_mfma_f32_16x16x32_bf16(aq, bt[1], pacc[jt][1], 0, 0, 0);
        }
    }

    // pack P -> Ptout (wave-private bounce in g_sb region)
    {
        unsigned short* pb = g_sb + w * 1024;
        #pragma unroll
        for (int jt = 0; jt < 2; jt++)
            #pragma unroll
            for (int nt = 0; nt < 2; nt++) {
                int grp = (nt * 2 + (l15 >> 3)) & 3;
                #pragma unroll
                for (int r = 0; r < 4; r++) {
                    int lane8 = grp * 16 + q * 4 + r;
                    pb[(jt * 64 + lane8) * 8 + (l15 & 7)] = f2bf(pacc[jt][nt][r]);
                }
            }
        int hs = hblk * 4 + w;
        uint4 f0 = *(uint4*)(pb + (0 * 64 + lane) * 8);
        uint4 f1 = *(uint4*)(pb + (1 * 64 + lane) * 8);
        *(uint4*)(Ptout + (((size_t)(b * 32 + hs) * 2 + 0) * 64 + lane) * 8) = f0;
        *(uint4*)(Ptout + (((size_t)(b * 32 + hs) * 2 + 1) * 64 + lane) * 8) = f1;
    }
}

// ---------------------------------------------------------------------------
// K2_final: Bn[b,d,j] = sum_h P[j,h] W2[h,d] + y u[j]  (fp32 out, last iter)
// ---------------------------------------------------------------------------
__global__ __launch_bounds__(256) void k2_kernel(
        const unsigned short* __restrict__ Ptp,  // [B][32 hs][2 mt][64][8] bf16
        const unsigned short* __restrict__ W2p,  // frag-packed
        const float* __restrict__ y_init,        // [B][512]
        const float* __restrict__ ws,
        float* __restrict__ Bn)                  // [B][512][32] fp32
{
    __shared__ __align__(16) float ls[4 * 544];

    const int t    = threadIdx.x;
    const int lane = t & 63;
    const int w    = t >> 6;
    const int q    = lane >> 4;
    const int l15  = lane & 15;
    const int b    = blockIdx.y;
    const int dblk = blockIdx.x;        // 0..7
    const int dw   = dblk * 64 + w * 16;

    f32x4 acc[2] = {};
    const unsigned short* Ab  = Ptp + (size_t)b * 32768;
    const unsigned short* W2b = W2p + (size_t)(dblk * 4 + w) * 16384;
    #pragma unroll 4
    for (int s = 0; s < 32; s++) {
        bf16x8 a0 = *(const bf16x8*)(Ab + (s * 2 + 0) * 512 + lane * 8);
        bf16x8 a1 = *(const bf16x8*)(Ab + (s * 2 + 1) * 512 + lane * 8);
        bf16x8 bb = *(const bf16x8*)(W2b + s * 512 + lane * 8);
        acc[0] = __builtin_amdgcn_mfma_f32_16x16x32_bf16(a0, bb, acc[0], 0, 0, 0);
        acc[1] = __builtin_amdgcn_mfma_f32_16x16x32_bf16(a1, bb, acc[1], 0, 0, 0);
    }

    const float* U = ws + OFF_U;
    float yv = y_init[(size_t)b * DD + dw + l15];
    #pragma unroll
    for (int mt = 0; mt < 2; mt++) {
        float4 uv = *(const float4*)(U + mt * 16 + q * 4);
        #pragma unroll
        for (int r = 0; r < 4; r++) {
            int j = mt * 16 + q * 4 + r;
            float uvr = (r == 0) ? uv.x : (r == 1) ? uv.y : (r == 2) ? uv.z : uv.w;
            ls[w * 544 + j * 17 + l15] = acc[mt][r] + yv * uvr;
        }
    }
    __syncthreads();
    #pragma unroll
    for (int it = 0; it < 8; it++) {
        int f = it * 64 + lane;
        int d_l = f >> 5, j2 = f & 31;
        Bn[((size_t)b * DD + dw + d_l) * NB + j2] = ls[w * 544 + j2 * 17 + d_l];
    }
}

// ---------------------------------------------------------------------------
// K3: out0[t,b,d] = sum_n Bn[b,d,n]*Phi_out[n,t] ; out1 = Bn
// ---------------------------------------------------------------------------
__global__ __launch_bounds__(256) void k3_kernel(
        const float* __restrict__ ws_c, float* __restrict__ out) {
    __shared__ float rows_s[64 * 33];
    __shared__ float phiout_s[NB * TT];

    const int t = threadIdx.x;
    const int r0 = blockIdx.x * 64;
    const float* Bf = ws_c + OFF_BN;

    for (int f = t; f < NB * TT; f += 256) phiout_s[f] = ws_c[OFF_PHIOUT + f];

    float vals[8];
    {
        int f = t;
        #pragma unroll
        for (int i = 0; i < 8; i++, f += 256) {
            float v = Bf[(size_t)r0 * NB + f];
            rows_s[(f >> 5) * 33 + (f & 31)] = v;
            vals[i] = v;
        }
    }
    float* out1 = out + (size_t)TT * BB * DD;
    {
        int f = t;
        #pragma unroll
        for (int i = 0; i < 8; i++, f += 256) out1[(size_t)r0 * NB + f] = vals[i];
    }
    __syncthreads();

    #pragma unroll
    for (int i = 0; i < 4; i++) {
        int idx = i * 256 + t;
        int tt = idx >> 6, rl = idx & 63;
        float s = 0.f;
        #pragma unroll
        for (int n = 0; n < NB; n++)
            s += rows_s[rl * 33 + n] * phiout_s[n * TT + tt];
        out[(size_t)tt * (BB * DD) + r0 + rl] = s;
    }
}

// ---------------------------------------------------------------------------
extern "C" void kernel_launch(void* const* d_in, const int* in_sizes, int n_in,
                              void* d_out, int out_size, void* d_ws, size_t ws_size,
                              hipStream_t stream) {
    const float* t_span = (const float*)d_in[0];
    const float* y_init = (const float*)d_in[1];
    const float* B_init = (const float*)d_in[2];
    const float* W1     = (const float*)d_in[3];
    const float* b1     = (const float*)d_in[4];
    const float* W2     = (const float*)d_in[5];
    float* ws  = (float*)d_ws;
    float* out = (float*)d_out;

    unsigned short* W1p  = (unsigned short*)(ws + OFF_W1P);
    unsigned short* W2p  = (unsigned short*)(ws + OFF_W2P);
    unsigned short* WWp  = (unsigned short*)(ws + OFF_WWP);
    float*          yW1  = ws + OFF_YW1;
    unsigned short* PtpA = (unsigned short*)(ws + OFF_BN);    // Bn region, dead until end
    unsigned short* PtpB = (unsigned short*)(ws + OFF_PTP0);
    float*          Bn   = ws + OFF_BN;

    setup_kernel<<<1, 256, 0, stream>>>(t_span, ws);
    pack_w1<<<dim3(64), 256, 0, stream>>>(W1, W1p);
    pack_w2<<<dim3(32), 256, 0, stream>>>(W2, W2p);
    pack_ww<<<dim3(8, 32), 256, 0, stream>>>(W2, W1p, WWp);
    yw1_kernel<<<dim3(8, 4), 256, 0, stream>>>(y_init, W1p, yW1);

    k1_kernel<<<dim3(8, BB), 256, 0, stream>>>(B_init, W1p, b1, ws, PtpA);

    unsigned short* pin  = PtpA;
    unsigned short* pout = PtpB;
    for (int it = 1; it < ITERS; it++) {
        kf_kernel<<<dim3(8, BB), 256, 0, stream>>>(pin, WWp, yW1, b1, ws, pout);
        unsigned short* tmp = pin; pin = pout; pout = tmp;
    }
    // 9 kf's -> final P in PtpB (pin == PtpB after odd swap count)
    k2_kernel<<<dim3(8, BB), 256, 0, stream>>>(pin, W2p, y_init, ws, Bn);

    k3_kernel<<<dim3((BB * DD) / 64), 256, 0, stream>>>(ws, out);
}

// Round 12
// 389.891 us; speedup vs baseline: 10.2137x; 1.0706x over previous
//
#include <hip/hip_runtime.h>
#include <hip/hip_bf16.h>
#include <math.h>

// Problem constants (fixed by setup_inputs)
#define BB 128
#define DD 512
#define HH 1024
#define NB 32     // num_coeff_per_dim
#define MM 63     // 2N-1 simpson points
#define TT 16
#define ITERS 10

// ws layout (float units)
#define OFF_U       0        // 32 fp32
#define OFF_TTRUE   64       // 64 fp32 (tt[63]=0)
#define OFF_PHIOUT  128      // 512 fp32
#define OFF_PHIF_BF 1024     // bf16 [64 m][32 n]  (row 63 = 0)   = 1024 floats
#define OFF_QT_BF   2048     // bf16 [32 j][64 m]  (col 63 = 0)   = 1024 floats
#define HDRF        4096
#define OFF_PTPA    HDRF                     // bf16 frag-packed [B][32 hs][2 mt][64][8] = 2097152 f
#define OFF_PTP0    (OFF_PTPA + 2097152)     // bf16 frag-packed ping-pong buffer       = 2097152 f
#define OFF_W1P     (OFF_PTP0 + 2097152)     // bf16 frag-packed [64 hb][16 ds][64][8] = 262144 f
#define OFF_W2P     (OFF_W1P + 262144)       // bf16 frag-packed [32 db][32 hs][64][8] = 262144 f
#define OFF_WWP     (OFF_W2P + 262144)       // bf16 frag-packed [64 h2b][32 hs][64][8] = 524288 f
#define OFF_YW1     (OFF_WWP + 524288)       // fp32 [128 b][1024 h2] = 131072 f
// end = 5378048 floats = 21.5 MB

typedef __attribute__((ext_vector_type(8))) short bf16x8;
typedef __attribute__((ext_vector_type(4))) float f32x4;

static __device__ __forceinline__ unsigned short f2bf(float f) {
    unsigned int x = __builtin_bit_cast(unsigned int, f);
    unsigned int r = x + 0x7FFFu + ((x >> 16) & 1u);   // RNE
    return (unsigned short)(r >> 16);
}

static __device__ __forceinline__ void store4bf(unsigned short* p,
                                                float v0, float v1, float v2, float v3) {
    unsigned int lo = (unsigned int)f2bf(v0) | ((unsigned int)f2bf(v1) << 16);
    unsigned int hi = (unsigned int)f2bf(v2) | ((unsigned int)f2bf(v3) << 16);
    uint2 u; u.x = lo; u.y = hi;
    *(uint2*)p = u;   // 8B-aligned by construction
}

static __device__ __forceinline__ float tanh_fast(float x) {
    float e = exp2f(x * 2.88539008177793f);   // 2*log2(e)
    return 1.0f - 2.0f / (e + 1.0f);
}

// XOR-swizzled LDS A-tile addressing: tile [32 r][512 c] bf16, linear 32KB,
// byte = (r*1024 + c*2) ^ ((r&7)<<4). Bijective per row, 16B-aligned b128.
static __device__ __forceinline__ unsigned short* aS(unsigned short* smA, int r, int c16) {
    return (unsigned short*)((char*)smA + (((r << 10) + (c16 << 4)) ^ ((r & 7) << 4)));
}

// ---------------------------------------------------------------------------
// PROLOGUE (single dispatch, blocks partitioned by role; no cross-block deps:
// pack_ww / yw1 gather W1 fp32 directly with the same f2bf -> bitwise-same
// results as the previous pack_w1 -> pack_ww chain).
//   bid 0        : setup (t grids, Phi_f, Phi_inv GJ, Q, u, Phi_out, tables)
//   bid 1..64    : pack_w1   (hb = bid-1)
//   bid 65..96   : pack_w2   (db = bid-65)
//   bid 97..352  : pack_ww   (idx: h2blk = idx&7, hpb = idx>>3)
//   bid 353..384 : yw1       (idx: h2blk = idx&7, bblk = idx>>3)
// LDS: 66560 B (setup's scratch; others use first 8KB as bounce).
// ---------------------------------------------------------------------------
__global__ __launch_bounds__(256) void prologue_kernel(
        const float* __restrict__ t_span, const float* __restrict__ W1,
        const float* __restrict__ W2, const float* __restrict__ y_init,
        float* __restrict__ ws) {
    __shared__ __align__(16) char smem[66560];
    const int bid  = blockIdx.x;
    const int t    = threadIdx.x;
    const int lane = t & 63;
    const int w    = t >> 6;
    const int q    = lane >> 4;
    const int l15  = lane & 15;

    if (bid == 0) {
        // ---------------- setup ----------------
        double* tsim    = (double*)(smem + 0);       // 63
        double* ttrue_d = (double*)(smem + 512);     // 63
        double* wid     = (double*)(smem + 1024);    // 31
        double* phid    = (double*)(smem + 1280);    // 32*63
        double* aug     = (double*)(smem + 17408);   // 32*64
        double* mlt     = (double*)(smem + 33792);   // 32
        double* Rl      = (double*)(smem + 34048);   // 63*32
        double* Qd      = (double*)(smem + 50176);   // 63*32
        int*    piv_s   = (int*)(smem + 66304);

        const int rgrp = t >> 6;
        const double PI = 3.14159265358979323846;
        const double t0 = (double)t_span[0];
        const double t1 = (double)t_span[TT - 1];

        if (t < MM) {
            double v;
            if ((t & 1) == 0) {
                int j = t >> 1;
                v = -cos(PI * (double)j / (double)(NB - 1));
            } else {
                int i = t >> 1;
                double a = -cos(PI * (double)i / (double)(NB - 1));
                double b = -cos(PI * (double)(i + 1) / (double)(NB - 1));
                v = 0.5 * (a + b);
            }
            tsim[t] = v;
            ttrue_d[t] = t0 + 0.5 * (t1 - t0) * (v + 1.0);
        }
        __syncthreads();
        if (t < 31) wid[t] = (ttrue_d[2 * t + 2] - ttrue_d[2 * t]) / 6.0;
        if (t < MM) ws[OFF_TTRUE + t] = (float)ttrue_d[t];
        if (t == 63) ws[OFF_TTRUE + 63] = 0.0f;

        if (t < MM) {
            double x = tsim[t];
            double r0 = 1.0, r1 = x;
            phid[0 * MM + t] = r0;
            phid[1 * MM + t] = r1;
            for (int n = 2; n < NB; n++) {
                double r2 = 2.0 * x * r1 - r0;
                phid[n * MM + t] = r2;
                r0 = r1; r1 = r2;
            }
        }
        __syncthreads();

        {   // phif_bf [m 64][n 32], row 63 = 0
            unsigned short* pf = (unsigned short*)(ws + OFF_PHIF_BF);
            for (int f = t; f < 64 * 32; f += 256) {
                int m = f >> 5, n = f & 31;
                pf[f] = f2bf(m < MM ? (float)phid[n * MM + m] : 0.0f);
            }
        }

        for (int f = t; f < NB * 64; f += 256) {
            int r = f >> 6, c = f & 63;
            double v;
            if (c < NB) v = phid[r * MM + 2 * c];
            else        v = ((c - NB) == r) ? 1.0 : 0.0;
            aug[f] = v;
        }
        __syncthreads();

        for (int k = 0; k < NB; k++) {
            if (t < 32) {
                double v = (t >= k) ? fabs(aug[t * 64 + k]) : -1.0;
                int idx = t;
                #pragma unroll
                for (int off = 16; off >= 1; off >>= 1) {
                    double ov = __shfl_xor(v, off);
                    int    oi = __shfl_xor(idx, off);
                    if (ov > v) { v = ov; idx = oi; }
                }
                if (t == 0) *piv_s = idx;
            }
            __syncthreads();
            const int p = *piv_s;
            if (t < 64) {
                double pv   = aug[p * 64 + k];
                double rowp = aug[p * 64 + t];
                double rowk = aug[k * 64 + t];
                aug[k * 64 + t] = rowp / pv;
                if (p != k) aug[p * 64 + t] = rowk;
            }
            __syncthreads();
            if (t < 32) mlt[t] = (t == k) ? 0.0 : aug[t * 64 + k];
            __syncthreads();
            {
                double pk = aug[k * 64 + lane];
                #pragma unroll
                for (int i = 0; i < 8; i++) {
                    int r = rgrp * 8 + i;
                    aug[r * 64 + lane] -= mlt[r] * pk;
                }
            }
            __syncthreads();
        }

        if (t < MM) {
            double acc = 0.0;
            Rl[t * NB + 0] = 0.0;
            for (int i = 1; i < NB; i++) {
                int ip = i - 1;
                double wv = 0.0;
                if (t == 2 * ip)     wv += wid[ip];
                if (t == 2 * ip + 1) wv += 4.0 * wid[ip];
                if (t == 2 * ip + 2) wv += wid[ip];
                acc += wv;
                Rl[t * NB + i] = acc;
            }
        }
        __syncthreads();

        for (int f = t; f < MM * NB; f += 256) {
            int m = f >> 5, j = f & 31;
            double s = 0.0;
            for (int i = 0; i < NB; i++) s += Rl[m * NB + i] * aug[i * 64 + 32 + j];
            Qd[f] = s;
        }
        __syncthreads();

        {   // qt_bf [j 32][m 64], col 63 = 0
            unsigned short* qt = (unsigned short*)(ws + OFF_QT_BF);
            for (int f = t; f < 32 * 64; f += 256) {
                int j = f >> 6, m = f & 63;
                qt[f] = f2bf(m < MM ? (float)Qd[m * NB + j] : 0.0f);
            }
        }
        if (t < NB) {
            double s = 0.0;
            for (int i = 0; i < NB; i++) s += aug[i * 64 + 32 + t];
            ws[OFF_U + t] = (float)s;
        }
        if (t < TT) {
            double x = -1.0 + 2.0 * ((double)t_span[t] - t0) / (t1 - t0);
            double r0 = 1.0, r1 = x;
            ws[OFF_PHIOUT + 0 * TT + t] = 1.0f;
            ws[OFF_PHIOUT + 1 * TT + t] = (float)x;
            for (int n = 2; n < NB; n++) {
                double r2 = 2.0 * x * r1 - r0;
                ws[OFF_PHIOUT + n * TT + t] = (float)r2;
                r0 = r1; r1 = r2;
            }
        }
        return;
    }

    if (bid <= 64) {
        // ---------------- pack_w1: hb = bid-1 ----------------
        unsigned short* W1p = (unsigned short*)(ws + OFF_W1P);
        const int hb = bid - 1;
        #pragma unroll
        for (int i = 0; i < 4; i++) {
            int f = i * 256 + t;
            int ds = f >> 6, ln = f & 63;
            int qq = ln >> 4, ll = ln & 15;
            unsigned short tmp[8];
            #pragma unroll
            for (int e = 0; e < 8; e++)
                tmp[e] = f2bf(W1[(size_t)(ds * 32 + qq * 8 + e) * HH + hb * 16 + ll]);
            *(uint4*)(W1p + ((size_t)(hb * 16 + ds) * 64 + ln) * 8) = *(uint4*)tmp;
        }
        return;
    }

    if (bid <= 96) {
        // ---------------- pack_w2: db = bid-65 ----------------
        unsigned short* W2p = (unsigned short*)(ws + OFF_W2P);
        const int db = bid - 65;
        #pragma unroll
        for (int i = 0; i < 8; i++) {
            int f = i * 256 + t;
            int hs = f >> 6, ln = f & 63;
            int qq = ln >> 4, ll = ln & 15;
            unsigned short tmp[8];
            #pragma unroll
            for (int e = 0; e < 8; e++)
                tmp[e] = f2bf(W2[(size_t)(hs * 32 + qq * 8 + e) * DD + db * 16 + ll]);
            *(uint4*)(W2p + ((size_t)(db * 32 + hs) * 64 + ln) * 8) = *(uint4*)tmp;
        }
        return;
    }

    if (bid <= 352) {
        // ---------------- pack_ww: WW = bf16(W2bf . W1bf), frag-packed ----
        unsigned short* WWp = (unsigned short*)(ws + OFF_WWP);
        unsigned short* pbounce = (unsigned short*)smem;   // 8 KB
        const int idx   = bid - 97;
        const int h2blk = idx & 7;     // 0..7
        const int hpb   = idx >> 3;    // 0..31
        const int h2w   = h2blk * 128 + w * 32;

        f32x4 acc[2][2] = {};
        #pragma unroll 4
        for (int ds = 0; ds < 16; ds++) {
            bf16x8 a[2];
            #pragma unroll
            for (int mt = 0; mt < 2; mt++) {
                const float* w2r = W2 + (size_t)(hpb * 32 + mt * 16 + l15) * DD + ds * 32 + q * 8;
                float4 va = *(const float4*)w2r;
                float4 vb = *(const float4*)(w2r + 4);
                unsigned short tmp[8] = { f2bf(va.x), f2bf(va.y), f2bf(va.z), f2bf(va.w),
                                          f2bf(vb.x), f2bf(vb.y), f2bf(vb.z), f2bf(vb.w) };
                a[mt] = *(bf16x8*)tmp;
            }
            bf16x8 bb0, bb1;
            {
                unsigned short tb[8];
                #pragma unroll
                for (int e = 0; e < 8; e++)
                    tb[e] = f2bf(W1[(size_t)(ds * 32 + q * 8 + e) * HH + h2w + l15]);
                bb0 = *(bf16x8*)tb;
                #pragma unroll
                for (int e = 0; e < 8; e++)
                    tb[e] = f2bf(W1[(size_t)(ds * 32 + q * 8 + e) * HH + h2w + 16 + l15]);
                bb1 = *(bf16x8*)tb;
            }
            acc[0][0] = __builtin_amdgcn_mfma_f32_16x16x32_bf16(a[0], bb0, acc[0][0], 0, 0, 0);
            acc[0][1] = __builtin_amdgcn_mfma_f32_16x16x32_bf16(a[0], bb1, acc[0][1], 0, 0, 0);
            acc[1][0] = __builtin_amdgcn_mfma_f32_16x16x32_bf16(a[1], bb0, acc[1][0], 0, 0, 0);
            acc[1][1] = __builtin_amdgcn_mfma_f32_16x16x32_bf16(a[1], bb1, acc[1][1], 0, 0, 0);
        }
        unsigned short* pb = pbounce + w * 1024;
        #pragma unroll
        for (int mt = 0; mt < 2; mt++)
            #pragma unroll
            for (int nt = 0; nt < 2; nt++) {
                int lane8 = (mt * 2 + (q >> 1)) * 16 + l15;
                #pragma unroll
                for (int r = 0; r < 4; r++)
                    pb[(nt * 64 + lane8) * 8 + (q & 1) * 4 + r] = f2bf(acc[mt][nt][r]);
            }
        uint4 f0 = *(uint4*)(pb + (0 * 64 + lane) * 8);
        uint4 f1 = *(uint4*)(pb + (1 * 64 + lane) * 8);
        int h2b0 = h2w >> 4;
        *(uint4*)(WWp + ((size_t)(h2b0 + 0) * 32 + hpb) * 512 + lane * 8) = f0;
        *(uint4*)(WWp + ((size_t)(h2b0 + 1) * 32 + hpb) * 512 + lane * 8) = f1;
        return;
    }

    {
        // ---------------- yw1: yW1[b][h2] = sum_d bf16(y) . W1bf ----------
        float* yW1 = ws + OFF_YW1;
        const int idx   = bid - 353;
        const int h2blk = idx & 7;     // 0..7
        const int bblk  = idx >> 3;    // 0..3
        const int h2w   = h2blk * 128 + w * 32;

        f32x4 acc[2][2] = {};
        #pragma unroll 4
        for (int ds = 0; ds < 16; ds++) {
            bf16x8 a[2];
            #pragma unroll
            for (int mt = 0; mt < 2; mt++) {
                const float* yr = y_init + (size_t)(bblk * 32 + mt * 16 + l15) * DD + ds * 32 + q * 8;
                float4 va = *(const float4*)yr;
                float4 vb = *(const float4*)(yr + 4);
                unsigned short tmp[8] = { f2bf(va.x), f2bf(va.y), f2bf(va.z), f2bf(va.w),
                                          f2bf(vb.x), f2bf(vb.y), f2bf(vb.z), f2bf(vb.w) };
                a[mt] = *(bf16x8*)tmp;
            }
            bf16x8 bb0, bb1;
            {
                unsigned short tb[8];
                #pragma unroll
                for (int e = 0; e < 8; e++)
                    tb[e] = f2bf(W1[(size_t)(ds * 32 + q * 8 + e) * HH + h2w + l15]);
                bb0 = *(bf16x8*)tb;
                #pragma unroll
                for (int e = 0; e < 8; e++)
                    tb[e] = f2bf(W1[(size_t)(ds * 32 + q * 8 + e) * HH + h2w + 16 + l15]);
                bb1 = *(bf16x8*)tb;
            }
            acc[0][0] = __builtin_amdgcn_mfma_f32_16x16x32_bf16(a[0], bb0, acc[0][0], 0, 0, 0);
            acc[0][1] = __builtin_amdgcn_mfma_f32_16x16x32_bf16(a[0], bb1, acc[0][1], 0, 0, 0);
            acc[1][0] = __builtin_amdgcn_mfma_f32_16x16x32_bf16(a[1], bb0, acc[1][0], 0, 0, 0);
            acc[1][1] = __builtin_amdgcn_mfma_f32_16x16x32_bf16(a[1], bb1, acc[1][1], 0, 0, 0);
        }
        #pragma unroll
        for (int mt = 0; mt < 2; mt++)
            #pragma unroll
            for (int nt = 0; nt < 2; nt++)
                #pragma unroll
                for (int r = 0; r < 4; r++) {
                    int b  = bblk * 32 + mt * 16 + q * 4 + r;
                    int h2 = h2w + nt * 16 + l15;
                    yW1[(size_t)b * HH + h2] = acc[mt][nt][r];
                }
    }
}

// ---------------------------------------------------------------------------
// K1_0 (first iteration only): stages B_init[b] fp32 -> LDS bf16 [n][d] (swz),
// G = A W1^T (B from W1p frags), Z = Phi_f^T G, tanh, P = Q^T T, pack -> Ptp.
// LDS: smA 32768 (t_sb overlays) + g_sb 8192 = 40960 B.
// ---------------------------------------------------------------------------
__global__ __launch_bounds__(256) void k1_kernel(
        const float* __restrict__ B_init,        // [B][512 d][32 n] fp32
        const unsigned short* __restrict__ W1p,  // frag-packed
        const float* __restrict__ b1,            // [1024]
        const float* __restrict__ ws,
        unsigned short* __restrict__ Ptp)        // [B][32 hs][2 mt][64][8] bf16
{
    __shared__ __align__(16) char smem[40960];
    unsigned short* smA  = (unsigned short*)smem;           // A [32 n][512 d] swz
    unsigned short* t_sb = (unsigned short*)smem;           // [128][72] (overlays A)
    unsigned short* g_sb = (unsigned short*)(smem + 32768); // [128][32]

    const int t    = threadIdx.x;
    const int lane = t & 63;
    const int w    = t >> 6;
    const int q    = lane >> 4;
    const int l15  = lane & 15;
    const int b    = blockIdx.y;
    const int hblk = blockIdx.x;
    const int hw   = hblk * 128 + w * 32;

    // stage: B_init[b] [512 d][32 n] fp32 -> smA bf16 [n][d] swizzled
    {
        const float* Bi = B_init + (size_t)b * DD * NB;
        #pragma unroll 8
        for (int i = 0; i < 64; i++) {
            int f = i * 256 + t;       // 0..16383
            int d = f >> 5, n = f & 31;
            *(unsigned short*)(smem + (((n << 10) + (d << 1)) ^ ((n & 7) << 4)))
                = f2bf(Bi[f]);
        }
    }
    __syncthreads();

    // Phase A: G = A W1^T, M=32(n) x N=32(h/wave) x K=512
    f32x4 acc[2][2] = {};
    const unsigned short* W1b = W1p + (size_t)(hw >> 4) * 8192;
    #pragma unroll 4
    for (int d0 = 0; d0 < DD; d0 += 32) {
        int c16 = (d0 >> 3) + q;
        int ds  = d0 >> 5;
        bf16x8 a0  = *(const bf16x8*)aS(smA, l15, c16);
        bf16x8 a1  = *(const bf16x8*)aS(smA, 16 + l15, c16);
        bf16x8 bb0 = *(const bf16x8*)(W1b + ds * 512 + lane * 8);
        bf16x8 bb1 = *(const bf16x8*)(W1b + 8192 + ds * 512 + lane * 8);
        acc[0][0] = __builtin_amdgcn_mfma_f32_16x16x32_bf16(a0, bb0, acc[0][0], 0, 0, 0);
        acc[0][1] = __builtin_amdgcn_mfma_f32_16x16x32_bf16(a0, bb1, acc[0][1], 0, 0, 0);
        acc[1][0] = __builtin_amdgcn_mfma_f32_16x16x32_bf16(a1, bb0, acc[1][0], 0, 0, 0);
        acc[1][1] = __builtin_amdgcn_mfma_f32_16x16x32_bf16(a1, bb1, acc[1][1], 0, 0, 0);
    }
    #pragma unroll
    for (int mt = 0; mt < 2; mt++)
        #pragma unroll
        for (int nt = 0; nt < 2; nt++) {
            int hl = w * 32 + nt * 16 + l15;
            store4bf(&g_sb[hl * 32 + mt * 16 + q * 4],
                     acc[mt][nt][0], acc[mt][nt][1], acc[mt][nt][2], acc[mt][nt][3]);
        }
    __syncthreads();   // all smA reads complete -> t_sb may overlay

    // Z = Phi_f^T G
    f32x4 zacc[4][2] = {};
    const unsigned short* PF = (const unsigned short*)(ws + OFF_PHIF_BF);
    bf16x8 gb[2];
    #pragma unroll
    for (int nt = 0; nt < 2; nt++)
        gb[nt] = *(const bf16x8*)(&g_sb[(w * 32 + nt * 16 + l15) * 32 + q * 8]);
    #pragma unroll
    for (int mt = 0; mt < 4; mt++) {
        bf16x8 af = *(const bf16x8*)(PF + (mt * 16 + l15) * 32 + q * 8);
        zacc[mt][0] = __builtin_amdgcn_mfma_f32_16x16x32_bf16(af, gb[0], zacc[mt][0], 0, 0, 0);
        zacc[mt][1] = __builtin_amdgcn_mfma_f32_16x16x32_bf16(af, gb[1], zacc[mt][1], 0, 0, 0);
    }

    const float* TTp = ws + OFF_TTRUE;
    float b1v[2] = { b1[hw + l15], b1[hw + 16 + l15] };
    #pragma unroll
    for (int mt = 0; mt < 4; mt++) {
        float4 ttv = *(const float4*)(TTp + mt * 16 + q * 4);
        #pragma unroll
        for (int nt = 0; nt < 2; nt++) {
            int hl = w * 32 + nt * 16 + l15;
            float v0 = tanh_fast(zacc[mt][nt][0] + ttv.x * b1v[nt]);
            float v1 = tanh_fast(zacc[mt][nt][1] + ttv.y * b1v[nt]);
            float v2 = tanh_fast(zacc[mt][nt][2] + ttv.z * b1v[nt]);
            float v3 = tanh_fast(zacc[mt][nt][3] + ttv.w * b1v[nt]);
            store4bf(&t_sb[hl * 72 + mt * 16 + q * 4], v0, v1, v2, v3);
        }
    }
    __syncthreads();

    // P = Q^T T
    f32x4 pacc[2][2] = {};
    const unsigned short* QT = (const unsigned short*)(ws + OFF_QT_BF);
    #pragma unroll
    for (int ks = 0; ks < 2; ks++) {
        bf16x8 bt[2];
        #pragma unroll
        for (int nt = 0; nt < 2; nt++)
            bt[nt] = *(const bf16x8*)(&t_sb[(w * 32 + nt * 16 + l15) * 72 + ks * 32 + q * 8]);
        #pragma unroll
        for (int jt = 0; jt < 2; jt++) {
            bf16x8 aq = *(const bf16x8*)(QT + (jt * 16 + l15) * 64 + ks * 32 + q * 8);
            pacc[jt][0] = __builtin_amdgcn_mfma_f32_16x16x32_bf16(aq, bt[0], pacc[jt][0], 0, 0, 0);
            pacc[jt][1] = __builtin_amdgcn_mfma_f32_16x16x32_bf16(aq, bt[1], pacc[jt][1], 0, 0, 0);
        }
    }

    // pack P -> Ptp via wave-private bounce (g_sb region dead after Z)
    {
        unsigned short* pb = g_sb + w * 1024;
        #pragma unroll
        for (int jt = 0; jt < 2; jt++)
            #pragma unroll
            for (int nt = 0; nt < 2; nt++) {
                int grp = (nt * 2 + (l15 >> 3)) & 3;
                #pragma unroll
                for (int r = 0; r < 4; r++) {
                    int lane8 = grp * 16 + q * 4 + r;
                    pb[(jt * 64 + lane8) * 8 + (l15 & 7)] = f2bf(pacc[jt][nt][r]);
                }
            }
        int hs = hblk * 4 + w;
        uint4 f0 = *(uint4*)(pb + (0 * 64 + lane) * 8);
        uint4 f1 = *(uint4*)(pb + (1 * 64 + lane) * 8);
        *(uint4*)(Ptp + (((size_t)(b * 32 + hs) * 2 + 0) * 64 + lane) * 8) = f0;
        *(uint4*)(Ptp + (((size_t)(b * 32 + hs) * 2 + 1) * 64 + lane) * 8) = f1;
    }
}

// ---------------------------------------------------------------------------
// KF (iterations 1..9 fused): G' = P.WW + u (x) yW1, then Z/tanh/P as k1.
// Pure streaming K-loop (K=1024, frag-packed A and B), no __syncthreads.
// ---------------------------------------------------------------------------
__global__ __launch_bounds__(256) void kf_kernel(
        const unsigned short* __restrict__ Ptin,  // [B][32 hs][2 mt][64][8]
        const unsigned short* __restrict__ WWp,   // [64 h2b][32 hs][64][8]
        const float* __restrict__ yW1,            // [B][1024] fp32
        const float* __restrict__ b1,
        const float* __restrict__ ws,
        unsigned short* __restrict__ Ptout)
{
    __shared__ __align__(16) unsigned short t_sb[128 * 72];
    __shared__ __align__(16) unsigned short g_sb[128 * 32];

    const int t    = threadIdx.x;
    const int lane = t & 63;
    const int w    = t >> 6;
    const int q    = lane >> 4;
    const int l15  = lane & 15;
    const int b    = blockIdx.y;
    const int hblk = blockIdx.x;
    const int hw   = hblk * 128 + w * 32;

    // G' = P.WW : M=32(j) x N=32(h2/wave) x K=1024
    f32x4 acc[2][2] = {};
    const unsigned short* Ab  = Ptin + (size_t)b * 32768;
    const unsigned short* WWb = WWp + (size_t)(hw >> 4) * 16384;
    #pragma unroll 4
    for (int s = 0; s < 32; s++) {
        bf16x8 a0  = *(const bf16x8*)(Ab + (s * 2 + 0) * 512 + lane * 8);
        bf16x8 a1  = *(const bf16x8*)(Ab + (s * 2 + 1) * 512 + lane * 8);
        bf16x8 bb0 = *(const bf16x8*)(WWb + s * 512 + lane * 8);
        bf16x8 bb1 = *(const bf16x8*)(WWb + 16384 + s * 512 + lane * 8);
        acc[0][0] = __builtin_amdgcn_mfma_f32_16x16x32_bf16(a0, bb0, acc[0][0], 0, 0, 0);
        acc[0][1] = __builtin_amdgcn_mfma_f32_16x16x32_bf16(a0, bb1, acc[0][1], 0, 0, 0);
        acc[1][0] = __builtin_amdgcn_mfma_f32_16x16x32_bf16(a1, bb0, acc[1][0], 0, 0, 0);
        acc[1][1] = __builtin_amdgcn_mfma_f32_16x16x32_bf16(a1, bb1, acc[1][1], 0, 0, 0);
    }

    // bias u[j]*yW1[b][h2], write g_sb[h_loc][j]
    const float* U = ws + OFF_U;
    float yw[2] = { yW1[(size_t)b * HH + hw + l15],
                    yW1[(size_t)b * HH + hw + 16 + l15] };
    #pragma unroll
    for (int mt = 0; mt < 2; mt++) {
        float4 uv = *(const float4*)(U + mt * 16 + q * 4);
        #pragma unroll
        for (int nt = 0; nt < 2; nt++) {
            int hl = w * 32 + nt * 16 + l15;
            store4bf(&g_sb[hl * 32 + mt * 16 + q * 4],
                     acc[mt][nt][0] + uv.x * yw[nt],
                     acc[mt][nt][1] + uv.y * yw[nt],
                     acc[mt][nt][2] + uv.z * yw[nt],
                     acc[mt][nt][3] + uv.w * yw[nt]);
        }
    }

    // Z = Phi_f^T G'
    f32x4 zacc[4][2] = {};
    const unsigned short* PF = (const unsigned short*)(ws + OFF_PHIF_BF);
    bf16x8 gb[2];
    #pragma unroll
    for (int nt = 0; nt < 2; nt++)
        gb[nt] = *(const bf16x8*)(&g_sb[(w * 32 + nt * 16 + l15) * 32 + q * 8]);
    #pragma unroll
    for (int mt = 0; mt < 4; mt++) {
        bf16x8 af = *(const bf16x8*)(PF + (mt * 16 + l15) * 32 + q * 8);
        zacc[mt][0] = __builtin_amdgcn_mfma_f32_16x16x32_bf16(af, gb[0], zacc[mt][0], 0, 0, 0);
        zacc[mt][1] = __builtin_amdgcn_mfma_f32_16x16x32_bf16(af, gb[1], zacc[mt][1], 0, 0, 0);
    }

    const float* TTp = ws + OFF_TTRUE;
    float b1v[2] = { b1[hw + l15], b1[hw + 16 + l15] };
    #pragma unroll
    for (int mt = 0; mt < 4; mt++) {
        float4 ttv = *(const float4*)(TTp + mt * 16 + q * 4);
        #pragma unroll
        for (int nt = 0; nt < 2; nt++) {
            int hl = w * 32 + nt * 16 + l15;
            float v0 = tanh_fast(zacc[mt][nt][0] + ttv.x * b1v[nt]);
            float v1 = tanh_fast(zacc[mt][nt][1] + ttv.y * b1v[nt]);
            float v2 = tanh_fast(zacc[mt][nt][2] + ttv.z * b1v[nt]);
            float v3 = tanh_fast(zacc[mt][nt][3] + ttv.w * b1v[nt]);
            store4bf(&t_sb[hl * 72 + mt * 16 + q * 4], v0, v1, v2, v3);
        }
    }

    // P = Q^T T
    f32x4 pacc[2][2] = {};
    const unsigned short* QT = (const unsigned short*)(ws + OFF_QT_BF);
    #pragma unroll
    for (int ks = 0; ks < 2; ks++) {
        bf16x8 bt[2];
        #pragma unroll
        for (int nt = 0; nt < 2; nt++)
            bt[nt] = *(const bf16x8*)(&t_sb[(w * 32 + nt * 16 + l15) * 72 + ks * 32 + q * 8]);
        #pragma unroll
        for (int jt = 0; jt < 2; jt++) {
            bf16x8 aq = *(const bf16x8*)(QT + (jt * 16 + l15) * 64 + ks * 32 + q * 8);
            pacc[jt][0] = __builtin_amdgcn_mfma_f32_16x16x32_bf16(aq, bt[0], pacc[jt][0], 0, 0, 0);
            pacc[jt][1] = __builtin_amdgcn_mfma_f32_16x16x32_bf16(aq, bt[1], pacc[jt][1], 0, 0, 0);
        }
    }

    // pack P -> Ptout (wave-private bounce in g_sb region)
    {
        unsigned short* pb = g_sb + w * 1024;
        #pragma unroll
        for (int jt = 0; jt < 2; jt++)
            #pragma unroll
            for (int nt = 0; nt < 2; nt++) {
                int grp = (nt * 2 + (l15 >> 3)) & 3;
                #pragma unroll
                for (int r = 0; r < 4; r++) {
                    int lane8 = grp * 16 + q * 4 + r;
                    pb[(jt * 64 + lane8) * 8 + (l15 & 7)] = f2bf(pacc[jt][nt][r]);
                }
            }
        int hs = hblk * 4 + w;
        uint4 f0 = *(uint4*)(pb + (0 * 64 + lane) * 8);
        uint4 f1 = *(uint4*)(pb + (1 * 64 + lane) * 8);
        *(uint4*)(Ptout + (((size_t)(b * 32 + hs) * 2 + 0) * 64 + lane) * 8) = f0;
        *(uint4*)(Ptout + (((size_t)(b * 32 + hs) * 2 + 1) * 64 + lane) * 8) = f1;
    }
}

// ---------------------------------------------------------------------------
// K2F (final): Bn_val[d][j] = sum_h P.W2 + y u  (fp32), then DIRECTLY:
//   out1[(b*DD+d)*NB+j] = Bn_val                (k3's copy, fused)
//   out0[t*(BB*DD)+b*DD+d] = sum_n Bn_val[d][n]*Phi_out[n][t]  (k3, fused)
// Same fp32 values & same ascending-n accumulation as the old k2+k3 pair.
// ---------------------------------------------------------------------------
__global__ __launch_bounds__(256) void k2f_kernel(
        const unsigned short* __restrict__ Ptp,  // [B][32 hs][2 mt][64][8] bf16
        const unsigned short* __restrict__ W2p,  // frag-packed
        const float* __restrict__ y_init,        // [B][512]
        const float* __restrict__ ws,
        float* __restrict__ out)
{
    __shared__ __align__(16) float ls[4 * 544];
    __shared__ float phiout_s[NB * TT];

    const int t    = threadIdx.x;
    const int lane = t & 63;
    const int w    = t >> 6;
    const int q    = lane >> 4;
    const int l15  = lane & 15;
    const int b    = blockIdx.y;
    const int dblk = blockIdx.x;        // 0..7
    const int dw   = dblk * 64 + w * 16;

    for (int f = t; f < NB * TT; f += 256) phiout_s[f] = ws[OFF_PHIOUT + f];

    f32x4 acc[2] = {};
    const unsigned short* Ab  = Ptp + (size_t)b * 32768;
    const unsigned short* W2b = W2p + (size_t)(dblk * 4 + w) * 16384;
    #pragma unroll 4
    for (int s = 0; s < 32; s++) {
        bf16x8 a0 = *(const bf16x8*)(Ab + (s * 2 + 0) * 512 + lane * 8);
        bf16x8 a1 = *(const bf16x8*)(Ab + (s * 2 + 1) * 512 + lane * 8);
        bf16x8 bb = *(const bf16x8*)(W2b + s * 512 + lane * 8);
        acc[0] = __builtin_amdgcn_mfma_f32_16x16x32_bf16(a0, bb, acc[0], 0, 0, 0);
        acc[1] = __builtin_amdgcn_mfma_f32_16x16x32_bf16(a1, bb, acc[1], 0, 0, 0);
    }

    const float* U = ws + OFF_U;
    float yv = y_init[(size_t)b * DD + dw + l15];
    #pragma unroll
    for (int mt = 0; mt < 2; mt++) {
        float4 uv = *(const float4*)(U + mt * 16 + q * 4);
        #pragma unroll
        for (int r = 0; r < 4; r++) {
            int j = mt * 16 + q * 4 + r;
            float uvr = (r == 0) ? uv.x : (r == 1) ? uv.y : (r == 2) ? uv.z : uv.w;
            ls[w * 544 + j * 17 + l15] = acc[mt][r] + yv * uvr;
        }
    }
    __syncthreads();

    // out1 = Bn copy (coalesced)
    float* out1 = out + (size_t)TT * BB * DD;
    #pragma unroll
    for (int it = 0; it < 8; it++) {
        int f = it * 64 + lane;
        int d_l = f >> 5, j2 = f & 31;
        out1[((size_t)b * DD + dw + d_l) * NB + j2] = ls[w * 544 + j2 * 17 + d_l];
    }

    // out0[t16, b, d] = sum_n val[d][n] * phiout[n][t16]   (64 d x 16 t per block)
    #pragma unroll
    for (int i = 0; i < 4; i++) {
        int idx = i * 256 + t;
        int t16 = idx >> 6, dl = idx & 63;
        float s = 0.f;
        #pragma unroll
        for (int n = 0; n < NB; n++)
            s += ls[(dl >> 4) * 544 + n * 17 + (dl & 15)] * phiout_s[n * TT + t16];
        out[(size_t)t16 * (BB * DD) + (size_t)b * DD + dblk * 64 + dl] = s;
    }
}

// ---------------------------------------------------------------------------
extern "C" void kernel_launch(void* const* d_in, const int* in_sizes, int n_in,
                              void* d_out, int out_size, void* d_ws, size_t ws_size,
                              hipStream_t stream) {
    const float* t_span = (const float*)d_in[0];
    const float* y_init = (const float*)d_in[1];
    const float* B_init = (const float*)d_in[2];
    const float* W1     = (const float*)d_in[3];
    const float* b1     = (const float*)d_in[4];
    const float* W2     = (const float*)d_in[5];
    float* ws  = (float*)d_ws;
    float* out = (float*)d_out;

    unsigned short* W1p  = (unsigned short*)(ws + OFF_W1P);
    unsigned short* W2p  = (unsigned short*)(ws + OFF_W2P);
    unsigned short* WWp  = (unsigned short*)(ws + OFF_WWP);
    float*          yW1  = ws + OFF_YW1;
    unsigned short* PtpA = (unsigned short*)(ws + OFF_PTPA);
    unsigned short* PtpB = (unsigned short*)(ws + OFF_PTP0);

    // ONE prologue dispatch: setup + pack_w1 + pack_w2 + pack_ww + yw1
    prologue_kernel<<<dim3(385), 256, 0, stream>>>(t_span, W1, W2, y_init, ws);

    k1_kernel<<<dim3(8, BB), 256, 0, stream>>>(B_init, W1p, b1, ws, PtpA);

    unsigned short* pin  = PtpA;
    unsigned short* pout = PtpB;
    for (int it = 1; it < ITERS; it++) {
        kf_kernel<<<dim3(8, BB), 256, 0, stream>>>(pin, WWp, yW1, b1, ws, pout);
        unsigned short* tmp = pin; pin = pout; pout = tmp;
    }
    // 9 kf's -> final P in pin
    k2f_kernel<<<dim3(8, BB), 256, 0, stream>>>(pin, W2p, y_init, ws, out);
}

// Round 13
// 368.493 us; speedup vs baseline: 10.8068x; 1.0581x over previous
//
#include <hip/hip_runtime.h>
#include <hip/hip_bf16.h>
#include <math.h>

// Problem constants (fixed by setup_inputs)
#define BB 128
#define DD 512
#define HH 1024
#define NB 32     // num_coeff_per_dim
#define MM 63     // 2N-1 simpson points
#define TT 16
#define ITERS 10

// ws layout (float units)
#define OFF_U       0        // 32 fp32
#define OFF_TTRUE   64       // 64 fp32 (tt[63]=0)
#define OFF_PHIOUT  128      // 512 fp32
#define OFF_PHIF_BF 1024     // bf16 [64 m][32 n]  (row 63 = 0)   = 1024 floats
#define OFF_QT_BF   2048     // bf16 [32 j][64 m]  (col 63 = 0)   = 1024 floats
#define HDRF        4096
#define OFF_PTPA    HDRF                     // bf16 frag-packed [B][32 hs][2 mt][64][8] = 2097152 f
#define OFF_PTP0    (OFF_PTPA + 2097152)     // bf16 frag-packed ping-pong buffer       = 2097152 f
#define OFF_W1P     (OFF_PTP0 + 2097152)     // bf16 frag-packed [64 hb][16 ds][64][8] = 262144 f
#define OFF_W2P     (OFF_W1P + 262144)       // bf16 frag-packed [32 db][32 hs][64][8] = 262144 f
#define OFF_WWP     (OFF_W2P + 262144)       // bf16 frag-packed [64 h2b][32 hs][64][8] = 524288 f
#define OFF_YW1     (OFF_WWP + 524288)       // fp32 [128 b][1024 h2] = 131072 f
// end = 5378048 floats = 21.5 MB

typedef __attribute__((ext_vector_type(8))) short bf16x8;
typedef __attribute__((ext_vector_type(4))) float f32x4;

static __device__ __forceinline__ unsigned short f2bf(float f) {
    unsigned int x = __builtin_bit_cast(unsigned int, f);
    unsigned int r = x + 0x7FFFu + ((x >> 16) & 1u);   // RNE
    return (unsigned short)(r >> 16);
}

static __device__ __forceinline__ void store4bf(unsigned short* p,
                                                float v0, float v1, float v2, float v3) {
    unsigned int lo = (unsigned int)f2bf(v0) | ((unsigned int)f2bf(v1) << 16);
    unsigned int hi = (unsigned int)f2bf(v2) | ((unsigned int)f2bf(v3) << 16);
    uint2 u; u.x = lo; u.y = hi;
    *(uint2*)p = u;   // 8B-aligned by construction
}

static __device__ __forceinline__ float tanh_fast(float x) {
    float e = exp2f(x * 2.88539008177793f);   // 2*log2(e)
    return 1.0f - 2.0f / (e + 1.0f);
}

// XOR-swizzled LDS A-tile addressing: tile [32 r][512 c] bf16, linear 32KB,
// byte = (r*1024 + c*2) ^ ((r&7)<<4). Bijective per row, 16B-aligned b128.
static __device__ __forceinline__ unsigned short* aS(unsigned short* smA, int r, int c16) {
    return (unsigned short*)((char*)smA + (((r << 10) + (c16 << 4)) ^ ((r & 7) << 4)));
}

// ---------------------------------------------------------------------------
// PROLOGUE (single dispatch, blocks partitioned by role):
//   bid 0        : setup
//   bid 1..64    : pack_w1   (hb = bid-1)
//   bid 65..96   : pack_w2   (db = bid-65)
//   bid 97..352  : pack_ww   (idx: h2grp = idx&31 [32 cols], hpb = (idx>>5)*4+w)
//   bid 353..384 : yw1       (h2grp = bid-353 [32 cols], waves = b-tiles)
// pack_ww / yw1 now stage their W1 column-slice in LDS via COALESCED reads
// (was: 256 scalar 4KB-strided gathers per lane -- the 62.7us hotspot).
// Same f2bf per element -> bitwise-identical fragments.
// ---------------------------------------------------------------------------
__global__ __launch_bounds__(256) void prologue_kernel(
        const float* __restrict__ t_span, const float* __restrict__ W1,
        const float* __restrict__ W2, const float* __restrict__ y_init,
        float* __restrict__ ws) {
    __shared__ __align__(16) char smem[66560];
    const int bid  = blockIdx.x;
    const int t    = threadIdx.x;
    const int lane = t & 63;
    const int w    = t >> 6;
    const int q    = lane >> 4;
    const int l15  = lane & 15;

    if (bid == 0) {
        // ---------------- setup ----------------
        double* tsim    = (double*)(smem + 0);       // 63
        double* ttrue_d = (double*)(smem + 512);     // 63
        double* wid     = (double*)(smem + 1024);    // 31
        double* phid    = (double*)(smem + 1280);    // 32*63
        double* aug     = (double*)(smem + 17408);   // 32*64
        double* mlt     = (double*)(smem + 33792);   // 32
        double* Rl      = (double*)(smem + 34048);   // 63*32
        double* Qd      = (double*)(smem + 50176);   // 63*32
        int*    piv_s   = (int*)(smem + 66304);

        const int rgrp = t >> 6;
        const double PI = 3.14159265358979323846;
        const double t0 = (double)t_span[0];
        const double t1 = (double)t_span[TT - 1];

        if (t < MM) {
            double v;
            if ((t & 1) == 0) {
                int j = t >> 1;
                v = -cos(PI * (double)j / (double)(NB - 1));
            } else {
                int i = t >> 1;
                double a = -cos(PI * (double)i / (double)(NB - 1));
                double b = -cos(PI * (double)(i + 1) / (double)(NB - 1));
                v = 0.5 * (a + b);
            }
            tsim[t] = v;
            ttrue_d[t] = t0 + 0.5 * (t1 - t0) * (v + 1.0);
        }
        __syncthreads();
        if (t < 31) wid[t] = (ttrue_d[2 * t + 2] - ttrue_d[2 * t]) / 6.0;
        if (t < MM) ws[OFF_TTRUE + t] = (float)ttrue_d[t];
        if (t == 63) ws[OFF_TTRUE + 63] = 0.0f;

        if (t < MM) {
            double x = tsim[t];
            double r0 = 1.0, r1 = x;
            phid[0 * MM + t] = r0;
            phid[1 * MM + t] = r1;
            for (int n = 2; n < NB; n++) {
                double r2 = 2.0 * x * r1 - r0;
                phid[n * MM + t] = r2;
                r0 = r1; r1 = r2;
            }
        }
        __syncthreads();

        {   // phif_bf [m 64][n 32], row 63 = 0
            unsigned short* pf = (unsigned short*)(ws + OFF_PHIF_BF);
            for (int f = t; f < 64 * 32; f += 256) {
                int m = f >> 5, n = f & 31;
                pf[f] = f2bf(m < MM ? (float)phid[n * MM + m] : 0.0f);
            }
        }

        for (int f = t; f < NB * 64; f += 256) {
            int r = f >> 6, c = f & 63;
            double v;
            if (c < NB) v = phid[r * MM + 2 * c];
            else        v = ((c - NB) == r) ? 1.0 : 0.0;
            aug[f] = v;
        }
        __syncthreads();

        for (int k = 0; k < NB; k++) {
            if (t < 32) {
                double v = (t >= k) ? fabs(aug[t * 64 + k]) : -1.0;
                int idx = t;
                #pragma unroll
                for (int off = 16; off >= 1; off >>= 1) {
                    double ov = __shfl_xor(v, off);
                    int    oi = __shfl_xor(idx, off);
                    if (ov > v) { v = ov; idx = oi; }
                }
                if (t == 0) *piv_s = idx;
            }
            __syncthreads();
            const int p = *piv_s;
            if (t < 64) {
                double pv   = aug[p * 64 + k];
                double rowp = aug[p * 64 + t];
                double rowk = aug[k * 64 + t];
                aug[k * 64 + t] = rowp / pv;
                if (p != k) aug[p * 64 + t] = rowk;
            }
            __syncthreads();
            if (t < 32) mlt[t] = (t == k) ? 0.0 : aug[t * 64 + k];
            __syncthreads();
            {
                double pk = aug[k * 64 + lane];
                #pragma unroll
                for (int i = 0; i < 8; i++) {
                    int r = rgrp * 8 + i;
                    aug[r * 64 + lane] -= mlt[r] * pk;
                }
            }
            __syncthreads();
        }

        if (t < MM) {
            double acc = 0.0;
            Rl[t * NB + 0] = 0.0;
            for (int i = 1; i < NB; i++) {
                int ip = i - 1;
                double wv = 0.0;
                if (t == 2 * ip)     wv += wid[ip];
                if (t == 2 * ip + 1) wv += 4.0 * wid[ip];
                if (t == 2 * ip + 2) wv += wid[ip];
                acc += wv;
                Rl[t * NB + i] = acc;
            }
        }
        __syncthreads();

        for (int f = t; f < MM * NB; f += 256) {
            int m = f >> 5, j = f & 31;
            double s = 0.0;
            for (int i = 0; i < NB; i++) s += Rl[m * NB + i] * aug[i * 64 + 32 + j];
            Qd[f] = s;
        }
        __syncthreads();

        {   // qt_bf [j 32][m 64], col 63 = 0
            unsigned short* qt = (unsigned short*)(ws + OFF_QT_BF);
            for (int f = t; f < 32 * 64; f += 256) {
                int j = f >> 6, m = f & 63;
                qt[f] = f2bf(m < MM ? (float)Qd[m * NB + j] : 0.0f);
            }
        }
        if (t < NB) {
            double s = 0.0;
            for (int i = 0; i < NB; i++) s += aug[i * 64 + 32 + t];
            ws[OFF_U + t] = (float)s;
        }
        if (t < TT) {
            double x = -1.0 + 2.0 * ((double)t_span[t] - t0) / (t1 - t0);
            double r0 = 1.0, r1 = x;
            ws[OFF_PHIOUT + 0 * TT + t] = 1.0f;
            ws[OFF_PHIOUT + 1 * TT + t] = (float)x;
            for (int n = 2; n < NB; n++) {
                double r2 = 2.0 * x * r1 - r0;
                ws[OFF_PHIOUT + n * TT + t] = (float)r2;
                r0 = r1; r1 = r2;
            }
        }
        return;
    }

    if (bid <= 64) {
        // ---------------- pack_w1: hb = bid-1 ----------------
        unsigned short* W1p = (unsigned short*)(ws + OFF_W1P);
        const int hb = bid - 1;
        #pragma unroll
        for (int i = 0; i < 4; i++) {
            int f = i * 256 + t;
            int ds = f >> 6, ln = f & 63;
            int qq = ln >> 4, ll = ln & 15;
            unsigned short tmp[8];
            #pragma unroll
            for (int e = 0; e < 8; e++)
                tmp[e] = f2bf(W1[(size_t)(ds * 32 + qq * 8 + e) * HH + hb * 16 + ll]);
            *(uint4*)(W1p + ((size_t)(hb * 16 + ds) * 64 + ln) * 8) = *(uint4*)tmp;
        }
        return;
    }

    if (bid <= 96) {
        // ---------------- pack_w2: db = bid-65 ----------------
        unsigned short* W2p = (unsigned short*)(ws + OFF_W2P);
        const int db = bid - 65;
        #pragma unroll
        for (int i = 0; i < 8; i++) {
            int f = i * 256 + t;
            int hs = f >> 6, ln = f & 63;
            int qq = ln >> 4, ll = ln & 15;
            unsigned short tmp[8];
            #pragma unroll
            for (int e = 0; e < 8; e++)
                tmp[e] = f2bf(W2[(size_t)(hs * 32 + qq * 8 + e) * DD + db * 16 + ll]);
            *(uint4*)(W2p + ((size_t)(db * 32 + hs) * 64 + ln) * 8) = *(uint4*)tmp;
        }
        return;
    }

    // shared helper region for pack_ww / yw1:
    // lw1 = bf16 [512 row][36 col-stride] staged W1 slice (36864 B)
    unsigned short* lw1 = (unsigned short*)smem;

    if (bid <= 352) {
        // ---------------- pack_ww: WW = bf16(W2bf . W1bf), frag-packed ----
        unsigned short* WWp = (unsigned short*)(ws + OFF_WWP);
        unsigned short* pbounce = (unsigned short*)(smem + 36864);   // 8 KB
        const int idx   = bid - 97;
        const int h2grp = idx & 31;           // 32-col group of h2
        const int hpb   = (idx >> 5) * 4 + w; // wave's h'-row block (0..31)
        const int h2c0  = h2grp * 32;

        // coalesced stage: W1[:, h2c0..h2c0+32) -> lw1 bf16
        for (int i = 0; i < 64; i++) {
            int f = i * 256 + t;
            int row = f >> 5, col = f & 31;
            lw1[row * 36 + col] = f2bf(W1[(size_t)row * HH + h2c0 + col]);
        }
        __syncthreads();

        f32x4 acc[2][2] = {};
        #pragma unroll 4
        for (int ds = 0; ds < 16; ds++) {
            bf16x8 a[2];
            #pragma unroll
            for (int mt = 0; mt < 2; mt++) {
                const float* w2r = W2 + (size_t)(hpb * 32 + mt * 16 + l15) * DD + ds * 32 + q * 8;
                float4 va = *(const float4*)w2r;
                float4 vb = *(const float4*)(w2r + 4);
                unsigned short tmp[8] = { f2bf(va.x), f2bf(va.y), f2bf(va.z), f2bf(va.w),
                                          f2bf(vb.x), f2bf(vb.y), f2bf(vb.z), f2bf(vb.w) };
                a[mt] = *(bf16x8*)tmp;
            }
            bf16x8 bb0, bb1;
            {
                unsigned short tb[8];
                #pragma unroll
                for (int e = 0; e < 8; e++)
                    tb[e] = lw1[(ds * 32 + q * 8 + e) * 36 + l15];
                bb0 = *(bf16x8*)tb;
                #pragma unroll
                for (int e = 0; e < 8; e++)
                    tb[e] = lw1[(ds * 32 + q * 8 + e) * 36 + 16 + l15];
                bb1 = *(bf16x8*)tb;
            }
            acc[0][0] = __builtin_amdgcn_mfma_f32_16x16x32_bf16(a[0], bb0, acc[0][0], 0, 0, 0);
            acc[0][1] = __builtin_amdgcn_mfma_f32_16x16x32_bf16(a[0], bb1, acc[0][1], 0, 0, 0);
            acc[1][0] = __builtin_amdgcn_mfma_f32_16x16x32_bf16(a[1], bb0, acc[1][0], 0, 0, 0);
            acc[1][1] = __builtin_amdgcn_mfma_f32_16x16x32_bf16(a[1], bb1, acc[1][1], 0, 0, 0);
        }
        unsigned short* pb = pbounce + w * 1024;
        #pragma unroll
        for (int mt = 0; mt < 2; mt++)
            #pragma unroll
            for (int nt = 0; nt < 2; nt++) {
                int lane8 = (mt * 2 + (q >> 1)) * 16 + l15;
                #pragma unroll
                for (int r = 0; r < 4; r++)
                    pb[(nt * 64 + lane8) * 8 + (q & 1) * 4 + r] = f2bf(acc[mt][nt][r]);
            }
        uint4 f0 = *(uint4*)(pb + (0 * 64 + lane) * 8);
        uint4 f1 = *(uint4*)(pb + (1 * 64 + lane) * 8);
        int h2b0 = h2grp * 2;
        *(uint4*)(WWp + ((size_t)(h2b0 + 0) * 32 + hpb) * 512 + lane * 8) = f0;
        *(uint4*)(WWp + ((size_t)(h2b0 + 1) * 32 + hpb) * 512 + lane * 8) = f1;
        return;
    }

    {
        // ---------------- yw1: yW1[b][h2] = sum_d bf16(y) . W1bf ----------
        // 32 blocks; block = 32-col h2 group; waves = b-tiles (w*32..+32).
        float* yW1 = ws + OFF_YW1;
        const int h2grp = bid - 353;   // 0..31
        const int h2c0  = h2grp * 32;

        for (int i = 0; i < 64; i++) {
            int f = i * 256 + t;
            int row = f >> 5, col = f & 31;
            lw1[row * 36 + col] = f2bf(W1[(size_t)row * HH + h2c0 + col]);
        }
        __syncthreads();

        f32x4 acc[2][2] = {};
        #pragma unroll 4
        for (int ds = 0; ds < 16; ds++) {
            bf16x8 a[2];
            #pragma unroll
            for (int mt = 0; mt < 2; mt++) {
                const float* yr = y_init + (size_t)(w * 32 + mt * 16 + l15) * DD + ds * 32 + q * 8;
                float4 va = *(const float4*)yr;
                float4 vb = *(const float4*)(yr + 4);
                unsigned short tmp[8] = { f2bf(va.x), f2bf(va.y), f2bf(va.z), f2bf(va.w),
                                          f2bf(vb.x), f2bf(vb.y), f2bf(vb.z), f2bf(vb.w) };
                a[mt] = *(bf16x8*)tmp;
            }
            bf16x8 bb0, bb1;
            {
                unsigned short tb[8];
                #pragma unroll
                for (int e = 0; e < 8; e++)
                    tb[e] = lw1[(ds * 32 + q * 8 + e) * 36 + l15];
                bb0 = *(bf16x8*)tb;
                #pragma unroll
                for (int e = 0; e < 8; e++)
                    tb[e] = lw1[(ds * 32 + q * 8 + e) * 36 + 16 + l15];
                bb1 = *(bf16x8*)tb;
            }
            acc[0][0] = __builtin_amdgcn_mfma_f32_16x16x32_bf16(a[0], bb0, acc[0][0], 0, 0, 0);
            acc[0][1] = __builtin_amdgcn_mfma_f32_16x16x32_bf16(a[0], bb1, acc[0][1], 0, 0, 0);
            acc[1][0] = __builtin_amdgcn_mfma_f32_16x16x32_bf16(a[1], bb0, acc[1][0], 0, 0, 0);
            acc[1][1] = __builtin_amdgcn_mfma_f32_16x16x32_bf16(a[1], bb1, acc[1][1], 0, 0, 0);
        }
        #pragma unroll
        for (int mt = 0; mt < 2; mt++)
            #pragma unroll
            for (int nt = 0; nt < 2; nt++)
                #pragma unroll
                for (int r = 0; r < 4; r++) {
                    int b  = w * 32 + mt * 16 + q * 4 + r;
                    int h2 = h2c0 + nt * 16 + l15;
                    yW1[(size_t)b * HH + h2] = acc[mt][nt][r];
                }
    }
}

// ---------------------------------------------------------------------------
// K1_0 (first iteration only). Grid 1024 1-D, XCD-swizzled: b = bid&127,
// hblk = bid>>7 -> bid%8 = b%8, so all 8 same-b blocks share one XCD
// (B_init[b] fetched once/XCD; W1p 2MB L2-resident; no capacity thrash).
// ---------------------------------------------------------------------------
__global__ __launch_bounds__(256) void k1_kernel(
        const float* __restrict__ B_init,        // [B][512 d][32 n] fp32
        const unsigned short* __restrict__ W1p,  // frag-packed
        const float* __restrict__ b1,            // [1024]
        const float* __restrict__ ws,
        unsigned short* __restrict__ Ptp)        // [B][32 hs][2 mt][64][8] bf16
{
    __shared__ __align__(16) char smem[40960];
    unsigned short* smA  = (unsigned short*)smem;           // A [32 n][512 d] swz
    unsigned short* t_sb = (unsigned short*)smem;           // [128][72] (overlays A)
    unsigned short* g_sb = (unsigned short*)(smem + 32768); // [128][32]

    const int t    = threadIdx.x;
    const int lane = t & 63;
    const int w    = t >> 6;
    const int q    = lane >> 4;
    const int l15  = lane & 15;
    const int bid  = blockIdx.x;
    const int b    = bid & 127;        // XCD affinity: bid%8 = b%8
    const int hblk = bid >> 7;
    const int hw   = hblk * 128 + w * 32;

    // stage: B_init[b] [512 d][32 n] fp32 -> smA bf16 [n][d] swizzled
    {
        const float* Bi = B_init + (size_t)b * DD * NB;
        #pragma unroll 8
        for (int i = 0; i < 64; i++) {
            int f = i * 256 + t;       // 0..16383
            int d = f >> 5, n = f & 31;
            *(unsigned short*)(smem + (((n << 10) + (d << 1)) ^ ((n & 7) << 4)))
                = f2bf(Bi[f]);
        }
    }
    __syncthreads();

    // Phase A: G = A W1^T, M=32(n) x N=32(h/wave) x K=512
    f32x4 acc[2][2] = {};
    const unsigned short* W1b = W1p + (size_t)(hw >> 4) * 8192;
    #pragma unroll 4
    for (int d0 = 0; d0 < DD; d0 += 32) {
        int c16 = (d0 >> 3) + q;
        int ds  = d0 >> 5;
        bf16x8 a0  = *(const bf16x8*)aS(smA, l15, c16);
        bf16x8 a1  = *(const bf16x8*)aS(smA, 16 + l15, c16);
        bf16x8 bb0 = *(const bf16x8*)(W1b + ds * 512 + lane * 8);
        bf16x8 bb1 = *(const bf16x8*)(W1b + 8192 + ds * 512 + lane * 8);
        acc[0][0] = __builtin_amdgcn_mfma_f32_16x16x32_bf16(a0, bb0, acc[0][0], 0, 0, 0);
        acc[0][1] = __builtin_amdgcn_mfma_f32_16x16x32_bf16(a0, bb1, acc[0][1], 0, 0, 0);
        acc[1][0] = __builtin_amdgcn_mfma_f32_16x16x32_bf16(a1, bb0, acc[1][0], 0, 0, 0);
        acc[1][1] = __builtin_amdgcn_mfma_f32_16x16x32_bf16(a1, bb1, acc[1][1], 0, 0, 0);
    }
    #pragma unroll
    for (int mt = 0; mt < 2; mt++)
        #pragma unroll
        for (int nt = 0; nt < 2; nt++) {
            int hl = w * 32 + nt * 16 + l15;
            store4bf(&g_sb[hl * 32 + mt * 16 + q * 4],
                     acc[mt][nt][0], acc[mt][nt][1], acc[mt][nt][2], acc[mt][nt][3]);
        }
    __syncthreads();   // all smA reads complete -> t_sb may overlay

    // Z = Phi_f^T G
    f32x4 zacc[4][2] = {};
    const unsigned short* PF = (const unsigned short*)(ws + OFF_PHIF_BF);
    bf16x8 gb[2];
    #pragma unroll
    for (int nt = 0; nt < 2; nt++)
        gb[nt] = *(const bf16x8*)(&g_sb[(w * 32 + nt * 16 + l15) * 32 + q * 8]);
    #pragma unroll
    for (int mt = 0; mt < 4; mt++) {
        bf16x8 af = *(const bf16x8*)(PF + (mt * 16 + l15) * 32 + q * 8);
        zacc[mt][0] = __builtin_amdgcn_mfma_f32_16x16x32_bf16(af, gb[0], zacc[mt][0], 0, 0, 0);
        zacc[mt][1] = __builtin_amdgcn_mfma_f32_16x16x32_bf16(af, gb[1], zacc[mt][1], 0, 0, 0);
    }

    const float* TTp = ws + OFF_TTRUE;
    float b1v[2] = { b1[hw + l15], b1[hw + 16 + l15] };
    #pragma unroll
    for (int mt = 0; mt < 4; mt++) {
        float4 ttv = *(const float4*)(TTp + mt * 16 + q * 4);
        #pragma unroll
        for (int nt = 0; nt < 2; nt++) {
            int hl = w * 32 + nt * 16 + l15;
            float v0 = tanh_fast(zacc[mt][nt][0] + ttv.x * b1v[nt]);
            float v1 = tanh_fast(zacc[mt][nt][1] + ttv.y * b1v[nt]);
            float v2 = tanh_fast(zacc[mt][nt][2] + ttv.z * b1v[nt]);
            float v3 = tanh_fast(zacc[mt][nt][3] + ttv.w * b1v[nt]);
            store4bf(&t_sb[hl * 72 + mt * 16 + q * 4], v0, v1, v2, v3);
        }
    }
    __syncthreads();

    // P = Q^T T
    f32x4 pacc[2][2] = {};
    const unsigned short* QT = (const unsigned short*)(ws + OFF_QT_BF);
    #pragma unroll
    for (int ks = 0; ks < 2; ks++) {
        bf16x8 bt[2];
        #pragma unroll
        for (int nt = 0; nt < 2; nt++)
            bt[nt] = *(const bf16x8*)(&t_sb[(w * 32 + nt * 16 + l15) * 72 + ks * 32 + q * 8]);
        #pragma unroll
        for (int jt = 0; jt < 2; jt++) {
            bf16x8 aq = *(const bf16x8*)(QT + (jt * 16 + l15) * 64 + ks * 32 + q * 8);
            pacc[jt][0] = __builtin_amdgcn_mfma_f32_16x16x32_bf16(aq, bt[0], pacc[jt][0], 0, 0, 0);
            pacc[jt][1] = __builtin_amdgcn_mfma_f32_16x16x32_bf16(aq, bt[1], pacc[jt][1], 0, 0, 0);
        }
    }

    // pack P -> Ptp via wave-private bounce (g_sb region dead after Z)
    {
        unsigned short* pb = g_sb + w * 1024;
        #pragma unroll
        for (int jt = 0; jt < 2; jt++)
            #pragma unroll
            for (int nt = 0; nt < 2; nt++) {
                int grp = (nt * 2 + (l15 >> 3)) & 3;
                #pragma unroll
                for (int r = 0; r < 4; r++) {
                    int lane8 = grp * 16 + q * 4 + r;
                    pb[(jt * 64 + lane8) * 8 + (l15 & 7)] = f2bf(pacc[jt][nt][r]);
                }
            }
        int hs = hblk * 4 + w;
        uint4 f0 = *(uint4*)(pb + (0 * 64 + lane) * 8);
        uint4 f1 = *(uint4*)(pb + (1 * 64 + lane) * 8);
        *(uint4*)(Ptp + (((size_t)(b * 32 + hs) * 2 + 0) * 64 + lane) * 8) = f0;
        *(uint4*)(Ptp + (((size_t)(b * 32 + hs) * 2 + 1) * 64 + lane) * 8) = f1;
    }
}

// ---------------------------------------------------------------------------
// KF (iterations 1..9 fused): G' = P.WW + u (x) yW1, then Z/tanh/P as k1.
// Grid 1024 1-D, XCD-swizzled (b = bid&127): each XCD holds 16 Ptin slices
// (512KB) + full WW (2MB) = 2.5MB < 4MB L2 (was: 4MB Ptin/XCD -> thrash).
// ---------------------------------------------------------------------------
__global__ __launch_bounds__(256) void kf_kernel(
        const unsigned short* __restrict__ Ptin,  // [B][32 hs][2 mt][64][8]
        const unsigned short* __restrict__ WWp,   // [64 h2b][32 hs][64][8]
        const float* __restrict__ yW1,            // [B][1024] fp32
        const float* __restrict__ b1,
        const float* __restrict__ ws,
        unsigned short* __restrict__ Ptout)
{
    __shared__ __align__(16) unsigned short t_sb[128 * 72];
    __shared__ __align__(16) unsigned short g_sb[128 * 32];

    const int t    = threadIdx.x;
    const int lane = t & 63;
    const int w    = t >> 6;
    const int q    = lane >> 4;
    const int l15  = lane & 15;
    const int bid  = blockIdx.x;
    const int b    = bid & 127;        // XCD affinity: bid%8 = b%8
    const int hblk = bid >> 7;
    const int hw   = hblk * 128 + w * 32;

    // G' = P.WW : M=32(j) x N=32(h2/wave) x K=1024
    f32x4 acc[2][2] = {};
    const unsigned short* Ab  = Ptin + (size_t)b * 32768;
    const unsigned short* WWb = WWp + (size_t)(hw >> 4) * 16384;
    #pragma unroll 4
    for (int s = 0; s < 32; s++) {
        bf16x8 a0  = *(const bf16x8*)(Ab + (s * 2 + 0) * 512 + lane * 8);
        bf16x8 a1  = *(const bf16x8*)(Ab + (s * 2 + 1) * 512 + lane * 8);
        bf16x8 bb0 = *(const bf16x8*)(WWb + s * 512 + lane * 8);
        bf16x8 bb1 = *(const bf16x8*)(WWb + 16384 + s * 512 + lane * 8);
        acc[0][0] = __builtin_amdgcn_mfma_f32_16x16x32_bf16(a0, bb0, acc[0][0], 0, 0, 0);
        acc[0][1] = __builtin_amdgcn_mfma_f32_16x16x32_bf16(a0, bb1, acc[0][1], 0, 0, 0);
        acc[1][0] = __builtin_amdgcn_mfma_f32_16x16x32_bf16(a1, bb0, acc[1][0], 0, 0, 0);
        acc[1][1] = __builtin_amdgcn_mfma_f32_16x16x32_bf16(a1, bb1, acc[1][1], 0, 0, 0);
    }

    // bias u[j]*yW1[b][h2], write g_sb[h_loc][j]
    const float* U = ws + OFF_U;
    float yw[2] = { yW1[(size_t)b * HH + hw + l15],
                    yW1[(size_t)b * HH + hw + 16 + l15] };
    #pragma unroll
    for (int mt = 0; mt < 2; mt++) {
        float4 uv = *(const float4*)(U + mt * 16 + q * 4);
        #pragma unroll
        for (int nt = 0; nt < 2; nt++) {
            int hl = w * 32 + nt * 16 + l15;
            store4bf(&g_sb[hl * 32 + mt * 16 + q * 4],
                     acc[mt][nt][0] + uv.x * yw[nt],
                     acc[mt][nt][1] + uv.y * yw[nt],
                     acc[mt][nt][2] + uv.z * yw[nt],
                     acc[mt][nt][3] + uv.w * yw[nt]);
        }
    }

    // Z = Phi_f^T G'
    f32x4 zacc[4][2] = {};
    const unsigned short* PF = (const unsigned short*)(ws + OFF_PHIF_BF);
    bf16x8 gb[2];
    #pragma unroll
    for (int nt = 0; nt < 2; nt++)
        gb[nt] = *(const bf16x8*)(&g_sb[(w * 32 + nt * 16 + l15) * 32 + q * 8]);
    #pragma unroll
    for (int mt = 0; mt < 4; mt++) {
        bf16x8 af = *(const bf16x8*)(PF + (mt * 16 + l15) * 32 + q * 8);
        zacc[mt][0] = __builtin_amdgcn_mfma_f32_16x16x32_bf16(af, gb[0], zacc[mt][0], 0, 0, 0);
        zacc[mt][1] = __builtin_amdgcn_mfma_f32_16x16x32_bf16(af, gb[1], zacc[mt][1], 0, 0, 0);
    }

    const float* TTp = ws + OFF_TTRUE;
    float b1v[2] = { b1[hw + l15], b1[hw + 16 + l15] };
    #pragma unroll
    for (int mt = 0; mt < 4; mt++) {
        float4 ttv = *(const float4*)(TTp + mt * 16 + q * 4);
        #pragma unroll
        for (int nt = 0; nt < 2; nt++) {
            int hl = w * 32 + nt * 16 + l15;
            float v0 = tanh_fast(zacc[mt][nt][0] + ttv.x * b1v[nt]);
            float v1 = tanh_fast(zacc[mt][nt][1] + ttv.y * b1v[nt]);
            float v2 = tanh_fast(zacc[mt][nt][2] + ttv.z * b1v[nt]);
            float v3 = tanh_fast(zacc[mt][nt][3] + ttv.w * b1v[nt]);
            store4bf(&t_sb[hl * 72 + mt * 16 + q * 4], v0, v1, v2, v3);
        }
    }

    // P = Q^T T
    f32x4 pacc[2][2] = {};
    const unsigned short* QT = (const unsigned short*)(ws + OFF_QT_BF);
    #pragma unroll
    for (int ks = 0; ks < 2; ks++) {
        bf16x8 bt[2];
        #pragma unroll
        for (int nt = 0; nt < 2; nt++)
            bt[nt] = *(const bf16x8*)(&t_sb[(w * 32 + nt * 16 + l15) * 72 + ks * 32 + q * 8]);
        #pragma unroll
        for (int jt = 0; jt < 2; jt++) {
            bf16x8 aq = *(const bf16x8*)(QT + (jt * 16 + l15) * 64 + ks * 32 + q * 8);
            pacc[jt][0] = __builtin_amdgcn_mfma_f32_16x16x32_bf16(aq, bt[0], pacc[jt][0], 0, 0, 0);
            pacc[jt][1] = __builtin_amdgcn_mfma_f32_16x16x32_bf16(aq, bt[1], pacc[jt][1], 0, 0, 0);
        }
    }

    // pack P -> Ptout (wave-private bounce in g_sb region)
    {
        unsigned short* pb = g_sb + w * 1024;
        #pragma unroll
        for (int jt = 0; jt < 2; jt++)
            #pragma unroll
            for (int nt = 0; nt < 2; nt++) {
                int grp = (nt * 2 + (l15 >> 3)) & 3;
                #pragma unroll
                for (int r = 0; r < 4; r++) {
                    int lane8 = grp * 16 + q * 4 + r;
                    pb[(jt * 64 + lane8) * 8 + (l15 & 7)] = f2bf(pacc[jt][nt][r]);
                }
            }
        int hs = hblk * 4 + w;
        uint4 f0 = *(uint4*)(pb + (0 * 64 + lane) * 8);
        uint4 f1 = *(uint4*)(pb + (1 * 64 + lane) * 8);
        *(uint4*)(Ptout + (((size_t)(b * 32 + hs) * 2 + 0) * 64 + lane) * 8) = f0;
        *(uint4*)(Ptout + (((size_t)(b * 32 + hs) * 2 + 1) * 64 + lane) * 8) = f1;
    }
}

// ---------------------------------------------------------------------------
// K2F (final): Bn_val = P.W2 + y u (fp32); writes out1 directly and
// out0 = sum_n Bn_val*Phi_out. Grid 1024 1-D, XCD-swizzled (b = bid&127).
// ---------------------------------------------------------------------------
__global__ __launch_bounds__(256) void k2f_kernel(
        const unsigned short* __restrict__ Ptp,  // [B][32 hs][2 mt][64][8] bf16
        const unsigned short* __restrict__ W2p,  // frag-packed
        const float* __restrict__ y_init,        // [B][512]
        const float* __restrict__ ws,
        float* __restrict__ out)
{
    __shared__ __align__(16) float ls[4 * 544];
    __shared__ float phiout_s[NB * TT];

    const int t    = threadIdx.x;
    const int lane = t & 63;
    const int w    = t >> 6;
    const int q    = lane >> 4;
    const int l15  = lane & 15;
    const int bid  = blockIdx.x;
    const int b    = bid & 127;        // XCD affinity
    const int dblk = bid >> 7;         // 0..7
    const int dw   = dblk * 64 + w * 16;

    for (int f = t; f < NB * TT; f += 256) phiout_s[f] = ws[OFF_PHIOUT + f];

    f32x4 acc[2] = {};
    const unsigned short* Ab  = Ptp + (size_t)b * 32768;
    const unsigned short* W2b = W2p + (size_t)(dblk * 4 + w) * 16384;
    #pragma unroll 4
    for (int s = 0; s < 32; s++) {
        bf16x8 a0 = *(const bf16x8*)(Ab + (s * 2 + 0) * 512 + lane * 8);
        bf16x8 a1 = *(const bf16x8*)(Ab + (s * 2 + 1) * 512 + lane * 8);
        bf16x8 bb = *(const bf16x8*)(W2b + s * 512 + lane * 8);
        acc[0] = __builtin_amdgcn_mfma_f32_16x16x32_bf16(a0, bb, acc[0], 0, 0, 0);
        acc[1] = __builtin_amdgcn_mfma_f32_16x16x32_bf16(a1, bb, acc[1], 0, 0, 0);
    }

    const float* U = ws + OFF_U;
    float yv = y_init[(size_t)b * DD + dw + l15];
    #pragma unroll
    for (int mt = 0; mt < 2; mt++) {
        float4 uv = *(const float4*)(U + mt * 16 + q * 4);
        #pragma unroll
        for (int r = 0; r < 4; r++) {
            int j = mt * 16 + q * 4 + r;
            float uvr = (r == 0) ? uv.x : (r == 1) ? uv.y : (r == 2) ? uv.z : uv.w;
            ls[w * 544 + j * 17 + l15] = acc[mt][r] + yv * uvr;
        }
    }
    __syncthreads();

    // out1 = Bn copy (coalesced)
    float* out1 = out + (size_t)TT * BB * DD;
    #pragma unroll
    for (int it = 0; it < 8; it++) {
        int f = it * 64 + lane;
        int d_l = f >> 5, j2 = f & 31;
        out1[((size_t)b * DD + dw + d_l) * NB + j2] = ls[w * 544 + j2 * 17 + d_l];
    }

    // out0[t16, b, d] = sum_n val[d][n] * phiout[n][t16]   (64 d x 16 t per block)
    #pragma unroll
    for (int i = 0; i < 4; i++) {
        int idx = i * 256 + t;
        int t16 = idx >> 6, dl = idx & 63;
        float s = 0.f;
        #pragma unroll
        for (int n = 0; n < NB; n++)
            s += ls[(dl >> 4) * 544 + n * 17 + (dl & 15)] * phiout_s[n * TT + t16];
        out[(size_t)t16 * (BB * DD) + (size_t)b * DD + dblk * 64 + dl] = s;
    }
}

// ---------------------------------------------------------------------------
extern "C" void kernel_launch(void* const* d_in, const int* in_sizes, int n_in,
                              void* d_out, int out_size, void* d_ws, size_t ws_size,
                              hipStream_t stream) {
    const float* t_span = (const float*)d_in[0];
    const float* y_init = (const float*)d_in[1];
    const float* B_init = (const float*)d_in[2];
    const float* W1     = (const float*)d_in[3];
    const float* b1     = (const float*)d_in[4];
    const float* W2     = (const float*)d_in[5];
    float* ws  = (float*)d_ws;
    float* out = (float*)d_out;

    unsigned short* W1p  = (unsigned short*)(ws + OFF_W1P);
    unsigned short* W2p  = (unsigned short*)(ws + OFF_W2P);
    unsigned short* WWp  = (unsigned short*)(ws + OFF_WWP);
    float*          yW1  = ws + OFF_YW1;
    unsigned short* PtpA = (unsigned short*)(ws + OFF_PTPA);
    unsigned short* PtpB = (unsigned short*)(ws + OFF_PTP0);

    // ONE prologue dispatch: setup + pack_w1 + pack_w2 + pack_ww + yw1
    prologue_kernel<<<dim3(385), 256, 0, stream>>>(t_span, W1, W2, y_init, ws);

    k1_kernel<<<dim3(1024), 256, 0, stream>>>(B_init, W1p, b1, ws, PtpA);

    unsigned short* pin  = PtpA;
    unsigned short* pout = PtpB;
    for (int it = 1; it < ITERS; it++) {
        kf_kernel<<<dim3(1024), 256, 0, stream>>>(pin, WWp, yW1, b1, ws, pout);
        unsigned short* tmp = pin; pin = pout; pout = tmp;
    }
    // 9 kf's -> final P in pin
    k2f_kernel<<<dim3(1024), 256, 0, stream>>>(pin, W2p, y_init, ws, out);
}

// Round 14
// 361.671 us; speedup vs baseline: 11.0106x; 1.0189x over previous
//
#include <hip/hip_runtime.h>
#include <hip/hip_bf16.h>
#include <math.h>

// Problem constants (fixed by setup_inputs)
#define BB 128
#define DD 512
#define HH 1024
#define NB 32     // num_coeff_per_dim
#define MM 63     // 2N-1 simpson points
#define TT 16
#define ITERS 10

// ws layout (float units)
#define OFF_U       0        // 32 fp32
#define OFF_TTRUE   64       // 64 fp32 (tt[63]=0)
#define OFF_PHIOUT  128      // 512 fp32
#define OFF_PHIF_BF 1024     // bf16 [64 m][32 n]  (row 63 = 0)   = 1024 floats
#define OFF_QT_BF   2048     // bf16 [32 j][64 m]  (col 63 = 0)   = 1024 floats
#define HDRF        4096
#define OFF_PTPA    HDRF                     // bf16 frag-packed [B][32 hs][2 mt][64][8] = 2097152 f
#define OFF_PTP0    (OFF_PTPA + 2097152)     // bf16 frag-packed ping-pong buffer       = 2097152 f
#define OFF_W1P     (OFF_PTP0 + 2097152)     // bf16 frag-packed [64 hb][16 ds][64][8] = 262144 f
#define OFF_W2P     (OFF_W1P + 262144)       // bf16 frag-packed [32 db][32 hs][64][8] = 262144 f
#define OFF_WWP     (OFF_W2P + 262144)       // bf16 frag-packed [64 h2b][32 hs][64][8] = 524288 f
#define OFF_YW1     (OFF_WWP + 524288)       // fp32 [128 b][1024 h2] = 131072 f
// end = 5378048 floats = 21.5 MB

typedef __attribute__((ext_vector_type(8))) short bf16x8;
typedef __attribute__((ext_vector_type(4))) float f32x4;

static __device__ __forceinline__ unsigned short f2bf(float f) {
    unsigned int x = __builtin_bit_cast(unsigned int, f);
    unsigned int r = x + 0x7FFFu + ((x >> 16) & 1u);   // RNE
    return (unsigned short)(r >> 16);
}

static __device__ __forceinline__ void store4bf(unsigned short* p,
                                                float v0, float v1, float v2, float v3) {
    unsigned int lo = (unsigned int)f2bf(v0) | ((unsigned int)f2bf(v1) << 16);
    unsigned int hi = (unsigned int)f2bf(v2) | ((unsigned int)f2bf(v3) << 16);
    uint2 u; u.x = lo; u.y = hi;
    *(uint2*)p = u;   // 8B-aligned by construction
}

static __device__ __forceinline__ float tanh_fast(float x) {
    float e = exp2f(x * 2.88539008177793f);   // 2*log2(e)
    return 1.0f - 2.0f / (e + 1.0f);
}

// XOR-swizzled LDS A-tile addressing: tile [32 r][512 c] bf16, linear 32KB,
// byte = (r*1024 + c*2) ^ ((r&7)<<4). Bijective per row, 16B-aligned b128.
static __device__ __forceinline__ unsigned short* aS(unsigned short* smA, int r, int c16) {
    return (unsigned short*)((char*)smA + (((r << 10) + (c16 << 4)) ^ ((r & 7) << 4)));
}

// ---------------------------------------------------------------------------
// PROLOGUE (single dispatch, blocks partitioned by role):
//   bid 0        : setup
//   bid 1..64    : pack_w1   (hb = bid-1)
//   bid 65..96   : pack_w2   (db = bid-65)
//   bid 97..352  : pack_ww   (idx: h2grp = idx&31, hpb = (idx>>5)*4+w)
//   bid 353..384 : yw1       (h2grp = bid-353, waves = b-tiles)
// pack_ww/yw1: W1 slice staged TRANSPOSED in LDS (lw1t[col][row], 520-stride)
// so fragment reads are single b128 (was: 8 scalar ds_read_u16 per operand).
// Same f2bf per element -> bitwise-identical fragments.
// ---------------------------------------------------------------------------
__global__ __launch_bounds__(256) void prologue_kernel(
        const float* __restrict__ t_span, const float* __restrict__ W1,
        const float* __restrict__ W2, const float* __restrict__ y_init,
        float* __restrict__ ws) {
    __shared__ __align__(16) char smem[66560];
    const int bid  = blockIdx.x;
    const int t    = threadIdx.x;
    const int lane = t & 63;
    const int w    = t >> 6;
    const int q    = lane >> 4;
    const int l15  = lane & 15;

    if (bid == 0) {
        // ---------------- setup ----------------
        double* tsim    = (double*)(smem + 0);       // 63
        double* ttrue_d = (double*)(smem + 512);     // 63
        double* wid     = (double*)(smem + 1024);    // 31
        double* phid    = (double*)(smem + 1280);    // 32*63
        double* aug     = (double*)(smem + 17408);   // 32*64
        double* mlt     = (double*)(smem + 33792);   // 32
        double* Rl      = (double*)(smem + 34048);   // 63*32
        double* Qd      = (double*)(smem + 50176);   // 63*32
        int*    piv_s   = (int*)(smem + 66304);

        const int rgrp = t >> 6;
        const double PI = 3.14159265358979323846;
        const double t0 = (double)t_span[0];
        const double t1 = (double)t_span[TT - 1];

        if (t < MM) {
            double v;
            if ((t & 1) == 0) {
                int j = t >> 1;
                v = -cos(PI * (double)j / (double)(NB - 1));
            } else {
                int i = t >> 1;
                double a = -cos(PI * (double)i / (double)(NB - 1));
                double b = -cos(PI * (double)(i + 1) / (double)(NB - 1));
                v = 0.5 * (a + b);
            }
            tsim[t] = v;
            ttrue_d[t] = t0 + 0.5 * (t1 - t0) * (v + 1.0);
        }
        __syncthreads();
        if (t < 31) wid[t] = (ttrue_d[2 * t + 2] - ttrue_d[2 * t]) / 6.0;
        if (t < MM) ws[OFF_TTRUE + t] = (float)ttrue_d[t];
        if (t == 63) ws[OFF_TTRUE + 63] = 0.0f;

        if (t < MM) {
            double x = tsim[t];
            double r0 = 1.0, r1 = x;
            phid[0 * MM + t] = r0;
            phid[1 * MM + t] = r1;
            for (int n = 2; n < NB; n++) {
                double r2 = 2.0 * x * r1 - r0;
                phid[n * MM + t] = r2;
                r0 = r1; r1 = r2;
            }
        }
        __syncthreads();

        {   // phif_bf [m 64][n 32], row 63 = 0
            unsigned short* pf = (unsigned short*)(ws + OFF_PHIF_BF);
            for (int f = t; f < 64 * 32; f += 256) {
                int m = f >> 5, n = f & 31;
                pf[f] = f2bf(m < MM ? (float)phid[n * MM + m] : 0.0f);
            }
        }

        for (int f = t; f < NB * 64; f += 256) {
            int r = f >> 6, c = f & 63;
            double v;
            if (c < NB) v = phid[r * MM + 2 * c];
            else        v = ((c - NB) == r) ? 1.0 : 0.0;
            aug[f] = v;
        }
        __syncthreads();

        for (int k = 0; k < NB; k++) {
            if (t < 32) {
                double v = (t >= k) ? fabs(aug[t * 64 + k]) : -1.0;
                int idx = t;
                #pragma unroll
                for (int off = 16; off >= 1; off >>= 1) {
                    double ov = __shfl_xor(v, off);
                    int    oi = __shfl_xor(idx, off);
                    if (ov > v) { v = ov; idx = oi; }
                }
                if (t == 0) *piv_s = idx;
            }
            __syncthreads();
            const int p = *piv_s;
            if (t < 64) {
                double pv   = aug[p * 64 + k];
                double rowp = aug[p * 64 + t];
                double rowk = aug[k * 64 + t];
                aug[k * 64 + t] = rowp / pv;
                if (p != k) aug[p * 64 + t] = rowk;
            }
            __syncthreads();
            if (t < 32) mlt[t] = (t == k) ? 0.0 : aug[t * 64 + k];
            __syncthreads();
            {
                double pk = aug[k * 64 + lane];
                #pragma unroll
                for (int i = 0; i < 8; i++) {
                    int r = rgrp * 8 + i;
                    aug[r * 64 + lane] -= mlt[r] * pk;
                }
            }
            __syncthreads();
        }

        if (t < MM) {
            double acc = 0.0;
            Rl[t * NB + 0] = 0.0;
            for (int i = 1; i < NB; i++) {
                int ip = i - 1;
                double wv = 0.0;
                if (t == 2 * ip)     wv += wid[ip];
                if (t == 2 * ip + 1) wv += 4.0 * wid[ip];
                if (t == 2 * ip + 2) wv += wid[ip];
                acc += wv;
                Rl[t * NB + i] = acc;
            }
        }
        __syncthreads();

        for (int f = t; f < MM * NB; f += 256) {
            int m = f >> 5, j = f & 31;
            double s = 0.0;
            for (int i = 0; i < NB; i++) s += Rl[m * NB + i] * aug[i * 64 + 32 + j];
            Qd[f] = s;
        }
        __syncthreads();

        {   // qt_bf [j 32][m 64], col 63 = 0
            unsigned short* qt = (unsigned short*)(ws + OFF_QT_BF);
            for (int f = t; f < 32 * 64; f += 256) {
                int j = f >> 6, m = f & 63;
                qt[f] = f2bf(m < MM ? (float)Qd[m * NB + j] : 0.0f);
            }
        }
        if (t < NB) {
            double s = 0.0;
            for (int i = 0; i < NB; i++) s += aug[i * 64 + 32 + t];
            ws[OFF_U + t] = (float)s;
        }
        if (t < TT) {
            double x = -1.0 + 2.0 * ((double)t_span[t] - t0) / (t1 - t0);
            double r0 = 1.0, r1 = x;
            ws[OFF_PHIOUT + 0 * TT + t] = 1.0f;
            ws[OFF_PHIOUT + 1 * TT + t] = (float)x;
            for (int n = 2; n < NB; n++) {
                double r2 = 2.0 * x * r1 - r0;
                ws[OFF_PHIOUT + n * TT + t] = (float)r2;
                r0 = r1; r1 = r2;
            }
        }
        return;
    }

    if (bid <= 64) {
        // ---------------- pack_w1: hb = bid-1 ----------------
        unsigned short* W1p = (unsigned short*)(ws + OFF_W1P);
        const int hb = bid - 1;
        #pragma unroll
        for (int i = 0; i < 4; i++) {
            int f = i * 256 + t;
            int ds = f >> 6, ln = f & 63;
            int qq = ln >> 4, ll = ln & 15;
            unsigned short tmp[8];
            #pragma unroll
            for (int e = 0; e < 8; e++)
                tmp[e] = f2bf(W1[(size_t)(ds * 32 + qq * 8 + e) * HH + hb * 16 + ll]);
            *(uint4*)(W1p + ((size_t)(hb * 16 + ds) * 64 + ln) * 8) = *(uint4*)tmp;
        }
        return;
    }

    if (bid <= 96) {
        // ---------------- pack_w2: db = bid-65 ----------------
        unsigned short* W2p = (unsigned short*)(ws + OFF_W2P);
        const int db = bid - 65;
        #pragma unroll
        for (int i = 0; i < 8; i++) {
            int f = i * 256 + t;
            int hs = f >> 6, ln = f & 63;
            int qq = ln >> 4, ll = ln & 15;
            unsigned short tmp[8];
            #pragma unroll
            for (int e = 0; e < 8; e++)
                tmp[e] = f2bf(W2[(size_t)(hs * 32 + qq * 8 + e) * DD + db * 16 + ll]);
            *(uint4*)(W2p + ((size_t)(db * 32 + hs) * 64 + ln) * 8) = *(uint4*)tmp;
        }
        return;
    }

    // lw1t = bf16 TRANSPOSED W1 slice: [32 col][520 row-stride] = 33280 B.
    // Fragment read = one b128 at lw1t[col*520 + ds*32 + q*8] (1040B row
    // stride = 65x16B aligned; lanes hit banks at 4-step -> <=2-way).
    unsigned short* lw1t = (unsigned short*)smem;

    if (bid <= 352) {
        // ---------------- pack_ww: WW = bf16(W2bf . W1bf), frag-packed ----
        unsigned short* WWp = (unsigned short*)(ws + OFF_WWP);
        unsigned short* pbounce = (unsigned short*)(smem + 33280);   // 8 KB
        const int idx   = bid - 97;
        const int h2grp = idx & 31;           // 32-col group of h2
        const int hpb   = (idx >> 5) * 4 + w; // wave's h'-row block (0..31)
        const int h2c0  = h2grp * 32;

        // coalesced stage: W1[:, h2c0..h2c0+32) -> lw1t[col][row] bf16
        for (int i = 0; i < 64; i++) {
            int f = i * 256 + t;
            int row = f >> 5, col = f & 31;
            lw1t[col * 520 + row] = f2bf(W1[(size_t)row * HH + h2c0 + col]);
        }
        __syncthreads();

        f32x4 acc[2][2] = {};
        #pragma unroll 4
        for (int ds = 0; ds < 16; ds++) {
            bf16x8 a[2];
            #pragma unroll
            for (int mt = 0; mt < 2; mt++) {
                const float* w2r = W2 + (size_t)(hpb * 32 + mt * 16 + l15) * DD + ds * 32 + q * 8;
                float4 va = *(const float4*)w2r;
                float4 vb = *(const float4*)(w2r + 4);
                unsigned short tmp[8] = { f2bf(va.x), f2bf(va.y), f2bf(va.z), f2bf(va.w),
                                          f2bf(vb.x), f2bf(vb.y), f2bf(vb.z), f2bf(vb.w) };
                a[mt] = *(bf16x8*)tmp;
            }
            bf16x8 bb0 = *(const bf16x8*)(lw1t + l15 * 520 + ds * 32 + q * 8);
            bf16x8 bb1 = *(const bf16x8*)(lw1t + (16 + l15) * 520 + ds * 32 + q * 8);
            acc[0][0] = __builtin_amdgcn_mfma_f32_16x16x32_bf16(a[0], bb0, acc[0][0], 0, 0, 0);
            acc[0][1] = __builtin_amdgcn_mfma_f32_16x16x32_bf16(a[0], bb1, acc[0][1], 0, 0, 0);
            acc[1][0] = __builtin_amdgcn_mfma_f32_16x16x32_bf16(a[1], bb0, acc[1][0], 0, 0, 0);
            acc[1][1] = __builtin_amdgcn_mfma_f32_16x16x32_bf16(a[1], bb1, acc[1][1], 0, 0, 0);
        }
        unsigned short* pb = pbounce + w * 1024;
        #pragma unroll
        for (int mt = 0; mt < 2; mt++)
            #pragma unroll
            for (int nt = 0; nt < 2; nt++) {
                int lane8 = (mt * 2 + (q >> 1)) * 16 + l15;
                #pragma unroll
                for (int r = 0; r < 4; r++)
                    pb[(nt * 64 + lane8) * 8 + (q & 1) * 4 + r] = f2bf(acc[mt][nt][r]);
            }
        uint4 f0 = *(uint4*)(pb + (0 * 64 + lane) * 8);
        uint4 f1 = *(uint4*)(pb + (1 * 64 + lane) * 8);
        int h2b0 = h2grp * 2;
        *(uint4*)(WWp + ((size_t)(h2b0 + 0) * 32 + hpb) * 512 + lane * 8) = f0;
        *(uint4*)(WWp + ((size_t)(h2b0 + 1) * 32 + hpb) * 512 + lane * 8) = f1;
        return;
    }

    {
        // ---------------- yw1: yW1[b][h2] = sum_d bf16(y) . W1bf ----------
        float* yW1 = ws + OFF_YW1;
        const int h2grp = bid - 353;   // 0..31
        const int h2c0  = h2grp * 32;

        for (int i = 0; i < 64; i++) {
            int f = i * 256 + t;
            int row = f >> 5, col = f & 31;
            lw1t[col * 520 + row] = f2bf(W1[(size_t)row * HH + h2c0 + col]);
        }
        __syncthreads();

        f32x4 acc[2][2] = {};
        #pragma unroll 4
        for (int ds = 0; ds < 16; ds++) {
            bf16x8 a[2];
            #pragma unroll
            for (int mt = 0; mt < 2; mt++) {
                const float* yr = y_init + (size_t)(w * 32 + mt * 16 + l15) * DD + ds * 32 + q * 8;
                float4 va = *(const float4*)yr;
                float4 vb = *(const float4*)(yr + 4);
                unsigned short tmp[8] = { f2bf(va.x), f2bf(va.y), f2bf(va.z), f2bf(va.w),
                                          f2bf(vb.x), f2bf(vb.y), f2bf(vb.z), f2bf(vb.w) };
                a[mt] = *(bf16x8*)tmp;
            }
            bf16x8 bb0 = *(const bf16x8*)(lw1t + l15 * 520 + ds * 32 + q * 8);
            bf16x8 bb1 = *(const bf16x8*)(lw1t + (16 + l15) * 520 + ds * 32 + q * 8);
            acc[0][0] = __builtin_amdgcn_mfma_f32_16x16x32_bf16(a[0], bb0, acc[0][0], 0, 0, 0);
            acc[0][1] = __builtin_amdgcn_mfma_f32_16x16x32_bf16(a[0], bb1, acc[0][1], 0, 0, 0);
            acc[1][0] = __builtin_amdgcn_mfma_f32_16x16x32_bf16(a[1], bb0, acc[1][0], 0, 0, 0);
            acc[1][1] = __builtin_amdgcn_mfma_f32_16x16x32_bf16(a[1], bb1, acc[1][1], 0, 0, 0);
        }
        #pragma unroll
        for (int mt = 0; mt < 2; mt++)
            #pragma unroll
            for (int nt = 0; nt < 2; nt++)
                #pragma unroll
                for (int r = 0; r < 4; r++) {
                    int b  = w * 32 + mt * 16 + q * 4 + r;
                    int h2 = h2c0 + nt * 16 + l15;
                    yW1[(size_t)b * HH + h2] = acc[mt][nt][r];
                }
    }
}

// ---------------------------------------------------------------------------
// K1_0 (first iteration only). Grid 1024 1-D, XCD-swizzled (b = bid&127).
// ---------------------------------------------------------------------------
__global__ __launch_bounds__(256) void k1_kernel(
        const float* __restrict__ B_init,        // [B][512 d][32 n] fp32
        const unsigned short* __restrict__ W1p,  // frag-packed
        const float* __restrict__ b1,            // [1024]
        const float* __restrict__ ws,
        unsigned short* __restrict__ Ptp)        // [B][32 hs][2 mt][64][8] bf16
{
    __shared__ __align__(16) char smem[40960];
    unsigned short* smA  = (unsigned short*)smem;           // A [32 n][512 d] swz
    unsigned short* t_sb = (unsigned short*)smem;           // [128][72] (overlays A)
    unsigned short* g_sb = (unsigned short*)(smem + 32768); // [128][32]

    const int t    = threadIdx.x;
    const int lane = t & 63;
    const int w    = t >> 6;
    const int q    = lane >> 4;
    const int l15  = lane & 15;
    const int bid  = blockIdx.x;
    const int b    = bid & 127;        // XCD affinity: bid%8 = b%8
    const int hblk = bid >> 7;
    const int hw   = hblk * 128 + w * 32;

    // stage: B_init[b] [512 d][32 n] fp32 -> smA bf16 [n][d] swizzled
    {
        const float* Bi = B_init + (size_t)b * DD * NB;
        #pragma unroll 8
        for (int i = 0; i < 64; i++) {
            int f = i * 256 + t;       // 0..16383
            int d = f >> 5, n = f & 31;
            *(unsigned short*)(smem + (((n << 10) + (d << 1)) ^ ((n & 7) << 4)))
                = f2bf(Bi[f]);
        }
    }
    __syncthreads();

    // Phase A: G = A W1^T, M=32(n) x N=32(h/wave) x K=512
    f32x4 acc[2][2] = {};
    const unsigned short* W1b = W1p + (size_t)(hw >> 4) * 8192;
    #pragma unroll 4
    for (int d0 = 0; d0 < DD; d0 += 32) {
        int c16 = (d0 >> 3) + q;
        int ds  = d0 >> 5;
        bf16x8 a0  = *(const bf16x8*)aS(smA, l15, c16);
        bf16x8 a1  = *(const bf16x8*)aS(smA, 16 + l15, c16);
        bf16x8 bb0 = *(const bf16x8*)(W1b + ds * 512 + lane * 8);
        bf16x8 bb1 = *(const bf16x8*)(W1b + 8192 + ds * 512 + lane * 8);
        acc[0][0] = __builtin_amdgcn_mfma_f32_16x16x32_bf16(a0, bb0, acc[0][0], 0, 0, 0);
        acc[0][1] = __builtin_amdgcn_mfma_f32_16x16x32_bf16(a0, bb1, acc[0][1], 0, 0, 0);
        acc[1][0] = __builtin_amdgcn_mfma_f32_16x16x32_bf16(a1, bb0, acc[1][0], 0, 0, 0);
        acc[1][1] = __builtin_amdgcn_mfma_f32_16x16x32_bf16(a1, bb1, acc[1][1], 0, 0, 0);
    }
    #pragma unroll
    for (int mt = 0; mt < 2; mt++)
        #pragma unroll
        for (int nt = 0; nt < 2; nt++) {
            int hl = w * 32 + nt * 16 + l15;
            store4bf(&g_sb[hl * 32 + mt * 16 + q * 4],
                     acc[mt][nt][0], acc[mt][nt][1], acc[mt][nt][2], acc[mt][nt][3]);
        }
    __syncthreads();   // all smA reads complete -> t_sb may overlay

    // Z = Phi_f^T G
    f32x4 zacc[4][2] = {};
    const unsigned short* PF = (const unsigned short*)(ws + OFF_PHIF_BF);
    bf16x8 gb[2];
    #pragma unroll
    for (int nt = 0; nt < 2; nt++)
        gb[nt] = *(const bf16x8*)(&g_sb[(w * 32 + nt * 16 + l15) * 32 + q * 8]);
    #pragma unroll
    for (int mt = 0; mt < 4; mt++) {
        bf16x8 af = *(const bf16x8*)(PF + (mt * 16 + l15) * 32 + q * 8);
        zacc[mt][0] = __builtin_amdgcn_mfma_f32_16x16x32_bf16(af, gb[0], zacc[mt][0], 0, 0, 0);
        zacc[mt][1] = __builtin_amdgcn_mfma_f32_16x16x32_bf16(af, gb[1], zacc[mt][1], 0, 0, 0);
    }

    const float* TTp = ws + OFF_TTRUE;
    float b1v[2] = { b1[hw + l15], b1[hw + 16 + l15] };
    #pragma unroll
    for (int mt = 0; mt < 4; mt++) {
        float4 ttv = *(const float4*)(TTp + mt * 16 + q * 4);
        #pragma unroll
        for (int nt = 0; nt < 2; nt++) {
            int hl = w * 32 + nt * 16 + l15;
            float v0 = tanh_fast(zacc[mt][nt][0] + ttv.x * b1v[nt]);
            float v1 = tanh_fast(zacc[mt][nt][1] + ttv.y * b1v[nt]);
            float v2 = tanh_fast(zacc[mt][nt][2] + ttv.z * b1v[nt]);
            float v3 = tanh_fast(zacc[mt][nt][3] + ttv.w * b1v[nt]);
            store4bf(&t_sb[hl * 72 + mt * 16 + q * 4], v0, v1, v2, v3);
        }
    }
    __syncthreads();

    // P = Q^T T
    f32x4 pacc[2][2] = {};
    const unsigned short* QT = (const unsigned short*)(ws + OFF_QT_BF);
    #pragma unroll
    for (int ks = 0; ks < 2; ks++) {
        bf16x8 bt[2];
        #pragma unroll
        for (int nt = 0; nt < 2; nt++)
            bt[nt] = *(const bf16x8*)(&t_sb[(w * 32 + nt * 16 + l15) * 72 + ks * 32 + q * 8]);
        #pragma unroll
        for (int jt = 0; jt < 2; jt++) {
            bf16x8 aq = *(const bf16x8*)(QT + (jt * 16 + l15) * 64 + ks * 32 + q * 8);
            pacc[jt][0] = __builtin_amdgcn_mfma_f32_16x16x32_bf16(aq, bt[0], pacc[jt][0], 0, 0, 0);
            pacc[jt][1] = __builtin_amdgcn_mfma_f32_16x16x32_bf16(aq, bt[1], pacc[jt][1], 0, 0, 0);
        }
    }

    // pack P -> Ptp via wave-private bounce (g_sb region dead after Z)
    {
        unsigned short* pb = g_sb + w * 1024;
        #pragma unroll
        for (int jt = 0; jt < 2; jt++)
            #pragma unroll
            for (int nt = 0; nt < 2; nt++) {
                int grp = (nt * 2 + (l15 >> 3)) & 3;
                #pragma unroll
                for (int r = 0; r < 4; r++) {
                    int lane8 = grp * 16 + q * 4 + r;
                    pb[(jt * 64 + lane8) * 8 + (l15 & 7)] = f2bf(pacc[jt][nt][r]);
                }
            }
        int hs = hblk * 4 + w;
        uint4 f0 = *(uint4*)(pb + (0 * 64 + lane) * 8);
        uint4 f1 = *(uint4*)(pb + (1 * 64 + lane) * 8);
        *(uint4*)(Ptp + (((size_t)(b * 32 + hs) * 2 + 0) * 64 + lane) * 8) = f0;
        *(uint4*)(Ptp + (((size_t)(b * 32 + hs) * 2 + 1) * 64 + lane) * 8) = f1;
    }
}

// ---------------------------------------------------------------------------
// KF (iterations 1..9): G' = P.WW + u (x) yW1, then Z/tanh/P.
// RESTRUCTURED: grid 512 (b = bid&127, hblk2 = bid>>7), N=64 h2 per wave;
// Ptin[b] staged once per block in double-buffered 16KB LDS chunks and
// SHARED by all 4 waves (was: each wave re-streamed the full 64KB from L2
// -> ~2MB L2 traffic per CU, the kf bottleneck). Phase-B LDS overlays the
// dead A-buffers: total 69632B -> 2 blocks/CU (= grid/256 exactly).
// Per-output K-order (s ascending) and all f2bf identical -> bitwise-same.
// ---------------------------------------------------------------------------
__global__ __launch_bounds__(256) void kf_kernel(
        const unsigned short* __restrict__ Ptin,  // [B][32 hs][2 mt][64][8]
        const unsigned short* __restrict__ WWp,   // [64 h2b][32 hs][64][8]
        const float* __restrict__ yW1,            // [B][1024] fp32
        const float* __restrict__ b1,
        const float* __restrict__ ws,
        unsigned short* __restrict__ Ptout)
{
    __shared__ __align__(16) char smem[69632];
    // main loop: A0 = [0,16384), A1 = [16384,32768)
    // phase B overlay: g_w = smem + w*4096          (64 rows x 32 n bf16)
    //                  t_w = smem + 16384 + w*9216  (64 rows x 72 bf16)
    //                  pb_w= smem + 53248 + w*4096  (4 frags x 512 bf16)

    const int t    = threadIdx.x;
    const int lane = t & 63;
    const int w    = t >> 6;
    const int q    = lane >> 4;
    const int l15  = lane & 15;
    const int bid  = blockIdx.x;
    const int b    = bid & 127;        // XCD affinity: bid%8 = b%8
    const int hblk2 = bid >> 7;        // 0..3
    const int hw   = hblk2 * 256 + w * 64;

    f32x4 acc[2][4] = {};
    const unsigned short* Ab  = Ptin + (size_t)b * 32768;
    const unsigned short* WWb = WWp + (size_t)(hblk2 * 16 + w * 4) * 16384;
    unsigned short* buf0 = (unsigned short*)smem;
    unsigned short* buf1 = (unsigned short*)(smem + 16384);

    {   // stage chunk 0 (16KB = 1024 uint4; 4 per thread, coalesced)
        const uint4* src = (const uint4*)Ab;
        uint4* dst = (uint4*)buf0;
        #pragma unroll
        for (int i = 0; i < 4; i++) dst[i * 256 + t] = src[i * 256 + t];
    }
    __syncthreads();

    #pragma unroll 1
    for (int c = 0; c < 4; ++c) {
        if (c < 3) {   // prefetch next chunk into the other buffer
            const uint4* src = (const uint4*)(Ab + (c + 1) * 8192);
            uint4* dst = (uint4*)((c & 1) ? buf0 : buf1);
            #pragma unroll
            for (int i = 0; i < 4; i++) dst[i * 256 + t] = src[i * 256 + t];
        }
        const unsigned short* Ac = (c & 1) ? buf1 : buf0;
        #pragma unroll
        for (int sl = 0; sl < 8; ++sl) {
            int s = c * 8 + sl;
            bf16x8 a0 = *(const bf16x8*)(Ac + (sl * 2 + 0) * 512 + lane * 8);
            bf16x8 a1 = *(const bf16x8*)(Ac + (sl * 2 + 1) * 512 + lane * 8);
            #pragma unroll
            for (int nt = 0; nt < 4; nt++) {
                bf16x8 bb = *(const bf16x8*)(WWb + nt * 16384 + s * 512 + lane * 8);
                acc[0][nt] = __builtin_amdgcn_mfma_f32_16x16x32_bf16(a0, bb, acc[0][nt], 0, 0, 0);
                acc[1][nt] = __builtin_amdgcn_mfma_f32_16x16x32_bf16(a1, bb, acc[1][nt], 0, 0, 0);
            }
        }
        __syncthreads();   // prefetch complete + A reads done before overwrite
    }

    unsigned short* g_w  = (unsigned short*)(smem + w * 4096);
    unsigned short* t_w  = (unsigned short*)(smem + 16384 + w * 9216);
    unsigned short* pb_w = (unsigned short*)(smem + 53248 + w * 4096);

    // bias u[j]*yW1[b][h2], write g_w[h2_loc][j]  (wave-private; A dead)
    const float* U = ws + OFF_U;
    float yw[4];
    #pragma unroll
    for (int nt = 0; nt < 4; nt++)
        yw[nt] = yW1[(size_t)b * HH + hw + nt * 16 + l15];
    #pragma unroll
    for (int mt = 0; mt < 2; mt++) {
        float4 uv = *(const float4*)(U + mt * 16 + q * 4);
        #pragma unroll
        for (int nt = 0; nt < 4; nt++) {
            int hl = nt * 16 + l15;
            store4bf(&g_w[hl * 32 + mt * 16 + q * 4],
                     acc[mt][nt][0] + uv.x * yw[nt],
                     acc[mt][nt][1] + uv.y * yw[nt],
                     acc[mt][nt][2] + uv.z * yw[nt],
                     acc[mt][nt][3] + uv.w * yw[nt]);
        }
    }

    // Z = Phi_f^T G' : M=64(m) x N=64(h2/wave) x K=32(j)
    f32x4 zacc[4][4] = {};
    const unsigned short* PF = (const unsigned short*)(ws + OFF_PHIF_BF);
    bf16x8 gb[4];
    #pragma unroll
    for (int nt = 0; nt < 4; nt++)
        gb[nt] = *(const bf16x8*)(&g_w[(nt * 16 + l15) * 32 + q * 8]);
    #pragma unroll
    for (int mt = 0; mt < 4; mt++) {
        bf16x8 af = *(const bf16x8*)(PF + (mt * 16 + l15) * 32 + q * 8);
        #pragma unroll
        for (int nt = 0; nt < 4; nt++)
            zacc[mt][nt] = __builtin_amdgcn_mfma_f32_16x16x32_bf16(af, gb[nt], zacc[mt][nt], 0, 0, 0);
    }

    const float* TTp = ws + OFF_TTRUE;
    float b1v[4];
    #pragma unroll
    for (int nt = 0; nt < 4; nt++)
        b1v[nt] = b1[hw + nt * 16 + l15];
    #pragma unroll
    for (int mt = 0; mt < 4; mt++) {
        float4 ttv = *(const float4*)(TTp + mt * 16 + q * 4);
        #pragma unroll
        for (int nt = 0; nt < 4; nt++) {
            int hl = nt * 16 + l15;
            float v0 = tanh_fast(zacc[mt][nt][0] + ttv.x * b1v[nt]);
            float v1 = tanh_fast(zacc[mt][nt][1] + ttv.y * b1v[nt]);
            float v2 = tanh_fast(zacc[mt][nt][2] + ttv.z * b1v[nt]);
            float v3 = tanh_fast(zacc[mt][nt][3] + ttv.w * b1v[nt]);
            store4bf(&t_w[hl * 72 + mt * 16 + q * 4], v0, v1, v2, v3);
        }
    }

    // P = Q^T T : M=32(j) x N=64(h2/wave) x K=64(m)
    f32x4 pacc[2][4] = {};
    const unsigned short* QT = (const unsigned short*)(ws + OFF_QT_BF);
    #pragma unroll
    for (int ks = 0; ks < 2; ks++) {
        bf16x8 bt[4];
        #pragma unroll
        for (int nt = 0; nt < 4; nt++)
            bt[nt] = *(const bf16x8*)(&t_w[(nt * 16 + l15) * 72 + ks * 32 + q * 8]);
        #pragma unroll
        for (int jt = 0; jt < 2; jt++) {
            bf16x8 aq = *(const bf16x8*)(QT + (jt * 16 + l15) * 64 + ks * 32 + q * 8);
            #pragma unroll
            for (int nt = 0; nt < 4; nt++)
                pacc[jt][nt] = __builtin_amdgcn_mfma_f32_16x16x32_bf16(aq, bt[nt], pacc[jt][nt], 0, 0, 0);
        }
    }

    // pack P -> Ptout (wave-private bounce; 4 fragments = 2 hs x 2 jt)
    {
        #pragma unroll
        for (int jt = 0; jt < 2; jt++)
            #pragma unroll
            for (int nt = 0; nt < 4; nt++) {
                int grp    = ((nt & 1) * 2 + (l15 >> 3)) & 3;
                int hs_loc = nt >> 1;
                #pragma unroll
                for (int r = 0; r < 4; r++) {
                    int lane8 = grp * 16 + q * 4 + r;
                    pb_w[(hs_loc * 2 + jt) * 512 + lane8 * 8 + (l15 & 7)] = f2bf(pacc[jt][nt][r]);
                }
            }
        int hs0 = hblk2 * 8 + w * 2;
        #pragma unroll
        for (int i = 0; i < 4; i++) {   // i = hs_loc*2 + jt
            uint4 fv = *(uint4*)(pb_w + i * 512 + lane * 8);
            int hs = hs0 + (i >> 1), jt = i & 1;
            *(uint4*)(Ptout + (((size_t)(b * 32 + hs) * 2 + jt) * 64 + lane) * 8) = fv;
        }
    }
}

// ---------------------------------------------------------------------------
// K2F (final): Bn_val = P.W2 + y u (fp32); writes out1 directly and
// out0 = sum_n Bn_val*Phi_out. Grid 1024 1-D, XCD-swizzled (b = bid&127).
// ---------------------------------------------------------------------------
__global__ __launch_bounds__(256) void k2f_kernel(
        const unsigned short* __restrict__ Ptp,  // [B][32 hs][2 mt][64][8] bf16
        const unsigned short* __restrict__ W2p,  // frag-packed
        const float* __restrict__ y_init,        // [B][512]
        const float* __restrict__ ws,
        float* __restrict__ out)
{
    __shared__ __align__(16) float ls[4 * 544];
    __shared__ float phiout_s[NB * TT];

    const int t    = threadIdx.x;
    const int lane = t & 63;
    const int w    = t >> 6;
    const int q    = lane >> 4;
    const int l15  = lane & 15;
    const int bid  = blockIdx.x;
    const int b    = bid & 127;        // XCD affinity
    const int dblk = bid >> 7;         // 0..7
    const int dw   = dblk * 64 + w * 16;

    for (int f = t; f < NB * TT; f += 256) phiout_s[f] = ws[OFF_PHIOUT + f];

    f32x4 acc[2] = {};
    const unsigned short* Ab  = Ptp + (size_t)b * 32768;
    const unsigned short* W2b = W2p + (size_t)(dblk * 4 + w) * 16384;
    #pragma unroll 4
    for (int s = 0; s < 32; s++) {
        bf16x8 a0 = *(const bf16x8*)(Ab + (s * 2 + 0) * 512 + lane * 8);
        bf16x8 a1 = *(const bf16x8*)(Ab + (s * 2 + 1) * 512 + lane * 8);
        bf16x8 bb = *(const bf16x8*)(W2b + s * 512 + lane * 8);
        acc[0] = __builtin_amdgcn_mfma_f32_16x16x32_bf16(a0, bb, acc[0], 0, 0, 0);
        acc[1] = __builtin_amdgcn_mfma_f32_16x16x32_bf16(a1, bb, acc[1], 0, 0, 0);
    }

    const float* U = ws + OFF_U;
    float yv = y_init[(size_t)b * DD + dw + l15];
    #pragma unroll
    for (int mt = 0; mt < 2; mt++) {
        float4 uv = *(const float4*)(U + mt * 16 + q * 4);
        #pragma unroll
        for (int r = 0; r < 4; r++) {
            int j = mt * 16 + q * 4 + r;
            float uvr = (r == 0) ? uv.x : (r == 1) ? uv.y : (r == 2) ? uv.z : uv.w;
            ls[w * 544 + j * 17 + l15] = acc[mt][r] + yv * uvr;
        }
    }
    __syncthreads();

    // out1 = Bn copy (coalesced)
    float* out1 = out + (size_t)TT * BB * DD;
    #pragma unroll
    for (int it = 0; it < 8; it++) {
        int f = it * 64 + lane;
        int d_l = f >> 5, j2 = f & 31;
        out1[((size_t)b * DD + dw + d_l) * NB + j2] = ls[w * 544 + j2 * 17 + d_l];
    }

    // out0[t16, b, d] = sum_n val[d][n] * phiout[n][t16]   (64 d x 16 t per block)
    #pragma unroll
    for (int i = 0; i < 4; i++) {
        int idx = i * 256 + t;
        int t16 = idx >> 6, dl = idx & 63;
        float s = 0.f;
        #pragma unroll
        for (int n = 0; n < NB; n++)
            s += ls[(dl >> 4) * 544 + n * 17 + (dl & 15)] * phiout_s[n * TT + t16];
        out[(size_t)t16 * (BB * DD) + (size_t)b * DD + dblk * 64 + dl] = s;
    }
}

// ---------------------------------------------------------------------------
extern "C" void kernel_launch(void* const* d_in, const int* in_sizes, int n_in,
                              void* d_out, int out_size, void* d_ws, size_t ws_size,
                              hipStream_t stream) {
    const float* t_span = (const float*)d_in[0];
    const float* y_init = (const float*)d_in[1];
    const float* B_init = (const float*)d_in[2];
    const float* W1     = (const float*)d_in[3];
    const float* b1     = (const float*)d_in[4];
    const float* W2     = (const float*)d_in[5];
    float* ws  = (float*)d_ws;
    float* out = (float*)d_out;

    unsigned short* W1p  = (unsigned short*)(ws + OFF_W1P);
    unsigned short* W2p  = (unsigned short*)(ws + OFF_W2P);
    unsigned short* WWp  = (unsigned short*)(ws + OFF_WWP);
    float*          yW1  = ws + OFF_YW1;
    unsigned short* PtpA = (unsigned short*)(ws + OFF_PTPA);
    unsigned short* PtpB = (unsigned short*)(ws + OFF_PTP0);

    // ONE prologue dispatch: setup + pack_w1 + pack_w2 + pack_ww + yw1
    prologue_kernel<<<dim3(385), 256, 0, stream>>>(t_span, W1, W2, y_init, ws);

    k1_kernel<<<dim3(1024), 256, 0, stream>>>(B_init, W1p, b1, ws, PtpA);

    unsigned short* pin  = PtpA;
    unsigned short* pout = PtpB;
    for (int it = 1; it < ITERS; it++) {
        kf_kernel<<<dim3(512), 256, 0, stream>>>(pin, WWp, yW1, b1, ws, pout);
        unsigned short* tmp = pin; pin = pout; pout = tmp;
    }
    // 9 kf's -> final P in pin
    k2f_kernel<<<dim3(1024), 256, 0, stream>>>(pin, W2p, y_init, ws, out);
}

// Round 15
// 338.440 us; speedup vs baseline: 11.7664x; 1.0686x over previous
//
#include <hip/hip_runtime.h>
#include <hip/hip_bf16.h>
#include <math.h>

// Problem constants (fixed by setup_inputs)
#define BB 128
#define DD 512
#define HH 1024
#define NB 32     // num_coeff_per_dim
#define MM 63     // 2N-1 simpson points
#define TT 16
#define ITERS 10

// ws layout (float units)
#define OFF_U       0        // 32 fp32
#define OFF_TTRUE   64       // 64 fp32 (tt[63]=0)
#define OFF_PHIOUT  128      // 512 fp32
#define OFF_PHIF_BF 1024     // bf16 [64 m][32 n]  (row 63 = 0)   = 1024 floats
#define OFF_QT_BF   2048     // bf16 [32 j][64 m]  (col 63 = 0)   = 1024 floats
#define HDRF        4096
#define OFF_PTPA    HDRF                     // bf16 frag-packed [B][32 hs][2 mt][64][8] = 2097152 f
#define OFF_PTP0    (OFF_PTPA + 2097152)     // bf16 frag-packed ping-pong buffer       = 2097152 f
#define OFF_W1P     (OFF_PTP0 + 2097152)     // bf16 frag-packed [64 hb][16 ds][64][8] = 262144 f
#define OFF_W2P     (OFF_W1P + 262144)       // bf16 frag-packed [32 db][32 hs][64][8] = 262144 f
#define OFF_WWP     (OFF_W2P + 262144)       // bf16 frag-packed [64 h2b][32 hs][64][8] = 524288 f
#define OFF_YW1     (OFF_WWP + 524288)       // fp32 [128 b][1024 h2] = 131072 f
// end = 5378048 floats = 21.5 MB

typedef __attribute__((ext_vector_type(8))) short bf16x8;
typedef __attribute__((ext_vector_type(4))) float f32x4;

static __device__ __forceinline__ unsigned short f2bf(float f) {
    unsigned int x = __builtin_bit_cast(unsigned int, f);
    unsigned int r = x + 0x7FFFu + ((x >> 16) & 1u);   // RNE
    return (unsigned short)(r >> 16);
}

static __device__ __forceinline__ void store4bf(unsigned short* p,
                                                float v0, float v1, float v2, float v3) {
    unsigned int lo = (unsigned int)f2bf(v0) | ((unsigned int)f2bf(v1) << 16);
    unsigned int hi = (unsigned int)f2bf(v2) | ((unsigned int)f2bf(v3) << 16);
    uint2 u; u.x = lo; u.y = hi;
    *(uint2*)p = u;   // 8B-aligned by construction
}

static __device__ __forceinline__ float tanh_fast(float x) {
    float e = exp2f(x * 2.88539008177793f);   // 2*log2(e)
    return 1.0f - 2.0f / (e + 1.0f);
}

// XOR-swizzled LDS A-tile addressing: tile [32 r][512 c] bf16, linear 32KB,
// byte = (r*1024 + c*2) ^ ((r&7)<<4). Bijective per row, 16B-aligned b128.
static __device__ __forceinline__ unsigned short* aS(unsigned short* smA, int r, int c16) {
    return (unsigned short*)((char*)smA + (((r << 10) + (c16 << 4)) ^ ((r & 7) << 4)));
}

// ---------------------------------------------------------------------------
// PROLOGUE (single dispatch, blocks partitioned by role):
//   bid 0        : setup -- GJ REPLACED by closed-form DCT-I inverse:
//                  Phi_inv[i][j] = 2*(-1)^j*cos(i*j*pi/31)/(31*c_i*c_j),
//                  c_0=c_31=2 else 1 (Chebyshev-Gauss-Lobatto orthogonality;
//                  kills the 32-step fp64 pivot loop that was the 44us tail).
//   bid 1..64    : pack_w1   (hb = bid-1)
//   bid 65..96   : pack_w2   (db = bid-65)
//   bid 97..352  : pack_ww   (idx: h2grp = idx&31, hpb = (idx>>5)*4+w)
//   bid 353..384 : yw1       (h2grp = bid-353, waves = b-tiles)
// ---------------------------------------------------------------------------
__global__ __launch_bounds__(256) void prologue_kernel(
        const float* __restrict__ t_span, const float* __restrict__ W1,
        const float* __restrict__ W2, const float* __restrict__ y_init,
        float* __restrict__ ws) {
    __shared__ __align__(16) char smem[66560];
    const int bid  = blockIdx.x;
    const int t    = threadIdx.x;
    const int lane = t & 63;
    const int w    = t >> 6;
    const int q    = lane >> 4;
    const int l15  = lane & 15;

    if (bid == 0) {
        // ---------------- setup ----------------
        double* tsim    = (double*)(smem + 0);       // 63
        double* ttrue_d = (double*)(smem + 512);     // 63
        double* wid     = (double*)(smem + 1024);    // 31
        double* phid    = (double*)(smem + 1280);    // 32*63
        double* pinv    = (double*)(smem + 17408);   // 32*32 closed-form Phi_inv
        double* Rl      = (double*)(smem + 34048);   // 63*32
        double* Qd      = (double*)(smem + 50176);   // 63*32

        const double PI = 3.14159265358979323846;
        const double t0 = (double)t_span[0];
        const double t1 = (double)t_span[TT - 1];

        if (t < MM) {
            double v;
            if ((t & 1) == 0) {
                int j = t >> 1;
                v = -cos(PI * (double)j / (double)(NB - 1));
            } else {
                int i = t >> 1;
                double a = -cos(PI * (double)i / (double)(NB - 1));
                double b = -cos(PI * (double)(i + 1) / (double)(NB - 1));
                v = 0.5 * (a + b);
            }
            tsim[t] = v;
            ttrue_d[t] = t0 + 0.5 * (t1 - t0) * (v + 1.0);
        }
        __syncthreads();
        if (t < 31) wid[t] = (ttrue_d[2 * t + 2] - ttrue_d[2 * t]) / 6.0;
        if (t < MM) ws[OFF_TTRUE + t] = (float)ttrue_d[t];
        if (t == 63) ws[OFF_TTRUE + 63] = 0.0f;

        if (t < MM) {
            double x = tsim[t];
            double r0 = 1.0, r1 = x;
            phid[0 * MM + t] = r0;
            phid[1 * MM + t] = r1;
            for (int n = 2; n < NB; n++) {
                double r2 = 2.0 * x * r1 - r0;
                phid[n * MM + t] = r2;
                r0 = r1; r1 = r2;
            }
        }

        // closed-form Phi_inv (no barrier needed before: independent of phid)
        for (int f = t; f < NB * NB; f += 256) {
            int i = f >> 5, j = f & 31;
            double ci = (i == 0 || i == NB - 1) ? 2.0 : 1.0;
            double cj = (j == 0 || j == NB - 1) ? 2.0 : 1.0;
            double v = 2.0 * cos(PI * (double)(i * j) / (double)(NB - 1))
                       / ((double)(NB - 1) * ci * cj);
            pinv[f] = (j & 1) ? -v : v;
        }
        __syncthreads();

        {   // phif_bf [m 64][n 32], row 63 = 0
            unsigned short* pf = (unsigned short*)(ws + OFF_PHIF_BF);
            for (int f = t; f < 64 * 32; f += 256) {
                int m = f >> 5, n = f & 31;
                pf[f] = f2bf(m < MM ? (float)phid[n * MM + m] : 0.0f);
            }
        }

        if (t < MM) {
            double acc = 0.0;
            Rl[t * NB + 0] = 0.0;
            for (int i = 1; i < NB; i++) {
                int ip = i - 1;
                double wv = 0.0;
                if (t == 2 * ip)     wv += wid[ip];
                if (t == 2 * ip + 1) wv += 4.0 * wid[ip];
                if (t == 2 * ip + 2) wv += wid[ip];
                acc += wv;
                Rl[t * NB + i] = acc;
            }
        }
        __syncthreads();

        for (int f = t; f < MM * NB; f += 256) {
            int m = f >> 5, j = f & 31;
            double s = 0.0;
            for (int i = 0; i < NB; i++) s += Rl[m * NB + i] * pinv[i * 32 + j];
            Qd[f] = s;
        }
        __syncthreads();

        {   // qt_bf [j 32][m 64], col 63 = 0
            unsigned short* qt = (unsigned short*)(ws + OFF_QT_BF);
            for (int f = t; f < 32 * 64; f += 256) {
                int j = f >> 6, m = f & 63;
                qt[f] = f2bf(m < MM ? (float)Qd[m * NB + j] : 0.0f);
            }
        }
        if (t < NB) {
            double s = 0.0;
            for (int i = 0; i < NB; i++) s += pinv[i * 32 + t];
            ws[OFF_U + t] = (float)s;
        }
        if (t < TT) {
            double x = -1.0 + 2.0 * ((double)t_span[t] - t0) / (t1 - t0);
            double r0 = 1.0, r1 = x;
            ws[OFF_PHIOUT + 0 * TT + t] = 1.0f;
            ws[OFF_PHIOUT + 1 * TT + t] = (float)x;
            for (int n = 2; n < NB; n++) {
                double r2 = 2.0 * x * r1 - r0;
                ws[OFF_PHIOUT + n * TT + t] = (float)r2;
                r0 = r1; r1 = r2;
            }
        }
        return;
    }

    if (bid <= 64) {
        // ---------------- pack_w1: hb = bid-1 ----------------
        unsigned short* W1p = (unsigned short*)(ws + OFF_W1P);
        const int hb = bid - 1;
        #pragma unroll
        for (int i = 0; i < 4; i++) {
            int f = i * 256 + t;
            int ds = f >> 6, ln = f & 63;
            int qq = ln >> 4, ll = ln & 15;
            unsigned short tmp[8];
            #pragma unroll
            for (int e = 0; e < 8; e++)
                tmp[e] = f2bf(W1[(size_t)(ds * 32 + qq * 8 + e) * HH + hb * 16 + ll]);
            *(uint4*)(W1p + ((size_t)(hb * 16 + ds) * 64 + ln) * 8) = *(uint4*)tmp;
        }
        return;
    }

    if (bid <= 96) {
        // ---------------- pack_w2: db = bid-65 ----------------
        unsigned short* W2p = (unsigned short*)(ws + OFF_W2P);
        const int db = bid - 65;
        #pragma unroll
        for (int i = 0; i < 8; i++) {
            int f = i * 256 + t;
            int hs = f >> 6, ln = f & 63;
            int qq = ln >> 4, ll = ln & 15;
            unsigned short tmp[8];
            #pragma unroll
            for (int e = 0; e < 8; e++)
                tmp[e] = f2bf(W2[(size_t)(hs * 32 + qq * 8 + e) * DD + db * 16 + ll]);
            *(uint4*)(W2p + ((size_t)(db * 32 + hs) * 64 + ln) * 8) = *(uint4*)tmp;
        }
        return;
    }

    // lw1t = bf16 TRANSPOSED W1 slice: [32 col][520 row-stride] = 33280 B.
    unsigned short* lw1t = (unsigned short*)smem;

    if (bid <= 352) {
        // ---------------- pack_ww: WW = bf16(W2bf . W1bf), frag-packed ----
        unsigned short* WWp = (unsigned short*)(ws + OFF_WWP);
        unsigned short* pbounce = (unsigned short*)(smem + 33280);   // 8 KB
        const int idx   = bid - 97;
        const int h2grp = idx & 31;           // 32-col group of h2
        const int hpb   = (idx >> 5) * 4 + w; // wave's h'-row block (0..31)
        const int h2c0  = h2grp * 32;

        // coalesced stage: W1[:, h2c0..h2c0+32) -> lw1t[col][row] bf16
        for (int i = 0; i < 64; i++) {
            int f = i * 256 + t;
            int row = f >> 5, col = f & 31;
            lw1t[col * 520 + row] = f2bf(W1[(size_t)row * HH + h2c0 + col]);
        }
        __syncthreads();

        f32x4 acc[2][2] = {};
        #pragma unroll 4
        for (int ds = 0; ds < 16; ds++) {
            bf16x8 a[2];
            #pragma unroll
            for (int mt = 0; mt < 2; mt++) {
                const float* w2r = W2 + (size_t)(hpb * 32 + mt * 16 + l15) * DD + ds * 32 + q * 8;
                float4 va = *(const float4*)w2r;
                float4 vb = *(const float4*)(w2r + 4);
                unsigned short tmp[8] = { f2bf(va.x), f2bf(va.y), f2bf(va.z), f2bf(va.w),
                                          f2bf(vb.x), f2bf(vb.y), f2bf(vb.z), f2bf(vb.w) };
                a[mt] = *(bf16x8*)tmp;
            }
            bf16x8 bb0 = *(const bf16x8*)(lw1t + l15 * 520 + ds * 32 + q * 8);
            bf16x8 bb1 = *(const bf16x8*)(lw1t + (16 + l15) * 520 + ds * 32 + q * 8);
            acc[0][0] = __builtin_amdgcn_mfma_f32_16x16x32_bf16(a[0], bb0, acc[0][0], 0, 0, 0);
            acc[0][1] = __builtin_amdgcn_mfma_f32_16x16x32_bf16(a[0], bb1, acc[0][1], 0, 0, 0);
            acc[1][0] = __builtin_amdgcn_mfma_f32_16x16x32_bf16(a[1], bb0, acc[1][0], 0, 0, 0);
            acc[1][1] = __builtin_amdgcn_mfma_f32_16x16x32_bf16(a[1], bb1, acc[1][1], 0, 0, 0);
        }
        unsigned short* pb = pbounce + w * 1024;
        #pragma unroll
        for (int mt = 0; mt < 2; mt++)
            #pragma unroll
            for (int nt = 0; nt < 2; nt++) {
                int lane8 = (mt * 2 + (q >> 1)) * 16 + l15;
                #pragma unroll
                for (int r = 0; r < 4; r++)
                    pb[(nt * 64 + lane8) * 8 + (q & 1) * 4 + r] = f2bf(acc[mt][nt][r]);
            }
        uint4 f0 = *(uint4*)(pb + (0 * 64 + lane) * 8);
        uint4 f1 = *(uint4*)(pb + (1 * 64 + lane) * 8);
        int h2b0 = h2grp * 2;
        *(uint4*)(WWp + ((size_t)(h2b0 + 0) * 32 + hpb) * 512 + lane * 8) = f0;
        *(uint4*)(WWp + ((size_t)(h2b0 + 1) * 32 + hpb) * 512 + lane * 8) = f1;
        return;
    }

    {
        // ---------------- yw1: yW1[b][h2] = sum_d bf16(y) . W1bf ----------
        float* yW1 = ws + OFF_YW1;
        const int h2grp = bid - 353;   // 0..31
        const int h2c0  = h2grp * 32;

        for (int i = 0; i < 64; i++) {
            int f = i * 256 + t;
            int row = f >> 5, col = f & 31;
            lw1t[col * 520 + row] = f2bf(W1[(size_t)row * HH + h2c0 + col]);
        }
        __syncthreads();

        f32x4 acc[2][2] = {};
        #pragma unroll 4
        for (int ds = 0; ds < 16; ds++) {
            bf16x8 a[2];
            #pragma unroll
            for (int mt = 0; mt < 2; mt++) {
                const float* yr = y_init + (size_t)(w * 32 + mt * 16 + l15) * DD + ds * 32 + q * 8;
                float4 va = *(const float4*)yr;
                float4 vb = *(const float4*)(yr + 4);
                unsigned short tmp[8] = { f2bf(va.x), f2bf(va.y), f2bf(va.z), f2bf(va.w),
                                          f2bf(vb.x), f2bf(vb.y), f2bf(vb.z), f2bf(vb.w) };
                a[mt] = *(bf16x8*)tmp;
            }
            bf16x8 bb0 = *(const bf16x8*)(lw1t + l15 * 520 + ds * 32 + q * 8);
            bf16x8 bb1 = *(const bf16x8*)(lw1t + (16 + l15) * 520 + ds * 32 + q * 8);
            acc[0][0] = __builtin_amdgcn_mfma_f32_16x16x32_bf16(a[0], bb0, acc[0][0], 0, 0, 0);
            acc[0][1] = __builtin_amdgcn_mfma_f32_16x16x32_bf16(a[0], bb1, acc[0][1], 0, 0, 0);
            acc[1][0] = __builtin_amdgcn_mfma_f32_16x16x32_bf16(a[1], bb0, acc[1][0], 0, 0, 0);
            acc[1][1] = __builtin_amdgcn_mfma_f32_16x16x32_bf16(a[1], bb1, acc[1][1], 0, 0, 0);
        }
        #pragma unroll
        for (int mt = 0; mt < 2; mt++)
            #pragma unroll
            for (int nt = 0; nt < 2; nt++)
                #pragma unroll
                for (int r = 0; r < 4; r++) {
                    int b  = w * 32 + mt * 16 + q * 4 + r;
                    int h2 = h2c0 + nt * 16 + l15;
                    yW1[(size_t)b * HH + h2] = acc[mt][nt][r];
                }
    }
}

// ---------------------------------------------------------------------------
// K1_0 (first iteration only). Grid 1024 1-D, XCD-swizzled (b = bid&127).
// ---------------------------------------------------------------------------
__global__ __launch_bounds__(256) void k1_kernel(
        const float* __restrict__ B_init,        // [B][512 d][32 n] fp32
        const unsigned short* __restrict__ W1p,  // frag-packed
        const float* __restrict__ b1,            // [1024]
        const float* __restrict__ ws,
        unsigned short* __restrict__ Ptp)        // [B][32 hs][2 mt][64][8] bf16
{
    __shared__ __align__(16) char smem[40960];
    unsigned short* smA  = (unsigned short*)smem;           // A [32 n][512 d] swz
    unsigned short* t_sb = (unsigned short*)smem;           // [128][72] (overlays A)
    unsigned short* g_sb = (unsigned short*)(smem + 32768); // [128][32]

    const int t    = threadIdx.x;
    const int lane = t & 63;
    const int w    = t >> 6;
    const int q    = lane >> 4;
    const int l15  = lane & 15;
    const int bid  = blockIdx.x;
    const int b    = bid & 127;        // XCD affinity: bid%8 = b%8
    const int hblk = bid >> 7;
    const int hw   = hblk * 128 + w * 32;

    // stage: B_init[b] [512 d][32 n] fp32 -> smA bf16 [n][d] swizzled
    {
        const float* Bi = B_init + (size_t)b * DD * NB;
        #pragma unroll 8
        for (int i = 0; i < 64; i++) {
            int f = i * 256 + t;       // 0..16383
            int d = f >> 5, n = f & 31;
            *(unsigned short*)(smem + (((n << 10) + (d << 1)) ^ ((n & 7) << 4)))
                = f2bf(Bi[f]);
        }
    }
    __syncthreads();

    // Phase A: G = A W1^T, M=32(n) x N=32(h/wave) x K=512
    f32x4 acc[2][2] = {};
    const unsigned short* W1b = W1p + (size_t)(hw >> 4) * 8192;
    #pragma unroll 4
    for (int d0 = 0; d0 < DD; d0 += 32) {
        int c16 = (d0 >> 3) + q;
        int ds  = d0 >> 5;
        bf16x8 a0  = *(const bf16x8*)aS(smA, l15, c16);
        bf16x8 a1  = *(const bf16x8*)aS(smA, 16 + l15, c16);
        bf16x8 bb0 = *(const bf16x8*)(W1b + ds * 512 + lane * 8);
        bf16x8 bb1 = *(const bf16x8*)(W1b + 8192 + ds * 512 + lane * 8);
        acc[0][0] = __builtin_amdgcn_mfma_f32_16x16x32_bf16(a0, bb0, acc[0][0], 0, 0, 0);
        acc[0][1] = __builtin_amdgcn_mfma_f32_16x16x32_bf16(a0, bb1, acc[0][1], 0, 0, 0);
        acc[1][0] = __builtin_amdgcn_mfma_f32_16x16x32_bf16(a1, bb0, acc[1][0], 0, 0, 0);
        acc[1][1] = __builtin_amdgcn_mfma_f32_16x16x32_bf16(a1, bb1, acc[1][1], 0, 0, 0);
    }
    #pragma unroll
    for (int mt = 0; mt < 2; mt++)
        #pragma unroll
        for (int nt = 0; nt < 2; nt++) {
            int hl = w * 32 + nt * 16 + l15;
            store4bf(&g_sb[hl * 32 + mt * 16 + q * 4],
                     acc[mt][nt][0], acc[mt][nt][1], acc[mt][nt][2], acc[mt][nt][3]);
        }
    __syncthreads();   // all smA reads complete -> t_sb may overlay

    // Z = Phi_f^T G
    f32x4 zacc[4][2] = {};
    const unsigned short* PF = (const unsigned short*)(ws + OFF_PHIF_BF);
    bf16x8 gb[2];
    #pragma unroll
    for (int nt = 0; nt < 2; nt++)
        gb[nt] = *(const bf16x8*)(&g_sb[(w * 32 + nt * 16 + l15) * 32 + q * 8]);
    #pragma unroll
    for (int mt = 0; mt < 4; mt++) {
        bf16x8 af = *(const bf16x8*)(PF + (mt * 16 + l15) * 32 + q * 8);
        zacc[mt][0] = __builtin_amdgcn_mfma_f32_16x16x32_bf16(af, gb[0], zacc[mt][0], 0, 0, 0);
        zacc[mt][1] = __builtin_amdgcn_mfma_f32_16x16x32_bf16(af, gb[1], zacc[mt][1], 0, 0, 0);
    }

    const float* TTp = ws + OFF_TTRUE;
    float b1v[2] = { b1[hw + l15], b1[hw + 16 + l15] };
    #pragma unroll
    for (int mt = 0; mt < 4; mt++) {
        float4 ttv = *(const float4*)(TTp + mt * 16 + q * 4);
        #pragma unroll
        for (int nt = 0; nt < 2; nt++) {
            int hl = w * 32 + nt * 16 + l15;
            float v0 = tanh_fast(zacc[mt][nt][0] + ttv.x * b1v[nt]);
            float v1 = tanh_fast(zacc[mt][nt][1] + ttv.y * b1v[nt]);
            float v2 = tanh_fast(zacc[mt][nt][2] + ttv.z * b1v[nt]);
            float v3 = tanh_fast(zacc[mt][nt][3] + ttv.w * b1v[nt]);
            store4bf(&t_sb[hl * 72 + mt * 16 + q * 4], v0, v1, v2, v3);
        }
    }
    __syncthreads();

    // P = Q^T T
    f32x4 pacc[2][2] = {};
    const unsigned short* QT = (const unsigned short*)(ws + OFF_QT_BF);
    #pragma unroll
    for (int ks = 0; ks < 2; ks++) {
        bf16x8 bt[2];
        #pragma unroll
        for (int nt = 0; nt < 2; nt++)
            bt[nt] = *(const bf16x8*)(&t_sb[(w * 32 + nt * 16 + l15) * 72 + ks * 32 + q * 8]);
        #pragma unroll
        for (int jt = 0; jt < 2; jt++) {
            bf16x8 aq = *(const bf16x8*)(QT + (jt * 16 + l15) * 64 + ks * 32 + q * 8);
            pacc[jt][0] = __builtin_amdgcn_mfma_f32_16x16x32_bf16(aq, bt[0], pacc[jt][0], 0, 0, 0);
            pacc[jt][1] = __builtin_amdgcn_mfma_f32_16x16x32_bf16(aq, bt[1], pacc[jt][1], 0, 0, 0);
        }
    }

    // pack P -> Ptp via wave-private bounce (g_sb region dead after Z)
    {
        unsigned short* pb = g_sb + w * 1024;
        #pragma unroll
        for (int jt = 0; jt < 2; jt++)
            #pragma unroll
            for (int nt = 0; nt < 2; nt++) {
                int grp = (nt * 2 + (l15 >> 3)) & 3;
                #pragma unroll
                for (int r = 0; r < 4; r++) {
                    int lane8 = grp * 16 + q * 4 + r;
                    pb[(jt * 64 + lane8) * 8 + (l15 & 7)] = f2bf(pacc[jt][nt][r]);
                }
            }
        int hs = hblk * 4 + w;
        uint4 f0 = *(uint4*)(pb + (0 * 64 + lane) * 8);
        uint4 f1 = *(uint4*)(pb + (1 * 64 + lane) * 8);
        *(uint4*)(Ptp + (((size_t)(b * 32 + hs) * 2 + 0) * 64 + lane) * 8) = f0;
        *(uint4*)(Ptp + (((size_t)(b * 32 + hs) * 2 + 1) * 64 + lane) * 8) = f1;
    }
}

// ---------------------------------------------------------------------------
// KF (iterations 1..9): G' = P.WW + u (x) yW1, then Z/tanh/P.
// Grid 512 (b = bid&127, hblk2 = bid>>7), N=64 h2 per wave; Ptin[b] staged
// once per block in double-buffered 16KB LDS chunks, shared by all 4 waves.
// ---------------------------------------------------------------------------
__global__ __launch_bounds__(256) void kf_kernel(
        const unsigned short* __restrict__ Ptin,  // [B][32 hs][2 mt][64][8]
        const unsigned short* __restrict__ WWp,   // [64 h2b][32 hs][64][8]
        const float* __restrict__ yW1,            // [B][1024] fp32
        const float* __restrict__ b1,
        const float* __restrict__ ws,
        unsigned short* __restrict__ Ptout)
{
    __shared__ __align__(16) char smem[69632];
    const int t    = threadIdx.x;
    const int lane = t & 63;
    const int w    = t >> 6;
    const int q    = lane >> 4;
    const int l15  = lane & 15;
    const int bid  = blockIdx.x;
    const int b    = bid & 127;        // XCD affinity: bid%8 = b%8
    const int hblk2 = bid >> 7;        // 0..3
    const int hw   = hblk2 * 256 + w * 64;

    f32x4 acc[2][4] = {};
    const unsigned short* Ab  = Ptin + (size_t)b * 32768;
    const unsigned short* WWb = WWp + (size_t)(hblk2 * 16 + w * 4) * 16384;
    unsigned short* buf0 = (unsigned short*)smem;
    unsigned short* buf1 = (unsigned short*)(smem + 16384);

    {   // stage chunk 0
        const uint4* src = (const uint4*)Ab;
        uint4* dst = (uint4*)buf0;
        #pragma unroll
        for (int i = 0; i < 4; i++) dst[i * 256 + t] = src[i * 256 + t];
    }
    __syncthreads();

    #pragma unroll 1
    for (int c = 0; c < 4; ++c) {
        if (c < 3) {
            const uint4* src = (const uint4*)(Ab + (c + 1) * 8192);
            uint4* dst = (uint4*)((c & 1) ? buf0 : buf1);
            #pragma unroll
            for (int i = 0; i < 4; i++) dst[i * 256 + t] = src[i * 256 + t];
        }
        const unsigned short* Ac = (c & 1) ? buf1 : buf0;
        #pragma unroll
        for (int sl = 0; sl < 8; ++sl) {
            int s = c * 8 + sl;
            bf16x8 a0 = *(const bf16x8*)(Ac + (sl * 2 + 0) * 512 + lane * 8);
            bf16x8 a1 = *(const bf16x8*)(Ac + (sl * 2 + 1) * 512 + lane * 8);
            #pragma unroll
            for (int nt = 0; nt < 4; nt++) {
                bf16x8 bb = *(const bf16x8*)(WWb + nt * 16384 + s * 512 + lane * 8);
                acc[0][nt] = __builtin_amdgcn_mfma_f32_16x16x32_bf16(a0, bb, acc[0][nt], 0, 0, 0);
                acc[1][nt] = __builtin_amdgcn_mfma_f32_16x16x32_bf16(a1, bb, acc[1][nt], 0, 0, 0);
            }
        }
        __syncthreads();
    }

    unsigned short* g_w  = (unsigned short*)(smem + w * 4096);
    unsigned short* t_w  = (unsigned short*)(smem + 16384 + w * 9216);
    unsigned short* pb_w = (unsigned short*)(smem + 53248 + w * 4096);

    const float* U = ws + OFF_U;
    float yw[4];
    #pragma unroll
    for (int nt = 0; nt < 4; nt++)
        yw[nt] = yW1[(size_t)b * HH + hw + nt * 16 + l15];
    #pragma unroll
    for (int mt = 0; mt < 2; mt++) {
        float4 uv = *(const float4*)(U + mt * 16 + q * 4);
        #pragma unroll
        for (int nt = 0; nt < 4; nt++) {
            int hl = nt * 16 + l15;
            store4bf(&g_w[hl * 32 + mt * 16 + q * 4],
                     acc[mt][nt][0] + uv.x * yw[nt],
                     acc[mt][nt][1] + uv.y * yw[nt],
                     acc[mt][nt][2] + uv.z * yw[nt],
                     acc[mt][nt][3] + uv.w * yw[nt]);
        }
    }

    // Z = Phi_f^T G' : M=64(m) x N=64(h2/wave) x K=32(j)
    f32x4 zacc[4][4] = {};
    const unsigned short* PF = (const unsigned short*)(ws + OFF_PHIF_BF);
    bf16x8 gb[4];
    #pragma unroll
    for (int nt = 0; nt < 4; nt++)
        gb[nt] = *(const bf16x8*)(&g_w[(nt * 16 + l15) * 32 + q * 8]);
    #pragma unroll
    for (int mt = 0; mt < 4; mt++) {
        bf16x8 af = *(const bf16x8*)(PF + (mt * 16 + l15) * 32 + q * 8);
        #pragma unroll
        for (int nt = 0; nt < 4; nt++)
            zacc[mt][nt] = __builtin_amdgcn_mfma_f32_16x16x32_bf16(af, gb[nt], zacc[mt][nt], 0, 0, 0);
    }

    const float* TTp = ws + OFF_TTRUE;
    float b1v[4];
    #pragma unroll
    for (int nt = 0; nt < 4; nt++)
        b1v[nt] = b1[hw + nt * 16 + l15];
    #pragma unroll
    for (int mt = 0; mt < 4; mt++) {
        float4 ttv = *(const float4*)(TTp + mt * 16 + q * 4);
        #pragma unroll
        for (int nt = 0; nt < 4; nt++) {
            int hl = nt * 16 + l15;
            float v0 = tanh_fast(zacc[mt][nt][0] + ttv.x * b1v[nt]);
            float v1 = tanh_fast(zacc[mt][nt][1] + ttv.y * b1v[nt]);
            float v2 = tanh_fast(zacc[mt][nt][2] + ttv.z * b1v[nt]);
            float v3 = tanh_fast(zacc[mt][nt][3] + ttv.w * b1v[nt]);
            store4bf(&t_w[hl * 72 + mt * 16 + q * 4], v0, v1, v2, v3);
        }
    }

    // P = Q^T T : M=32(j) x N=64(h2/wave) x K=64(m)
    f32x4 pacc[2][4] = {};
    const unsigned short* QT = (const unsigned short*)(ws + OFF_QT_BF);
    #pragma unroll
    for (int ks = 0; ks < 2; ks++) {
        bf16x8 bt[4];
        #pragma unroll
        for (int nt = 0; nt < 4; nt++)
            bt[nt] = *(const bf16x8*)(&t_w[(nt * 16 + l15) * 72 + ks * 32 + q * 8]);
        #pragma unroll
        for (int jt = 0; jt < 2; jt++) {
            bf16x8 aq = *(const bf16x8*)(QT + (jt * 16 + l15) * 64 + ks * 32 + q * 8);
            #pragma unroll
            for (int nt = 0; nt < 4; nt++)
                pacc[jt][nt] = __builtin_amdgcn_mfma_f32_16x16x32_bf16(aq, bt[nt], pacc[jt][nt], 0, 0, 0);
        }
    }

    // pack P -> Ptout (wave-private bounce; 4 fragments = 2 hs x 2 jt)
    {
        #pragma unroll
        for (int jt = 0; jt < 2; jt++)
            #pragma unroll
            for (int nt = 0; nt < 4; nt++) {
                int grp    = ((nt & 1) * 2 + (l15 >> 3)) & 3;
                int hs_loc = nt >> 1;
                #pragma unroll
                for (int r = 0; r < 4; r++) {
                    int lane8 = grp * 16 + q * 4 + r;
                    pb_w[(hs_loc * 2 + jt) * 512 + lane8 * 8 + (l15 & 7)] = f2bf(pacc[jt][nt][r]);
                }
            }
        int hs0 = hblk2 * 8 + w * 2;
        #pragma unroll
        for (int i = 0; i < 4; i++) {   // i = hs_loc*2 + jt
            uint4 fv = *(uint4*)(pb_w + i * 512 + lane * 8);
            int hs = hs0 + (i >> 1), jt = i & 1;
            *(uint4*)(Ptout + (((size_t)(b * 32 + hs) * 2 + jt) * 64 + lane) * 8) = fv;
        }
    }
}

// ---------------------------------------------------------------------------
// K2F (final): Bn_val = P.W2 + y u (fp32); writes out1 directly and
// out0 = sum_n Bn_val*Phi_out. Grid 1024 1-D, XCD-swizzled (b = bid&127).
// ---------------------------------------------------------------------------
__global__ __launch_bounds__(256) void k2f_kernel(
        const unsigned short* __restrict__ Ptp,  // [B][32 hs][2 mt][64][8] bf16
        const unsigned short* __restrict__ W2p,  // frag-packed
        const float* __restrict__ y_init,        // [B][512]
        const float* __restrict__ ws,
        float* __restrict__ out)
{
    __shared__ __align__(16) float ls[4 * 544];
    __shared__ float phiout_s[NB * TT];

    const int t    = threadIdx.x;
    const int lane = t & 63;
    const int w    = t >> 6;
    const int q    = lane >> 4;
    const int l15  = lane & 15;
    const int bid  = blockIdx.x;
    const int b    = bid & 127;        // XCD affinity
    const int dblk = bid >> 7;         // 0..7
    const int dw   = dblk * 64 + w * 16;

    for (int f = t; f < NB * TT; f += 256) phiout_s[f] = ws[OFF_PHIOUT + f];

    f32x4 acc[2] = {};
    const unsigned short* Ab  = Ptp + (size_t)b * 32768;
    const unsigned short* W2b = W2p + (size_t)(dblk * 4 + w) * 16384;
    #pragma unroll 4
    for (int s = 0; s < 32; s++) {
        bf16x8 a0 = *(const bf16x8*)(Ab + (s * 2 + 0) * 512 + lane * 8);
        bf16x8 a1 = *(const bf16x8*)(Ab + (s * 2 + 1) * 512 + lane * 8);
        bf16x8 bb = *(const bf16x8*)(W2b + s * 512 + lane * 8);
        acc[0] = __builtin_amdgcn_mfma_f32_16x16x32_bf16(a0, bb, acc[0], 0, 0, 0);
        acc[1] = __builtin_amdgcn_mfma_f32_16x16x32_bf16(a1, bb, acc[1], 0, 0, 0);
    }

    const float* U = ws + OFF_U;
    float yv = y_init[(size_t)b * DD + dw + l15];
    #pragma unroll
    for (int mt = 0; mt < 2; mt++) {
        float4 uv = *(const float4*)(U + mt * 16 + q * 4);
        #pragma unroll
        for (int r = 0; r < 4; r++) {
            int j = mt * 16 + q * 4 + r;
            float uvr = (r == 0) ? uv.x : (r == 1) ? uv.y : (r == 2) ? uv.z : uv.w;
            ls[w * 544 + j * 17 + l15] = acc[mt][r] + yv * uvr;
        }
    }
    __syncthreads();

    // out1 = Bn copy (coalesced)
    float* out1 = out + (size_t)TT * BB * DD;
    #pragma unroll
    for (int it = 0; it < 8; it++) {
        int f = it * 64 + lane;
        int d_l = f >> 5, j2 = f & 31;
        out1[((size_t)b * DD + dw + d_l) * NB + j2] = ls[w * 544 + j2 * 17 + d_l];
    }

    // out0[t16, b, d] = sum_n val[d][n] * phiout[n][t16]   (64 d x 16 t per block)
    #pragma unroll
    for (int i = 0; i < 4; i++) {
        int idx = i * 256 + t;
        int t16 = idx >> 6, dl = idx & 63;
        float s = 0.f;
        #pragma unroll
        for (int n = 0; n < NB; n++)
            s += ls[(dl >> 4) * 544 + n * 17 + (dl & 15)] * phiout_s[n * TT + t16];
        out[(size_t)t16 * (BB * DD) + (size_t)b * DD + dblk * 64 + dl] = s;
    }
}

// ---------------------------------------------------------------------------
extern "C" void kernel_launch(void* const* d_in, const int* in_sizes, int n_in,
                              void* d_out, int out_size, void* d_ws, size_t ws_size,
                              hipStream_t stream) {
    const float* t_span = (const float*)d_in[0];
    const float* y_init = (const float*)d_in[1];
    const float* B_init = (const float*)d_in[2];
    const float* W1     = (const float*)d_in[3];
    const float* b1     = (const float*)d_in[4];
    const float* W2     = (const float*)d_in[5];
    float* ws  = (float*)d_ws;
    float* out = (float*)d_out;

    unsigned short* W1p  = (unsigned short*)(ws + OFF_W1P);
    unsigned short* W2p  = (unsigned short*)(ws + OFF_W2P);
    unsigned short* WWp  = (unsigned short*)(ws + OFF_WWP);
    float*          yW1  = ws + OFF_YW1;
    unsigned short* PtpA = (unsigned short*)(ws + OFF_PTPA);
    unsigned short* PtpB = (unsigned short*)(ws + OFF_PTP0);

    // ONE prologue dispatch: setup + pack_w1 + pack_w2 + pack_ww + yw1
    prologue_kernel<<<dim3(385), 256, 0, stream>>>(t_span, W1, W2, y_init, ws);

    k1_kernel<<<dim3(1024), 256, 0, stream>>>(B_init, W1p, b1, ws, PtpA);

    unsigned short* pin  = PtpA;
    unsigned short* pout = PtpB;
    for (int it = 1; it < ITERS; it++) {
        kf_kernel<<<dim3(512), 256, 0, stream>>>(pin, WWp, yW1, b1, ws, pout);
        unsigned short* tmp = pin; pin = pout; pout = tmp;
    }
    // 9 kf's -> final P in pin
    k2f_kernel<<<dim3(1024), 256, 0, stream>>>(pin, W2p, y_init, ws, out);
}

// Round 16
// 317.587 us; speedup vs baseline: 12.5389x; 1.0657x over previous
//
#include <hip/hip_runtime.h>
#include <hip/hip_bf16.h>
#include <math.h>

// Problem constants (fixed by setup_inputs)
#define BB 128
#define DD 512
#define HH 1024
#define NB 32     // num_coeff_per_dim
#define MM 63     // 2N-1 simpson points
#define TT 16
#define ITERS 10

// ws layout (float units)
#define OFF_U       0        // 32 fp32
#define OFF_TTRUE   64       // 64 fp32 (tt[63]=0)
#define OFF_PHIOUT  128      // 512 fp32
#define OFF_PHIF_BF 1024     // bf16 [64 m][32 n]  (row 63 = 0)   = 1024 floats
#define OFF_QT_BF   2048     // bf16 [32 j][64 m]  (col 63 = 0)   = 1024 floats
#define HDRF        4096
#define OFF_PTPA    HDRF                     // bf16 frag-packed [B][32 hs][2 mt][64][8] = 2097152 f
#define OFF_PTP0    (OFF_PTPA + 2097152)     // bf16 frag-packed ping-pong buffer       = 2097152 f
#define OFF_W1P     (OFF_PTP0 + 2097152)     // bf16 frag-packed [64 hb][16 ds][64][8] = 262144 f
#define OFF_W2P     (OFF_W1P + 262144)       // bf16 frag-packed [32 db][32 hs][64][8] = 262144 f
#define OFF_WWP     (OFF_W2P + 262144)       // bf16 frag-packed [64 h2b][32 hs][64][8] = 524288 f
#define OFF_YW1     (OFF_WWP + 524288)       // fp32 [128 b][1024 h2] = 131072 f
// end = 5378048 floats = 21.5 MB

typedef __attribute__((ext_vector_type(8))) short bf16x8;
typedef __attribute__((ext_vector_type(4))) float f32x4;

static __device__ __forceinline__ unsigned short f2bf(float f) {
    unsigned int x = __builtin_bit_cast(unsigned int, f);
    unsigned int r = x + 0x7FFFu + ((x >> 16) & 1u);   // RNE
    return (unsigned short)(r >> 16);
}

static __device__ __forceinline__ void store4bf(unsigned short* p,
                                                float v0, float v1, float v2, float v3) {
    unsigned int lo = (unsigned int)f2bf(v0) | ((unsigned int)f2bf(v1) << 16);
    unsigned int hi = (unsigned int)f2bf(v2) | ((unsigned int)f2bf(v3) << 16);
    uint2 u; u.x = lo; u.y = hi;
    *(uint2*)p = u;   // 8B-aligned by construction
}

static __device__ __forceinline__ float tanh_fast(float x) {
    float e = exp2f(x * 2.88539008177793f);   // 2*log2(e)
    return 1.0f - 2.0f / (e + 1.0f);
}

// XOR-swizzled LDS A-tile addressing: tile [32 r][512 c] bf16, linear 32KB,
// byte = (r*1024 + c*2) ^ ((r&7)<<4). Bijective per row, 16B-aligned b128.
static __device__ __forceinline__ unsigned short* aS(unsigned short* smA, int r, int c16) {
    return (unsigned short*)((char*)smA + (((r << 10) + (c16 << 4)) ^ ((r & 7) << 4)));
}

// ---------------------------------------------------------------------------
// PROLOGUE (single dispatch, blocks partitioned by role):
//   bid 0        : setup -- closed-form DCT-I Phi_inv (no GJ)
//   bid 1..64    : pack_w1   (hb = bid-1)
//   bid 65..96   : pack_w2   (db = bid-65)
//   bid 97..352  : pack_ww   (idx: h2grp = idx&31, hpb = (idx>>5)*4+w)
//   bid 353..384 : yw1       (h2grp = bid-353, waves = b-tiles)
// ---------------------------------------------------------------------------
__global__ __launch_bounds__(256) void prologue_kernel(
        const float* __restrict__ t_span, const float* __restrict__ W1,
        const float* __restrict__ W2, const float* __restrict__ y_init,
        float* __restrict__ ws) {
    __shared__ __align__(16) char smem[66560];
    const int bid  = blockIdx.x;
    const int t    = threadIdx.x;
    const int lane = t & 63;
    const int w    = t >> 6;
    const int q    = lane >> 4;
    const int l15  = lane & 15;

    if (bid == 0) {
        // ---------------- setup ----------------
        double* tsim    = (double*)(smem + 0);       // 63
        double* ttrue_d = (double*)(smem + 512);     // 63
        double* wid     = (double*)(smem + 1024);    // 31
        double* phid    = (double*)(smem + 1280);    // 32*63
        double* pinv    = (double*)(smem + 17408);   // 32*32 closed-form Phi_inv
        double* Rl      = (double*)(smem + 34048);   // 63*32
        double* Qd      = (double*)(smem + 50176);   // 63*32

        const double PI = 3.14159265358979323846;
        const double t0 = (double)t_span[0];
        const double t1 = (double)t_span[TT - 1];

        if (t < MM) {
            double v;
            if ((t & 1) == 0) {
                int j = t >> 1;
                v = -cos(PI * (double)j / (double)(NB - 1));
            } else {
                int i = t >> 1;
                double a = -cos(PI * (double)i / (double)(NB - 1));
                double b = -cos(PI * (double)(i + 1) / (double)(NB - 1));
                v = 0.5 * (a + b);
            }
            tsim[t] = v;
            ttrue_d[t] = t0 + 0.5 * (t1 - t0) * (v + 1.0);
        }
        __syncthreads();
        if (t < 31) wid[t] = (ttrue_d[2 * t + 2] - ttrue_d[2 * t]) / 6.0;
        if (t < MM) ws[OFF_TTRUE + t] = (float)ttrue_d[t];
        if (t == 63) ws[OFF_TTRUE + 63] = 0.0f;

        if (t < MM) {
            double x = tsim[t];
            double r0 = 1.0, r1 = x;
            phid[0 * MM + t] = r0;
            phid[1 * MM + t] = r1;
            for (int n = 2; n < NB; n++) {
                double r2 = 2.0 * x * r1 - r0;
                phid[n * MM + t] = r2;
                r0 = r1; r1 = r2;
            }
        }

        // closed-form Phi_inv (independent of phid)
        for (int f = t; f < NB * NB; f += 256) {
            int i = f >> 5, j = f & 31;
            double ci = (i == 0 || i == NB - 1) ? 2.0 : 1.0;
            double cj = (j == 0 || j == NB - 1) ? 2.0 : 1.0;
            double v = 2.0 * cos(PI * (double)(i * j) / (double)(NB - 1))
                       / ((double)(NB - 1) * ci * cj);
            pinv[f] = (j & 1) ? -v : v;
        }
        __syncthreads();

        {   // phif_bf [m 64][n 32], row 63 = 0
            unsigned short* pf = (unsigned short*)(ws + OFF_PHIF_BF);
            for (int f = t; f < 64 * 32; f += 256) {
                int m = f >> 5, n = f & 31;
                pf[f] = f2bf(m < MM ? (float)phid[n * MM + m] : 0.0f);
            }
        }

        if (t < MM) {
            double acc = 0.0;
            Rl[t * NB + 0] = 0.0;
            for (int i = 1; i < NB; i++) {
                int ip = i - 1;
                double wv = 0.0;
                if (t == 2 * ip)     wv += wid[ip];
                if (t == 2 * ip + 1) wv += 4.0 * wid[ip];
                if (t == 2 * ip + 2) wv += wid[ip];
                acc += wv;
                Rl[t * NB + i] = acc;
            }
        }
        __syncthreads();

        for (int f = t; f < MM * NB; f += 256) {
            int m = f >> 5, j = f & 31;
            double s = 0.0;
            for (int i = 0; i < NB; i++) s += Rl[m * NB + i] * pinv[i * 32 + j];
            Qd[f] = s;
        }
        __syncthreads();

        {   // qt_bf [j 32][m 64], col 63 = 0
            unsigned short* qt = (unsigned short*)(ws + OFF_QT_BF);
            for (int f = t; f < 32 * 64; f += 256) {
                int j = f >> 6, m = f & 63;
                qt[f] = f2bf(m < MM ? (float)Qd[m * NB + j] : 0.0f);
            }
        }
        if (t < NB) {
            double s = 0.0;
            for (int i = 0; i < NB; i++) s += pinv[i * 32 + t];
            ws[OFF_U + t] = (float)s;
        }
        if (t < TT) {
            double x = -1.0 + 2.0 * ((double)t_span[t] - t0) / (t1 - t0);
            double r0 = 1.0, r1 = x;
            ws[OFF_PHIOUT + 0 * TT + t] = 1.0f;
            ws[OFF_PHIOUT + 1 * TT + t] = (float)x;
            for (int n = 2; n < NB; n++) {
                double r2 = 2.0 * x * r1 - r0;
                ws[OFF_PHIOUT + n * TT + t] = (float)r2;
                r0 = r1; r1 = r2;
            }
        }
        return;
    }

    if (bid <= 64) {
        // ---------------- pack_w1: hb = bid-1 ----------------
        unsigned short* W1p = (unsigned short*)(ws + OFF_W1P);
        const int hb = bid - 1;
        #pragma unroll
        for (int i = 0; i < 4; i++) {
            int f = i * 256 + t;
            int ds = f >> 6, ln = f & 63;
            int qq = ln >> 4, ll = ln & 15;
            unsigned short tmp[8];
            #pragma unroll
            for (int e = 0; e < 8; e++)
                tmp[e] = f2bf(W1[(size_t)(ds * 32 + qq * 8 + e) * HH + hb * 16 + ll]);
            *(uint4*)(W1p + ((size_t)(hb * 16 + ds) * 64 + ln) * 8) = *(uint4*)tmp;
        }
        return;
    }

    if (bid <= 96) {
        // ---------------- pack_w2: db = bid-65 ----------------
        unsigned short* W2p = (unsigned short*)(ws + OFF_W2P);
        const int db = bid - 65;
        #pragma unroll
        for (int i = 0; i < 8; i++) {
            int f = i * 256 + t;
            int hs = f >> 6, ln = f & 63;
            int qq = ln >> 4, ll = ln & 15;
            unsigned short tmp[8];
            #pragma unroll
            for (int e = 0; e < 8; e++)
                tmp[e] = f2bf(W2[(size_t)(hs * 32 + qq * 8 + e) * DD + db * 16 + ll]);
            *(uint4*)(W2p + ((size_t)(db * 32 + hs) * 64 + ln) * 8) = *(uint4*)tmp;
        }
        return;
    }

    // lw1t = bf16 TRANSPOSED W1 slice: [32 col][520 row-stride] = 33280 B.
    unsigned short* lw1t = (unsigned short*)smem;

    if (bid <= 352) {
        // ---------------- pack_ww: WW = bf16(W2bf . W1bf), frag-packed ----
        unsigned short* WWp = (unsigned short*)(ws + OFF_WWP);
        unsigned short* pbounce = (unsigned short*)(smem + 33280);   // 8 KB
        const int idx   = bid - 97;
        const int h2grp = idx & 31;           // 32-col group of h2
        const int hpb   = (idx >> 5) * 4 + w; // wave's h'-row block (0..31)
        const int h2c0  = h2grp * 32;

        // coalesced stage: W1[:, h2c0..h2c0+32) -> lw1t[col][row] bf16
        for (int i = 0; i < 64; i++) {
            int f = i * 256 + t;
            int row = f >> 5, col = f & 31;
            lw1t[col * 520 + row] = f2bf(W1[(size_t)row * HH + h2c0 + col]);
        }
        __syncthreads();

        f32x4 acc[2][2] = {};
        #pragma unroll 4
        for (int ds = 0; ds < 16; ds++) {
            bf16x8 a[2];
            #pragma unroll
            for (int mt = 0; mt < 2; mt++) {
                const float* w2r = W2 + (size_t)(hpb * 32 + mt * 16 + l15) * DD + ds * 32 + q * 8;
                float4 va = *(const float4*)w2r;
                float4 vb = *(const float4*)(w2r + 4);
                unsigned short tmp[8] = { f2bf(va.x), f2bf(va.y), f2bf(va.z), f2bf(va.w),
                                          f2bf(vb.x), f2bf(vb.y), f2bf(vb.z), f2bf(vb.w) };
                a[mt] = *(bf16x8*)tmp;
            }
            bf16x8 bb0 = *(const bf16x8*)(lw1t + l15 * 520 + ds * 32 + q * 8);
            bf16x8 bb1 = *(const bf16x8*)(lw1t + (16 + l15) * 520 + ds * 32 + q * 8);
            acc[0][0] = __builtin_amdgcn_mfma_f32_16x16x32_bf16(a[0], bb0, acc[0][0], 0, 0, 0);
            acc[0][1] = __builtin_amdgcn_mfma_f32_16x16x32_bf16(a[0], bb1, acc[0][1], 0, 0, 0);
            acc[1][0] = __builtin_amdgcn_mfma_f32_16x16x32_bf16(a[1], bb0, acc[1][0], 0, 0, 0);
            acc[1][1] = __builtin_amdgcn_mfma_f32_16x16x32_bf16(a[1], bb1, acc[1][1], 0, 0, 0);
        }
        unsigned short* pb = pbounce + w * 1024;
        #pragma unroll
        for (int mt = 0; mt < 2; mt++)
            #pragma unroll
            for (int nt = 0; nt < 2; nt++) {
                int lane8 = (mt * 2 + (q >> 1)) * 16 + l15;
                #pragma unroll
                for (int r = 0; r < 4; r++)
                    pb[(nt * 64 + lane8) * 8 + (q & 1) * 4 + r] = f2bf(acc[mt][nt][r]);
            }
        uint4 f0 = *(uint4*)(pb + (0 * 64 + lane) * 8);
        uint4 f1 = *(uint4*)(pb + (1 * 64 + lane) * 8);
        int h2b0 = h2grp * 2;
        *(uint4*)(WWp + ((size_t)(h2b0 + 0) * 32 + hpb) * 512 + lane * 8) = f0;
        *(uint4*)(WWp + ((size_t)(h2b0 + 1) * 32 + hpb) * 512 + lane * 8) = f1;
        return;
    }

    {
        // ---------------- yw1: yW1[b][h2] = sum_d bf16(y) . W1bf ----------
        float* yW1 = ws + OFF_YW1;
        const int h2grp = bid - 353;   // 0..31
        const int h2c0  = h2grp * 32;

        for (int i = 0; i < 64; i++) {
            int f = i * 256 + t;
            int row = f >> 5, col = f & 31;
            lw1t[col * 520 + row] = f2bf(W1[(size_t)row * HH + h2c0 + col]);
        }
        __syncthreads();

        f32x4 acc[2][2] = {};
        #pragma unroll 4
        for (int ds = 0; ds < 16; ds++) {
            bf16x8 a[2];
            #pragma unroll
            for (int mt = 0; mt < 2; mt++) {
                const float* yr = y_init + (size_t)(w * 32 + mt * 16 + l15) * DD + ds * 32 + q * 8;
                float4 va = *(const float4*)yr;
                float4 vb = *(const float4*)(yr + 4);
                unsigned short tmp[8] = { f2bf(va.x), f2bf(va.y), f2bf(va.z), f2bf(va.w),
                                          f2bf(vb.x), f2bf(vb.y), f2bf(vb.z), f2bf(vb.w) };
                a[mt] = *(bf16x8*)tmp;
            }
            bf16x8 bb0 = *(const bf16x8*)(lw1t + l15 * 520 + ds * 32 + q * 8);
            bf16x8 bb1 = *(const bf16x8*)(lw1t + (16 + l15) * 520 + ds * 32 + q * 8);
            acc[0][0] = __builtin_amdgcn_mfma_f32_16x16x32_bf16(a[0], bb0, acc[0][0], 0, 0, 0);
            acc[0][1] = __builtin_amdgcn_mfma_f32_16x16x32_bf16(a[0], bb1, acc[0][1], 0, 0, 0);
            acc[1][0] = __builtin_amdgcn_mfma_f32_16x16x32_bf16(a[1], bb0, acc[1][0], 0, 0, 0);
            acc[1][1] = __builtin_amdgcn_mfma_f32_16x16x32_bf16(a[1], bb1, acc[1][1], 0, 0, 0);
        }
        #pragma unroll
        for (int mt = 0; mt < 2; mt++)
            #pragma unroll
            for (int nt = 0; nt < 2; nt++)
                #pragma unroll
                for (int r = 0; r < 4; r++) {
                    int b  = w * 32 + mt * 16 + q * 4 + r;
                    int h2 = h2c0 + nt * 16 + l15;
                    yW1[(size_t)b * HH + h2] = acc[mt][nt][r];
                }
    }
}

// ---------------------------------------------------------------------------
// K1_0 (first iteration only). Grid 1024 1-D, XCD-swizzled (b = bid&127).
// ---------------------------------------------------------------------------
__global__ __launch_bounds__(256) void k1_kernel(
        const float* __restrict__ B_init,        // [B][512 d][32 n] fp32
        const unsigned short* __restrict__ W1p,  // frag-packed
        const float* __restrict__ b1,            // [1024]
        const float* __restrict__ ws,
        unsigned short* __restrict__ Ptp)        // [B][32 hs][2 mt][64][8] bf16
{
    __shared__ __align__(16) char smem[40960];
    unsigned short* smA  = (unsigned short*)smem;           // A [32 n][512 d] swz
    unsigned short* t_sb = (unsigned short*)smem;           // [128][72] (overlays A)
    unsigned short* g_sb = (unsigned short*)(smem + 32768); // [128][32]

    const int t    = threadIdx.x;
    const int lane = t & 63;
    const int w    = t >> 6;
    const int q    = lane >> 4;
    const int l15  = lane & 15;
    const int bid  = blockIdx.x;
    const int b    = bid & 127;        // XCD affinity: bid%8 = b%8
    const int hblk = bid >> 7;
    const int hw   = hblk * 128 + w * 32;

    // stage: B_init[b] [512 d][32 n] fp32 -> smA bf16 [n][d] swizzled
    {
        const float* Bi = B_init + (size_t)b * DD * NB;
        #pragma unroll 8
        for (int i = 0; i < 64; i++) {
            int f = i * 256 + t;       // 0..16383
            int d = f >> 5, n = f & 31;
            *(unsigned short*)(smem + (((n << 10) + (d << 1)) ^ ((n & 7) << 4)))
                = f2bf(Bi[f]);
        }
    }
    __syncthreads();

    // Phase A: G = A W1^T, M=32(n) x N=32(h/wave) x K=512
    f32x4 acc[2][2] = {};
    const unsigned short* W1b = W1p + (size_t)(hw >> 4) * 8192;
    #pragma unroll 4
    for (int d0 = 0; d0 < DD; d0 += 32) {
        int c16 = (d0 >> 3) + q;
        int ds  = d0 >> 5;
        bf16x8 a0  = *(const bf16x8*)aS(smA, l15, c16);
        bf16x8 a1  = *(const bf16x8*)aS(smA, 16 + l15, c16);
        bf16x8 bb0 = *(const bf16x8*)(W1b + ds * 512 + lane * 8);
        bf16x8 bb1 = *(const bf16x8*)(W1b + 8192 + ds * 512 + lane * 8);
        acc[0][0] = __builtin_amdgcn_mfma_f32_16x16x32_bf16(a0, bb0, acc[0][0], 0, 0, 0);
        acc[0][1] = __builtin_amdgcn_mfma_f32_16x16x32_bf16(a0, bb1, acc[0][1], 0, 0, 0);
        acc[1][0] = __builtin_amdgcn_mfma_f32_16x16x32_bf16(a1, bb0, acc[1][0], 0, 0, 0);
        acc[1][1] = __builtin_amdgcn_mfma_f32_16x16x32_bf16(a1, bb1, acc[1][1], 0, 0, 0);
    }
    #pragma unroll
    for (int mt = 0; mt < 2; mt++)
        #pragma unroll
        for (int nt = 0; nt < 2; nt++) {
            int hl = w * 32 + nt * 16 + l15;
            store4bf(&g_sb[hl * 32 + mt * 16 + q * 4],
                     acc[mt][nt][0], acc[mt][nt][1], acc[mt][nt][2], acc[mt][nt][3]);
        }
    __syncthreads();   // all smA reads complete -> t_sb may overlay

    // Z = Phi_f^T G
    f32x4 zacc[4][2] = {};
    const unsigned short* PF = (const unsigned short*)(ws + OFF_PHIF_BF);
    bf16x8 gb[2];
    #pragma unroll
    for (int nt = 0; nt < 2; nt++)
        gb[nt] = *(const bf16x8*)(&g_sb[(w * 32 + nt * 16 + l15) * 32 + q * 8]);
    #pragma unroll
    for (int mt = 0; mt < 4; mt++) {
        bf16x8 af = *(const bf16x8*)(PF + (mt * 16 + l15) * 32 + q * 8);
        zacc[mt][0] = __builtin_amdgcn_mfma_f32_16x16x32_bf16(af, gb[0], zacc[mt][0], 0, 0, 0);
        zacc[mt][1] = __builtin_amdgcn_mfma_f32_16x16x32_bf16(af, gb[1], zacc[mt][1], 0, 0, 0);
    }

    const float* TTp = ws + OFF_TTRUE;
    float b1v[2] = { b1[hw + l15], b1[hw + 16 + l15] };
    #pragma unroll
    for (int mt = 0; mt < 4; mt++) {
        float4 ttv = *(const float4*)(TTp + mt * 16 + q * 4);
        #pragma unroll
        for (int nt = 0; nt < 2; nt++) {
            int hl = w * 32 + nt * 16 + l15;
            float v0 = tanh_fast(zacc[mt][nt][0] + ttv.x * b1v[nt]);
            float v1 = tanh_fast(zacc[mt][nt][1] + ttv.y * b1v[nt]);
            float v2 = tanh_fast(zacc[mt][nt][2] + ttv.z * b1v[nt]);
            float v3 = tanh_fast(zacc[mt][nt][3] + ttv.w * b1v[nt]);
            store4bf(&t_sb[hl * 72 + mt * 16 + q * 4], v0, v1, v2, v3);
        }
    }
    __syncthreads();

    // P = Q^T T
    f32x4 pacc[2][2] = {};
    const unsigned short* QT = (const unsigned short*)(ws + OFF_QT_BF);
    #pragma unroll
    for (int ks = 0; ks < 2; ks++) {
        bf16x8 bt[2];
        #pragma unroll
        for (int nt = 0; nt < 2; nt++)
            bt[nt] = *(const bf16x8*)(&t_sb[(w * 32 + nt * 16 + l15) * 72 + ks * 32 + q * 8]);
        #pragma unroll
        for (int jt = 0; jt < 2; jt++) {
            bf16x8 aq = *(const bf16x8*)(QT + (jt * 16 + l15) * 64 + ks * 32 + q * 8);
            pacc[jt][0] = __builtin_amdgcn_mfma_f32_16x16x32_bf16(aq, bt[0], pacc[jt][0], 0, 0, 0);
            pacc[jt][1] = __builtin_amdgcn_mfma_f32_16x16x32_bf16(aq, bt[1], pacc[jt][1], 0, 0, 0);
        }
    }

    // pack P -> Ptp via wave-private bounce (g_sb region dead after Z)
    {
        unsigned short* pb = g_sb + w * 1024;
        #pragma unroll
        for (int jt = 0; jt < 2; jt++)
            #pragma unroll
            for (int nt = 0; nt < 2; nt++) {
                int grp = (nt * 2 + (l15 >> 3)) & 3;
                #pragma unroll
                for (int r = 0; r < 4; r++) {
                    int lane8 = grp * 16 + q * 4 + r;
                    pb[(jt * 64 + lane8) * 8 + (l15 & 7)] = f2bf(pacc[jt][nt][r]);
                }
            }
        int hs = hblk * 4 + w;
        uint4 f0 = *(uint4*)(pb + (0 * 64 + lane) * 8);
        uint4 f1 = *(uint4*)(pb + (1 * 64 + lane) * 8);
        *(uint4*)(Ptp + (((size_t)(b * 32 + hs) * 2 + 0) * 64 + lane) * 8) = f0;
        *(uint4*)(Ptp + (((size_t)(b * 32 + hs) * 2 + 1) * 64 + lane) * 8) = f1;
    }
}

// ---------------------------------------------------------------------------
// KF (iterations 1..9): G' = P.WW + u (x) yW1, then Z/tanh/P.
// v3: grid 1024 (b = bid&127, hblk = bid>>7), N=32 h2/wave (R13 shape) +
// shared double-buffered A staging (R14 mechanism) in 32KB LDS total ->
// 4 blocks/CU = 4 waves/SIMD (was 2: the latency-hiding kf lacked).
// Phase-B scratch (g 2KB + t 4.6KB per wave, pb overlays g) overlays the
// dead A buffers after the K-loop's final barrier. Bitwise-same numerics.
// ---------------------------------------------------------------------------
__global__ __launch_bounds__(256) void kf_kernel(
        const unsigned short* __restrict__ Ptin,  // [B][32 hs][2 mt][64][8]
        const unsigned short* __restrict__ WWp,   // [64 h2b][32 hs][64][8]
        const float* __restrict__ yW1,            // [B][1024] fp32
        const float* __restrict__ b1,
        const float* __restrict__ ws,
        unsigned short* __restrict__ Ptout)
{
    __shared__ __align__(16) char smem[32768];
    const int t    = threadIdx.x;
    const int lane = t & 63;
    const int w    = t >> 6;
    const int q    = lane >> 4;
    const int l15  = lane & 15;
    const int bid  = blockIdx.x;
    const int b    = bid & 127;        // XCD affinity: bid%8 = b%8
    const int hblk = bid >> 7;         // 0..7
    const int hw   = hblk * 128 + w * 32;

    f32x4 acc[2][2] = {};
    const unsigned short* Ab  = Ptin + (size_t)b * 32768;
    const unsigned short* WWb = WWp + (size_t)(hw >> 4) * 16384;
    unsigned short* buf0 = (unsigned short*)smem;
    unsigned short* buf1 = (unsigned short*)(smem + 16384);

    {   // stage chunk 0 (16KB, coalesced, shared by all 4 waves)
        const uint4* src = (const uint4*)Ab;
        uint4* dst = (uint4*)buf0;
        #pragma unroll
        for (int i = 0; i < 4; i++) dst[i * 256 + t] = src[i * 256 + t];
    }
    __syncthreads();

    #pragma unroll 1
    for (int c = 0; c < 4; ++c) {
        if (c < 3) {   // prefetch next chunk into the other buffer
            const uint4* src = (const uint4*)(Ab + (c + 1) * 8192);
            uint4* dst = (uint4*)((c & 1) ? buf0 : buf1);
            #pragma unroll
            for (int i = 0; i < 4; i++) dst[i * 256 + t] = src[i * 256 + t];
        }
        const unsigned short* Ac = (c & 1) ? buf1 : buf0;
        #pragma unroll
        for (int sl = 0; sl < 8; ++sl) {
            int s = c * 8 + sl;
            bf16x8 a0  = *(const bf16x8*)(Ac + (sl * 2 + 0) * 512 + lane * 8);
            bf16x8 a1  = *(const bf16x8*)(Ac + (sl * 2 + 1) * 512 + lane * 8);
            bf16x8 bb0 = *(const bf16x8*)(WWb + s * 512 + lane * 8);
            bf16x8 bb1 = *(const bf16x8*)(WWb + 16384 + s * 512 + lane * 8);
            acc[0][0] = __builtin_amdgcn_mfma_f32_16x16x32_bf16(a0, bb0, acc[0][0], 0, 0, 0);
            acc[0][1] = __builtin_amdgcn_mfma_f32_16x16x32_bf16(a0, bb1, acc[0][1], 0, 0, 0);
            acc[1][0] = __builtin_amdgcn_mfma_f32_16x16x32_bf16(a1, bb0, acc[1][0], 0, 0, 0);
            acc[1][1] = __builtin_amdgcn_mfma_f32_16x16x32_bf16(a1, bb1, acc[1][1], 0, 0, 0);
        }
        __syncthreads();   // prefetch complete + A reads done before overwrite
    }
    // A buffers dead; wave-private phase-B scratch overlays them:
    unsigned short* g_w = (unsigned short*)(smem + w * 2048);          // [32][32]
    unsigned short* t_w = (unsigned short*)(smem + 8192 + w * 4608);   // [32][72]
    unsigned short* pb_w = g_w;    // reused after Z consumes g

    // bias u[j]*yW1[b][h2], write g_w[h2_loc][j]
    const float* U = ws + OFF_U;
    float yw[2] = { yW1[(size_t)b * HH + hw + l15],
                    yW1[(size_t)b * HH + hw + 16 + l15] };
    #pragma unroll
    for (int mt = 0; mt < 2; mt++) {
        float4 uv = *(const float4*)(U + mt * 16 + q * 4);
        #pragma unroll
        for (int nt = 0; nt < 2; nt++) {
            int hl = nt * 16 + l15;
            store4bf(&g_w[hl * 32 + mt * 16 + q * 4],
                     acc[mt][nt][0] + uv.x * yw[nt],
                     acc[mt][nt][1] + uv.y * yw[nt],
                     acc[mt][nt][2] + uv.z * yw[nt],
                     acc[mt][nt][3] + uv.w * yw[nt]);
        }
    }

    // Z = Phi_f^T G' : M=64(m) x N=32(h2/wave) x K=32(j)
    f32x4 zacc[4][2] = {};
    const unsigned short* PF = (const unsigned short*)(ws + OFF_PHIF_BF);
    bf16x8 gb[2];
    #pragma unroll
    for (int nt = 0; nt < 2; nt++)
        gb[nt] = *(const bf16x8*)(&g_w[(nt * 16 + l15) * 32 + q * 8]);
    #pragma unroll
    for (int mt = 0; mt < 4; mt++) {
        bf16x8 af = *(const bf16x8*)(PF + (mt * 16 + l15) * 32 + q * 8);
        zacc[mt][0] = __builtin_amdgcn_mfma_f32_16x16x32_bf16(af, gb[0], zacc[mt][0], 0, 0, 0);
        zacc[mt][1] = __builtin_amdgcn_mfma_f32_16x16x32_bf16(af, gb[1], zacc[mt][1], 0, 0, 0);
    }

    const float* TTp = ws + OFF_TTRUE;
    float b1v[2] = { b1[hw + l15], b1[hw + 16 + l15] };
    #pragma unroll
    for (int mt = 0; mt < 4; mt++) {
        float4 ttv = *(const float4*)(TTp + mt * 16 + q * 4);
        #pragma unroll
        for (int nt = 0; nt < 2; nt++) {
            int hl = nt * 16 + l15;
            float v0 = tanh_fast(zacc[mt][nt][0] + ttv.x * b1v[nt]);
            float v1 = tanh_fast(zacc[mt][nt][1] + ttv.y * b1v[nt]);
            float v2 = tanh_fast(zacc[mt][nt][2] + ttv.z * b1v[nt]);
            float v3 = tanh_fast(zacc[mt][nt][3] + ttv.w * b1v[nt]);
            store4bf(&t_w[hl * 72 + mt * 16 + q * 4], v0, v1, v2, v3);
        }
    }

    // P = Q^T T : M=32(j) x N=32(h2/wave) x K=64(m)
    f32x4 pacc[2][2] = {};
    const unsigned short* QT = (const unsigned short*)(ws + OFF_QT_BF);
    #pragma unroll
    for (int ks = 0; ks < 2; ks++) {
        bf16x8 bt[2];
        #pragma unroll
        for (int nt = 0; nt < 2; nt++)
            bt[nt] = *(const bf16x8*)(&t_w[(nt * 16 + l15) * 72 + ks * 32 + q * 8]);
        #pragma unroll
        for (int jt = 0; jt < 2; jt++) {
            bf16x8 aq = *(const bf16x8*)(QT + (jt * 16 + l15) * 64 + ks * 32 + q * 8);
            pacc[jt][0] = __builtin_amdgcn_mfma_f32_16x16x32_bf16(aq, bt[0], pacc[jt][0], 0, 0, 0);
            pacc[jt][1] = __builtin_amdgcn_mfma_f32_16x16x32_bf16(aq, bt[1], pacc[jt][1], 0, 0, 0);
        }
    }

    // pack P -> Ptout (wave-private bounce in pb_w = g_w region, dead after Z)
    {
        #pragma unroll
        for (int jt = 0; jt < 2; jt++)
            #pragma unroll
            for (int nt = 0; nt < 2; nt++) {
                int grp = (nt * 2 + (l15 >> 3)) & 3;
                #pragma unroll
                for (int r = 0; r < 4; r++) {
                    int lane8 = grp * 16 + q * 4 + r;
                    pb_w[(jt * 64 + lane8) * 8 + (l15 & 7)] = f2bf(pacc[jt][nt][r]);
                }
            }
        int hs = hblk * 4 + w;
        uint4 f0 = *(uint4*)(pb_w + (0 * 64 + lane) * 8);
        uint4 f1 = *(uint4*)(pb_w + (1 * 64 + lane) * 8);
        *(uint4*)(Ptout + (((size_t)(b * 32 + hs) * 2 + 0) * 64 + lane) * 8) = f0;
        *(uint4*)(Ptout + (((size_t)(b * 32 + hs) * 2 + 1) * 64 + lane) * 8) = f1;
    }
}

// ---------------------------------------------------------------------------
// K2F (final): Bn_val = P.W2 + y u (fp32); writes out1 directly and
// out0 = sum_n Bn_val*Phi_out. Grid 1024 1-D, XCD-swizzled (b = bid&127).
// ---------------------------------------------------------------------------
__global__ __launch_bounds__(256) void k2f_kernel(
        const unsigned short* __restrict__ Ptp,  // [B][32 hs][2 mt][64][8] bf16
        const unsigned short* __restrict__ W2p,  // frag-packed
        const float* __restrict__ y_init,        // [B][512]
        const float* __restrict__ ws,
        float* __restrict__ out)
{
    __shared__ __align__(16) float ls[4 * 544];
    __shared__ float phiout_s[NB * TT];

    const int t    = threadIdx.x;
    const int lane = t & 63;
    const int w    = t >> 6;
    const int q    = lane >> 4;
    const int l15  = lane & 15;
    const int bid  = blockIdx.x;
    const int b    = bid & 127;        // XCD affinity
    const int dblk = bid >> 7;         // 0..7
    const int dw   = dblk * 64 + w * 16;

    for (int f = t; f < NB * TT; f += 256) phiout_s[f] = ws[OFF_PHIOUT + f];

    f32x4 acc[2] = {};
    const unsigned short* Ab  = Ptp + (size_t)b * 32768;
    const unsigned short* W2b = W2p + (size_t)(dblk * 4 + w) * 16384;
    #pragma unroll 4
    for (int s = 0; s < 32; s++) {
        bf16x8 a0 = *(const bf16x8*)(Ab + (s * 2 + 0) * 512 + lane * 8);
        bf16x8 a1 = *(const bf16x8*)(Ab + (s * 2 + 1) * 512 + lane * 8);
        bf16x8 bb = *(const bf16x8*)(W2b + s * 512 + lane * 8);
        acc[0] = __builtin_amdgcn_mfma_f32_16x16x32_bf16(a0, bb, acc[0], 0, 0, 0);
        acc[1] = __builtin_amdgcn_mfma_f32_16x16x32_bf16(a1, bb, acc[1], 0, 0, 0);
    }

    const float* U = ws + OFF_U;
    float yv = y_init[(size_t)b * DD + dw + l15];
    #pragma unroll
    for (int mt = 0; mt < 2; mt++) {
        float4 uv = *(const float4*)(U + mt * 16 + q * 4);
        #pragma unroll
        for (int r = 0; r < 4; r++) {
            int j = mt * 16 + q * 4 + r;
            float uvr = (r == 0) ? uv.x : (r == 1) ? uv.y : (r == 2) ? uv.z : uv.w;
            ls[w * 544 + j * 17 + l15] = acc[mt][r] + yv * uvr;
        }
    }
    __syncthreads();

    // out1 = Bn copy (coalesced)
    float* out1 = out + (size_t)TT * BB * DD;
    #pragma unroll
    for (int it = 0; it < 8; it++) {
        int f = it * 64 + lane;
        int d_l = f >> 5, j2 = f & 31;
        out1[((size_t)b * DD + dw + d_l) * NB + j2] = ls[w * 544 + j2 * 17 + d_l];
    }

    // out0[t16, b, d] = sum_n val[d][n] * phiout[n][t16]   (64 d x 16 t per block)
    #pragma unroll
    for (int i = 0; i < 4; i++) {
        int idx = i * 256 + t;
        int t16 = idx >> 6, dl = idx & 63;
        float s = 0.f;
        #pragma unroll
        for (int n = 0; n < NB; n++)
            s += ls[(dl >> 4) * 544 + n * 17 + (dl & 15)] * phiout_s[n * TT + t16];
        out[(size_t)t16 * (BB * DD) + (size_t)b * DD + dblk * 64 + dl] = s;
    }
}

// ---------------------------------------------------------------------------
extern "C" void kernel_launch(void* const* d_in, const int* in_sizes, int n_in,
                              void* d_out, int out_size, void* d_ws, size_t ws_size,
                              hipStream_t stream) {
    const float* t_span = (const float*)d_in[0];
    const float* y_init = (const float*)d_in[1];
    const float* B_init = (const float*)d_in[2];
    const float* W1     = (const float*)d_in[3];
    const float* b1     = (const float*)d_in[4];
    const float* W2     = (const float*)d_in[5];
    float* ws  = (float*)d_ws;
    float* out = (float*)d_out;

    unsigned short* W1p  = (unsigned short*)(ws + OFF_W1P);
    unsigned short* W2p  = (unsigned short*)(ws + OFF_W2P);
    unsigned short* WWp  = (unsigned short*)(ws + OFF_WWP);
    float*          yW1  = ws + OFF_YW1;
    unsigned short* PtpA = (unsigned short*)(ws + OFF_PTPA);
    unsigned short* PtpB = (unsigned short*)(ws + OFF_PTP0);

    // ONE prologue dispatch: setup + pack_w1 + pack_w2 + pack_ww + yw1
    prologue_kernel<<<dim3(385), 256, 0, stream>>>(t_span, W1, W2, y_init, ws);

    k1_kernel<<<dim3(1024), 256, 0, stream>>>(B_init, W1p, b1, ws, PtpA);

    unsigned short* pin  = PtpA;
    unsigned short* pout = PtpB;
    for (int it = 1; it < ITERS; it++) {
        kf_kernel<<<dim3(1024), 256, 0, stream>>>(pin, WWp, yW1, b1, ws, pout);
        unsigned short* tmp = pin; pin = pout; pout = tmp;
    }
    // 9 kf's -> final P in pin
    k2f_kernel<<<dim3(1024), 256, 0, stream>>>(pin, W2p, y_init, ws, out);
}